// Round 1
// baseline (1487.750 us; speedup 1.0000x reference)
//
#include <hip/hip_runtime.h>
#include <hip/hip_fp16.h>
#include <math.h>
#include <cstdint>
#include <cstddef>

#define NGRAPH 64
#define NN 200
#define ADJN 40000
#define DIN 4000
#define NNODE 12800

typedef float    f32x4 __attribute__((ext_vector_type(4)));
typedef _Float16 f16x8 __attribute__((ext_vector_type(8)));
typedef _Float16 f16x4 __attribute__((ext_vector_type(4)));
typedef _Float16 f16x2 __attribute__((ext_vector_type(2)));
typedef short    bf8v  __attribute__((ext_vector_type(8)));
typedef short    bf4v  __attribute__((ext_vector_type(4)));

union BF8U  { bf8v v; bf4v h[2]; };
union F16X8U{ f16x8 v; f16x4 h[2]; f16x2 p[4]; };

__device__ __forceinline__ unsigned short f2bf(float f) {
  unsigned u = __float_as_uint(f);
  return (unsigned short)((u + 0x7fffu + ((u >> 16) & 1u)) >> 16);
}
__device__ __forceinline__ float bf2f(unsigned short s) {
  return __uint_as_float(((unsigned)s) << 16);
}
__device__ __forceinline__ float gelu_f(float x) {
  return x * 0.5f * (1.0f + erff(x * 0.70710678118654752f));
}

#if defined(__has_builtin)
#if __has_builtin(__builtin_amdgcn_fdot2)
#define FDOT2(a, b, c) __builtin_amdgcn_fdot2((a), (b), (c), false)
#endif
#endif
#ifndef FDOT2
#define FDOT2(a, b, c) ((c) + (float)(a)[0] * (float)(b)[0] + (float)(a)[1] * (float)(b)[1])
#endif

// ---------------------------------------------------------------------------
// K1: adj[64][40000] = sigmoid(raw_fc[64,4000] @ gbW[4000,40000] + gbb)
// split-bf16 MFMA (hi/lo), tile M=64 x N=64, BK=32, 4 waves (wave = 16 rows)
// ---------------------------------------------------------------------------
__global__ __launch_bounds__(256) void build_adj(
    const float* __restrict__ A, const float* __restrict__ W,
    const float* __restrict__ bias, float* __restrict__ adj) {
  __shared__ short Ah[64 * 44], Al[64 * 44], Wh[64 * 44], Wl[64 * 44];
  const int t = threadIdx.x, wave = t >> 6, lane = t & 63;
  const int n0 = blockIdx.x * 64;
  f32x4 acc[4] = {};
  const int arow = t >> 2, akc = (t & 3) * 8;
  const int wk = t >> 3, wnc = (t & 7) * 8;
  for (int k0 = 0; k0 < DIN; k0 += 32) {
    __syncthreads();
    {  // stage A tile [64][32] -> hi/lo bf16, padded stride 44
      const float* src = A + (size_t)arow * DIN + k0 + akc;
      float4 v0 = *(const float4*)src;
      float4 v1 = *(const float4*)(src + 4);
      float vv[8] = {v0.x, v0.y, v0.z, v0.w, v1.x, v1.y, v1.z, v1.w};
      bf4v h0, h1, l0, l1;
#pragma unroll
      for (int i = 0; i < 4; ++i) {
        unsigned short hh = f2bf(vv[i]);
        h0[i] = (short)hh; l0[i] = (short)f2bf(vv[i] - bf2f(hh));
      }
#pragma unroll
      for (int i = 0; i < 4; ++i) {
        unsigned short hh = f2bf(vv[4 + i]);
        h1[i] = (short)hh; l1[i] = (short)f2bf(vv[4 + i] - bf2f(hh));
      }
      *(bf4v*)(Ah + arow * 44 + akc)     = h0;
      *(bf4v*)(Ah + arow * 44 + akc + 4) = h1;
      *(bf4v*)(Al + arow * 44 + akc)     = l0;
      *(bf4v*)(Al + arow * 44 + akc + 4) = l1;
    }
    {  // stage W tile [32][64] transposed -> Wt[n][k], hi/lo
      const float* src = W + (size_t)(k0 + wk) * ADJN + n0 + wnc;
      float4 w0 = *(const float4*)src;
      float4 w1 = *(const float4*)(src + 4);
      float wv[8] = {w0.x, w0.y, w0.z, w0.w, w1.x, w1.y, w1.z, w1.w};
#pragma unroll
      for (int q = 0; q < 8; ++q) {
        unsigned short hh = f2bf(wv[q]);
        Wh[(wnc + q) * 44 + wk] = (short)hh;
        Wl[(wnc + q) * 44 + wk] = (short)f2bf(wv[q] - bf2f(hh));
      }
    }
    __syncthreads();
    const int kb = (lane >> 4) * 8;
    const int fr = (wave * 16 + (lane & 15)) * 44 + kb;
    BF8U ah, al;
    ah.h[0] = *(const bf4v*)(Ah + fr); ah.h[1] = *(const bf4v*)(Ah + fr + 4);
    al.h[0] = *(const bf4v*)(Al + fr); al.h[1] = *(const bf4v*)(Al + fr + 4);
#pragma unroll
    for (int j = 0; j < 4; ++j) {
      const int bc = (j * 16 + (lane & 15)) * 44 + kb;
      BF8U bh, bl;
      bh.h[0] = *(const bf4v*)(Wh + bc); bh.h[1] = *(const bf4v*)(Wh + bc + 4);
      bl.h[0] = *(const bf4v*)(Wl + bc); bl.h[1] = *(const bf4v*)(Wl + bc + 4);
      acc[j] = __builtin_amdgcn_mfma_f32_16x16x32_bf16(ah.v, bh.v, acc[j], 0, 0, 0);
      acc[j] = __builtin_amdgcn_mfma_f32_16x16x32_bf16(ah.v, bl.v, acc[j], 0, 0, 0);
      acc[j] = __builtin_amdgcn_mfma_f32_16x16x32_bf16(al.v, bh.v, acc[j], 0, 0, 0);
    }
  }
#pragma unroll
  for (int j = 0; j < 4; ++j) {
    const int col = n0 + j * 16 + (lane & 15);
    const float bb = bias[col];
#pragma unroll
    for (int vv = 0; vv < 4; ++vv) {
      const int row = wave * 16 + (lane >> 4) * 4 + vv;
      float x = acc[j][vv] + bb;
      adj[(size_t)row * ADJN + col] = 1.0f / (1.0f + __expf(-x));
    }
  }
}

// ---------------------------------------------------------------------------
// K2: adjS = 0.5*(adj + adj^T) per graph
// ---------------------------------------------------------------------------
__global__ void symmetrize(const float* __restrict__ adj, float* __restrict__ adjS) {
  const int idx = blockIdx.x * 256 + threadIdx.x;  // 2,560,000 exact
  const int b = idx / ADJN, r = idx % ADJN;
  const int i = r / NN, j = r % NN;
  adjS[idx] = 0.5f * (adj[(size_t)b * ADJN + i * NN + j] + adj[(size_t)b * ADJN + j * NN + i]);
}

// ---------------------------------------------------------------------------
// K2b: per-row mean / std(ddof=1)
// ---------------------------------------------------------------------------
__global__ __launch_bounds__(256) void rowstats(const float* __restrict__ adjS,
                                                float* __restrict__ meanv,
                                                float* __restrict__ stdv) {
  const int row = blockIdx.x * 4 + (threadIdx.x >> 6);
  const int lane = threadIdx.x & 63;
  const float* r = adjS + (size_t)row * NN;
  float s = 0.f, q = 0.f;
#pragma unroll
  for (int k = 0; k < 4; ++k) {
    int i = k * 64 + lane;
    if (i < NN) { float v = r[i]; s += v; q += v * v; }
  }
#pragma unroll
  for (int off = 32; off > 0; off >>= 1) { s += __shfl_xor(s, off); q += __shfl_xor(q, off); }
  if (lane == 0) {
    float m = s * (1.0f / 200.0f);
    float var = (q - 200.0f * m * m) * (1.0f / 199.0f);
    var = fmaxf(var, 0.f);
    meanv[row] = m;
    stdv[row] = sqrtf(var) + 1e-6f;
  }
}

// ---------------------------------------------------------------------------
// K3: exact 10000th-largest per graph via fp32-bit radix select
// ---------------------------------------------------------------------------
__global__ __launch_bounds__(256) void radix_select(const float* __restrict__ adjS,
                                                    float* __restrict__ tau) {
  __shared__ unsigned hist[2048];
  __shared__ unsigned s_pref, s_cA;
  const int g = blockIdx.x, t = threadIdx.x;
  const float* v = adjS + (size_t)g * ADJN;
  unsigned prefix = 0, pmask = 0, cA = 0;
  const int shifts[3] = {20, 9, 0};
  const int widths[3] = {2048, 2048, 512};
  for (int pass = 0; pass < 3; ++pass) {
    const int nb = widths[pass], sh = shifts[pass];
    for (int i = t; i < nb; i += 256) hist[i] = 0u;
    __syncthreads();
    for (int e = t; e < ADJN; e += 256) {
      unsigned u = __float_as_uint(v[e]);
      if ((u & pmask) == prefix) atomicAdd(&hist[(u >> sh) & (nb - 1)], 1u);
    }
    __syncthreads();
    if (t == 0) {
      unsigned cum = cA; int b = nb - 1;
      for (; b > 0; --b) { unsigned hb = hist[b]; if (cum + hb >= 10000u) break; cum += hb; }
      s_pref = prefix | ((unsigned)b << sh);
      s_cA = cum;
    }
    __syncthreads();
    prefix = s_pref; cA = s_cA;
    pmask |= (unsigned)(widths[pass] - 1) << sh;
    __syncthreads();
  }
  if (t == 0) tau[g] = __uint_as_float(prefix);
}

// ---------------------------------------------------------------------------
// K4: [mean,std] -> MLP(2->8 gelu ->16) -> LayerNorm(16) -> x0 f32
// ---------------------------------------------------------------------------
__global__ __launch_bounds__(256) void node_mlp(
    const float* __restrict__ meanv, const float* __restrict__ stdv,
    const float* __restrict__ feW1, const float* __restrict__ feb1,
    const float* __restrict__ feW2, const float* __restrict__ feb2,
    const float* __restrict__ ln_g, const float* __restrict__ ln_b,
    float* __restrict__ x0) {
  const int n = blockIdx.x * 256 + threadIdx.x;  // 12800 exact
  const float mu = meanv[n], sd = stdv[n];
  float h1[8];
#pragma unroll
  for (int o = 0; o < 8; ++o) h1[o] = gelu_f(mu * feW1[o] + sd * feW1[8 + o] + feb1[o]);
  float h2[16]; float s = 0.f;
#pragma unroll
  for (int o = 0; o < 16; ++o) {
    float a = feb2[o];
#pragma unroll
    for (int k = 0; k < 8; ++k) a += h1[k] * feW2[k * 16 + o];
    h2[o] = a; s += a;
  }
  s *= (1.0f / 16.0f);
  float var = 0.f;
#pragma unroll
  for (int o = 0; o < 16; ++o) { float d = h2[o] - s; var += d * d; }
  var *= (1.0f / 16.0f);
  const float inv = 1.0f / sqrtf(var + 1e-5f);
#pragma unroll
  for (int o = 0; o < 16; ++o) x0[(size_t)n * 16 + o] = (h2[o] - s) * inv * ln_g[o] + ln_b[o];
}

// ---------------------------------------------------------------------------
// K5: per-dst neighbor lists (row scan of symmetric adjS), ballot-compacted
// list1: v>=tau ; list2: (v>=tau && i!=j) + self appended
// ---------------------------------------------------------------------------
__global__ __launch_bounds__(256) void build_lists(
    const float* __restrict__ adjS, const float* __restrict__ tau,
    int* __restrict__ cnt1, int* __restrict__ cnt2,
    unsigned char* __restrict__ list1, unsigned char* __restrict__ list2) {
  const int g = blockIdx.x;
  const float tv = tau[g];
  const int t = threadIdx.x, wave = t >> 6, lane = t & 63;
  for (int j = wave; j < NN; j += 4) {
    const float* row = adjS + (size_t)g * ADJN + (size_t)j * NN;
    unsigned char* l1 = list1 + ((size_t)g * NN + j) * NN;
    unsigned char* l2 = list2 + ((size_t)g * NN + j) * NN;
    int c1 = 0, c2 = 0;
#pragma unroll
    for (int r = 0; r < 4; ++r) {
      int i = r * 64 + lane;
      bool p1 = false, p2 = false;
      if (i < NN) { float v = row[i]; p1 = (v >= tv); p2 = p1 && (i != j); }
      unsigned long long b1 = __ballot(p1);
      unsigned long long b2 = __ballot(p2);
      unsigned long long below = (lane == 0) ? 0ull : ((~0ull) >> (64 - lane));
      if (p1) l1[c1 + __popcll(b1 & below)] = (unsigned char)i;
      if (p2) l2[c2 + __popcll(b2 & below)] = (unsigned char)i;
      c1 += (int)__popcll(b1); c2 += (int)__popcll(b2);
    }
    if (lane == 0) {
      l2[c2] = (unsigned char)j;
      cnt1[g * NN + j] = c1;
      cnt2[g * NN + j] = c2 + 1;
    }
  }
}

// ---------------------------------------------------------------------------
// K6: xl1/xr1 = x0[12800,16] @ W[16,1024] + b  (K=16, VALU), out f16
// ---------------------------------------------------------------------------
__global__ __launch_bounds__(256) void lin16(const float* __restrict__ x0,
                                             const float* __restrict__ W,
                                             const float* __restrict__ bias,
                                             _Float16* __restrict__ out) {
  const int idx = blockIdx.x * 256 + threadIdx.x;  // 12800*128
  const int n = idx >> 7, oc = (idx & 127) * 8;
  float xr[16];
#pragma unroll
  for (int k = 0; k < 4; ++k) {
    float4 v = *(const float4*)(x0 + (size_t)n * 16 + k * 4);
    xr[4 * k] = v.x; xr[4 * k + 1] = v.y; xr[4 * k + 2] = v.z; xr[4 * k + 3] = v.w;
  }
  float acc[8] = {};
#pragma unroll
  for (int k = 0; k < 16; ++k) {
    float4 w0 = *(const float4*)(W + (size_t)k * 1024 + oc);
    float4 w1 = *(const float4*)(W + (size_t)k * 1024 + oc + 4);
    acc[0] += xr[k] * w0.x; acc[1] += xr[k] * w0.y;
    acc[2] += xr[k] * w0.z; acc[3] += xr[k] * w0.w;
    acc[4] += xr[k] * w1.x; acc[5] += xr[k] * w1.y;
    acc[6] += xr[k] * w1.z; acc[7] += xr[k] * w1.w;
  }
  f16x8 o;
#pragma unroll
  for (int q = 0; q < 8; ++q) o[q] = (_Float16)(acc[q] + bias[oc + q]);
  *(f16x8*)(out + (size_t)n * 1024 + oc) = o;
}

// ---------------------------------------------------------------------------
// K9: C[12800,Nhalf] = A[12800,1024]f16 @ W[1024,Nhalf]f32->f16 + bias, f16 out
// two weight/bias/out halves selected by blockIdx.y. 128x128 tile, BK=32.
// ---------------------------------------------------------------------------
__global__ __launch_bounds__(256) void gemm_f16(
    const _Float16* __restrict__ A,
    const float* __restrict__ W0, const float* __restrict__ W1,
    const float* __restrict__ b0, const float* __restrict__ b1,
    _Float16* __restrict__ out0, _Float16* __restrict__ out1,
    int Nhalf, int tilesPerHalf) {
  __shared__ _Float16 As[128 * 44];
  __shared__ _Float16 Ws[128 * 44];
  const int mbase = blockIdx.x * 128;
  const int hsel = blockIdx.y / tilesPerHalf;
  const int ncol0 = (blockIdx.y % tilesPerHalf) * 128;
  const float* W = hsel ? W1 : W0;
  const float* bias = hsel ? b1 : b0;
  _Float16* out = hsel ? out1 : out0;
  const int t = threadIdx.x, wave = t >> 6, lane = t & 63;
  const int wm = wave >> 1, wn = wave & 1;
  f32x4 acc[4][4] = {};
  const int ar = t >> 1, akc = (t & 1) * 16;
  const int wk = t >> 3, wnc = (t & 7) * 16;
  for (int k0 = 0; k0 < 1024; k0 += 32) {
    __syncthreads();
    {
      F16X8U u0, u1;
      u0.v = *(const f16x8*)(A + (size_t)(mbase + ar) * 1024 + k0 + akc);
      u1.v = *(const f16x8*)(A + (size_t)(mbase + ar) * 1024 + k0 + akc + 8);
      *(f16x4*)(As + ar * 44 + akc)      = u0.h[0];
      *(f16x4*)(As + ar * 44 + akc + 4)  = u0.h[1];
      *(f16x4*)(As + ar * 44 + akc + 8)  = u1.h[0];
      *(f16x4*)(As + ar * 44 + akc + 12) = u1.h[1];
    }
    {
      const float* src = W + (size_t)(k0 + wk) * Nhalf + ncol0 + wnc;
#pragma unroll
      for (int q = 0; q < 4; ++q) {
        float4 wv = *(const float4*)(src + q * 4);
        Ws[(wnc + q * 4 + 0) * 44 + wk] = (_Float16)wv.x;
        Ws[(wnc + q * 4 + 1) * 44 + wk] = (_Float16)wv.y;
        Ws[(wnc + q * 4 + 2) * 44 + wk] = (_Float16)wv.z;
        Ws[(wnc + q * 4 + 3) * 44 + wk] = (_Float16)wv.w;
      }
    }
    __syncthreads();
    const int kb = (lane >> 4) * 8;
    F16X8U af[4];
#pragma unroll
    for (int m = 0; m < 4; ++m) {
      const int row = wm * 64 + m * 16 + (lane & 15);
      af[m].h[0] = *(const f16x4*)(As + row * 44 + kb);
      af[m].h[1] = *(const f16x4*)(As + row * 44 + kb + 4);
    }
#pragma unroll
    for (int j = 0; j < 4; ++j) {
      const int col = wn * 64 + j * 16 + (lane & 15);
      F16X8U bfv;
      bfv.h[0] = *(const f16x4*)(Ws + col * 44 + kb);
      bfv.h[1] = *(const f16x4*)(Ws + col * 44 + kb + 4);
#pragma unroll
      for (int m = 0; m < 4; ++m)
        acc[m][j] = __builtin_amdgcn_mfma_f32_16x16x32_f16(af[m].v, bfv.v, acc[m][j], 0, 0, 0);
    }
  }
#pragma unroll
  for (int j = 0; j < 4; ++j) {
    const int col = ncol0 + wn * 64 + j * 16 + (lane & 15);
    const float bb = bias[col];
#pragma unroll
    for (int m = 0; m < 4; ++m) {
#pragma unroll
      for (int vv = 0; vv < 4; ++vv) {
        const int row = mbase + wm * 64 + m * 16 + (lane >> 4) * 4 + vv;
        out[(size_t)row * Nhalf + col] = (_Float16)(acc[m][j][vv] + bb);
      }
    }
  }
}

// ---------------------------------------------------------------------------
// K7: GATv2 layer (L1: C=128,H=8; L2: C=256,H=4 in 2 dst-ranges)
// WG = (graph, head, range), 8 waves, wave-per-dst. xl swizzled in LDS.
// ---------------------------------------------------------------------------
template <int C, int NR, int NSPLIT, int HC>
__global__ __launch_bounds__(512, 2) void gat_layer(
    const _Float16* __restrict__ xlb, const _Float16* __restrict__ xrb,
    const float* __restrict__ attw, const float* __restrict__ biasw,
    const int* __restrict__ cnts, const unsigned char* __restrict__ lists,
    _Float16* __restrict__ outb) {
  extern __shared__ char smem[];
  constexpr int XLB = 200 * C * 2;
  constexpr int XRB = NR * C * 2;
  _Float16* xr_s = (_Float16*)(smem + XLB);
  float* aw = (float*)(smem + XLB + XRB);
  unsigned char* ll = (unsigned char*)(smem + XLB + XRB + 8 * 200 * 4);
  const int g = blockIdx.x;
  const int hd = blockIdx.y / NSPLIT;
  const int range = blockIdx.y % NSPLIT;
  const int r0 = range * NR;
  const int t = threadIdx.x, wave = t >> 6, lane = t & 63;

  for (int ch = t; ch < 200 * (C / 8); ch += 512) {
    const int node = ch / (C / 8), cc = (ch % (C / 8)) * 8;
    f16x8 v = *(const f16x8*)(xlb + (size_t)(g * 200 + node) * HC + hd * C + cc);
    *(f16x8*)(smem + (((node * C + cc) * 2) ^ ((node & 15) << 4))) = v;
  }
  for (int ch = t; ch < NR * (C / 8); ch += 512) {
    const int node = ch / (C / 8), cc = (ch % (C / 8)) * 8;
    *(f16x8*)(xr_s + node * C + cc) =
        *(const f16x8*)(xrb + (size_t)(g * 200 + r0 + node) * HC + hd * C + cc);
  }
  unsigned attr[C / 2];
#pragma unroll
  for (int i = 0; i < C / 2; ++i) {
    f16x2 a;
    a[0] = (_Float16)attw[hd * C + 2 * i];
    a[1] = (_Float16)attw[hd * C + 2 * i + 1];
    attr[i] = __builtin_bit_cast(unsigned, a);
  }
  __syncthreads();

  for (int jj = wave; jj < NR; jj += 8) {
    const int j = r0 + jj;
    const int gn = g * 200 + j;
    const int cnt = cnts[gn];
    const unsigned char* lst = lists + (size_t)gn * NN;
    float lg[4] = {-INFINITY, -INFINITY, -INFINITY, -INFINITY};
#pragma unroll
    for (int r = 0; r < 4; ++r) {
      const int e = (r << 6) + lane;
      if (e < cnt) {
        const int s = lst[e];
        ll[wave * 200 + e] = (unsigned char)s;
        const int swz = (s & 15) << 4;
        float accv[4] = {0.f, 0.f, 0.f, 0.f};
#pragma unroll
        for (int c0 = 0; c0 < C; c0 += 16) {
          const int ai = ((c0 >> 4) & 1) * 2;
          F16X8U xa, xb, ra, rb;
          xa.v = *(const f16x8*)(smem + (((s * C + c0) * 2) ^ swz));
          xb.v = *(const f16x8*)(smem + (((s * C + c0 + 8) * 2) ^ swz));
          ra.v = *(const f16x8*)(xr_s + jj * C + c0);
          rb.v = *(const f16x8*)(xr_s + jj * C + c0 + 8);
#pragma unroll
          for (int p = 0; p < 4; ++p) {
            f16x2 z = xa.p[p] + ra.p[p];
            f16x2 zs = z * (_Float16)0.2f;
            f16x2 m = __builtin_elementwise_max(z, zs);
            accv[ai] = FDOT2(__builtin_bit_cast(f16x2, attr[c0 / 2 + p]), m, accv[ai]);
            f16x2 z2 = xb.p[p] + rb.p[p];
            f16x2 zs2 = z2 * (_Float16)0.2f;
            f16x2 m2 = __builtin_elementwise_max(z2, zs2);
            accv[ai + 1] = FDOT2(__builtin_bit_cast(f16x2, attr[c0 / 2 + 4 + p]), m2, accv[ai + 1]);
          }
        }
        lg[r] = (accv[0] + accv[1]) + (accv[2] + accv[3]);
      }
    }
    float mloc = fmaxf(fmaxf(lg[0], lg[1]), fmaxf(lg[2], lg[3]));
#pragma unroll
    for (int off = 32; off > 0; off >>= 1) mloc = fmaxf(mloc, __shfl_xor(mloc, off));
    float ex[4]; float ps = 0.f;
#pragma unroll
    for (int r = 0; r < 4; ++r) { ex[r] = __expf(lg[r] - mloc); ps += ex[r]; }
#pragma unroll
    for (int off = 32; off > 0; off >>= 1) ps += __shfl_xor(ps, off);
    const float denom = ps + 1e-16f;
#pragma unroll
    for (int r = 0; r < 4; ++r) {
      const int e = (r << 6) + lane;
      if (e < cnt) aw[wave * 200 + e] = ex[r] / denom;
    }
    constexpr int CPL = C / 64;
    float o[CPL] = {};
#pragma unroll 2
    for (int e = 0; e < cnt; ++e) {
      const float a = aw[wave * 200 + e];
      const int s = ll[wave * 200 + e];
      const int swz = (s & 15) << 4;
      if constexpr (CPL == 2) {
        f16x2 xv = *(const f16x2*)(smem + (((s * C + lane * 2) * 2) ^ swz));
        o[0] += a * (float)xv[0];
        o[1] += a * (float)xv[1];
      } else {
        f16x4 xv = *(const f16x4*)(smem + (((s * C + lane * 4) * 2) ^ swz));
        o[0] += a * (float)xv[0];
        o[1] += a * (float)xv[1];
        o[2] += a * (float)xv[2];
        o[3] += a * (float)xv[3];
      }
    }
    const int colb = hd * C + lane * CPL;
#pragma unroll
    for (int q = 0; q < CPL; ++q) {
      float val = o[q] + biasw[colb + q];
      outb[(size_t)gn * HC + colb + q] = (_Float16)gelu_f(val);
    }
  }
}

// ---------------------------------------------------------------------------
// K7-L3: GATv2 (H=1, C=512) channel-chunked; fused bias+gelu+partial mean pool
// WG = (graph, dst-range of 50). psum[32][64][512].
// ---------------------------------------------------------------------------
__global__ __launch_bounds__(512, 2) void gat_l3(
    const _Float16* __restrict__ xlb, const _Float16* __restrict__ xrb,
    const float* __restrict__ attw, const float* __restrict__ biasw,
    const int* __restrict__ cnts, const unsigned char* __restrict__ lists,
    float* __restrict__ psum) {
  extern __shared__ char smem[];
  _Float16* xr_s = (_Float16*)(smem + 51200);
  float* plog = (float*)(smem + 64000);
  unsigned char* ll = (unsigned char*)(smem + 104000);
  const int g = blockIdx.x, range = blockIdx.y, r0 = range * 50;
  const int t = threadIdx.x, wave = t >> 6, lane = t & 63;

  for (int chunk = 0; chunk < 4; ++chunk) {
    if (chunk) __syncthreads();
    for (int ch = t; ch < 200 * 16; ch += 512) {
      const int node = ch >> 4, cc = (ch & 15) * 8;
      *(f16x8*)(smem + (((node * 128 + cc) * 2) ^ ((node & 15) << 4))) =
          *(const f16x8*)(xlb + (size_t)(g * 200 + node) * 512 + chunk * 128 + cc);
    }
    for (int ch = t; ch < 50 * 16; ch += 512) {
      const int node = ch >> 4, cc = (ch & 15) * 8;
      *(f16x8*)(xr_s + node * 128 + cc) =
          *(const f16x8*)(xrb + (size_t)(g * 200 + r0 + node) * 512 + chunk * 128 + cc);
    }
    unsigned attr[64];
#pragma unroll
    for (int i = 0; i < 64; ++i) {
      f16x2 a;
      a[0] = (_Float16)attw[chunk * 128 + 2 * i];
      a[1] = (_Float16)attw[chunk * 128 + 2 * i + 1];
      attr[i] = __builtin_bit_cast(unsigned, a);
    }
    __syncthreads();
    for (int jj = wave; jj < 50; jj += 8) {
      const int gn = g * 200 + r0 + jj;
      const int cnt = cnts[gn];
      const unsigned char* lst = lists + (size_t)gn * NN;
#pragma unroll
      for (int r = 0; r < 4; ++r) {
        const int e = (r << 6) + lane;
        if (e < cnt) {
          const int s = lst[e];
          if (chunk == 0) ll[wave * 200 + e] = (unsigned char)s;
          const int swz = (s & 15) << 4;
          float accv[4] = {0.f, 0.f, 0.f, 0.f};
#pragma unroll
          for (int c0 = 0; c0 < 128; c0 += 16) {
            const int ai = ((c0 >> 4) & 1) * 2;
            F16X8U xa, xb, ra, rb;
            xa.v = *(const f16x8*)(smem + (((s * 128 + c0) * 2) ^ swz));
            xb.v = *(const f16x8*)(smem + (((s * 128 + c0 + 8) * 2) ^ swz));
            ra.v = *(const f16x8*)(xr_s + jj * 128 + c0);
            rb.v = *(const f16x8*)(xr_s + jj * 128 + c0 + 8);
#pragma unroll
            for (int p = 0; p < 4; ++p) {
              f16x2 z = xa.p[p] + ra.p[p];
              f16x2 zs = z * (_Float16)0.2f;
              f16x2 m = __builtin_elementwise_max(z, zs);
              accv[ai] = FDOT2(__builtin_bit_cast(f16x2, attr[c0 / 2 + p]), m, accv[ai]);
              f16x2 z2 = xb.p[p] + rb.p[p];
              f16x2 zs2 = z2 * (_Float16)0.2f;
              f16x2 m2 = __builtin_elementwise_max(z2, zs2);
              accv[ai + 1] = FDOT2(__builtin_bit_cast(f16x2, attr[c0 / 2 + 4 + p]), m2, accv[ai + 1]);
            }
          }
          const float acc = (accv[0] + accv[1]) + (accv[2] + accv[3]);
          if (chunk == 0) plog[jj * 200 + e] = acc;
          else plog[jj * 200 + e] += acc;
        }
      }
    }
  }
  __syncthreads();
  // softmax per dst (in plog)
  for (int jj = wave; jj < 50; jj += 8) {
    const int gn = g * 200 + r0 + jj;
    const int cnt = cnts[gn];
    float lg[4] = {-INFINITY, -INFINITY, -INFINITY, -INFINITY};
#pragma unroll
    for (int r = 0; r < 4; ++r) {
      const int e = (r << 6) + lane;
      if (e < cnt) lg[r] = plog[jj * 200 + e];
    }
    float mloc = fmaxf(fmaxf(lg[0], lg[1]), fmaxf(lg[2], lg[3]));
#pragma unroll
    for (int off = 32; off > 0; off >>= 1) mloc = fmaxf(mloc, __shfl_xor(mloc, off));
    float ex[4]; float ps = 0.f;
#pragma unroll
    for (int r = 0; r < 4; ++r) { ex[r] = __expf(lg[r] - mloc); ps += ex[r]; }
#pragma unroll
    for (int off = 32; off > 0; off >>= 1) ps += __shfl_xor(ps, off);
    const float denom = ps + 1e-16f;
#pragma unroll
    for (int r = 0; r < 4; ++r) {
      const int e = (r << 6) + lane;
      if (e < cnt) plog[jj * 200 + e] = ex[r] / denom;
    }
  }
  // aggregation, chunked; fused bias + gelu + partial mean pool
  for (int chunk = 0; chunk < 4; ++chunk) {
    __syncthreads();
    for (int ch = t; ch < 200 * 16; ch += 512) {
      const int node = ch >> 4, cc = (ch & 15) * 8;
      *(f16x8*)(smem + (((node * 128 + cc) * 2) ^ ((node & 15) << 4))) =
          *(const f16x8*)(xlb + (size_t)(g * 200 + node) * 512 + chunk * 128 + cc);
    }
    __syncthreads();
    float p0 = 0.f, p1 = 0.f;
    for (int jj = wave; jj < 50; jj += 8) {
      const int gn = g * 200 + r0 + jj;
      const int cnt = cnts[gn];
      float o0 = 0.f, o1 = 0.f;
#pragma unroll 2
      for (int e = 0; e < cnt; ++e) {
        const float a = plog[jj * 200 + e];
        const int s = ll[wave * 200 + e];
        f16x2 xv = *(const f16x2*)(smem + (((s * 128 + lane * 2) * 2) ^ ((s & 15) << 4)));
        o0 += a * (float)xv[0];
        o1 += a * (float)xv[1];
      }
      const int col = chunk * 128 + lane * 2;
      p0 += gelu_f(o0 + biasw[col]);
      p1 += gelu_f(o1 + biasw[col + 1]);
    }
    const int slot = range * 8 + wave;
    const int col = chunk * 128 + lane * 2;
    psum[((size_t)slot * 64 + g) * 512 + col] = p0;
    psum[((size_t)slot * 64 + g) * 512 + col + 1] = p1;
  }
}

// ---------------------------------------------------------------------------
// K10: d_out[b][c] = (1/200) * sum over 32 partial slots
// ---------------------------------------------------------------------------
__global__ void finalize(const float* __restrict__ psum, float* __restrict__ out) {
  const int idx = blockIdx.x * 256 + threadIdx.x;  // 32768 exact
  float s = 0.f;
#pragma unroll
  for (int k = 0; k < 32; ++k) s += psum[(size_t)k * 32768 + idx];
  out[idx] = s * 0.005f;
}

// ---------------------------------------------------------------------------
extern "C" void kernel_launch(void* const* d_in, const int* in_sizes, int n_in,
                              void* d_out, int out_size, void* d_ws, size_t ws_size,
                              hipStream_t stream) {
  const float* raw_fc = (const float*)d_in[0];
  const float* gbW = (const float*)d_in[1];
  const float* gbb = (const float*)d_in[2];
  const float* feW1 = (const float*)d_in[3];
  const float* feb1 = (const float*)d_in[4];
  const float* feW2 = (const float*)d_in[5];
  const float* feb2 = (const float*)d_in[6];
  const float* ln_g = (const float*)d_in[7];
  const float* ln_b = (const float*)d_in[8];
  const float* W1l = (const float*)d_in[9];  const float* b1l = (const float*)d_in[10];
  const float* W1r = (const float*)d_in[11]; const float* b1r = (const float*)d_in[12];
  const float* att1 = (const float*)d_in[13]; const float* bias1 = (const float*)d_in[14];
  const float* W2l = (const float*)d_in[15]; const float* b2l = (const float*)d_in[16];
  const float* W2r = (const float*)d_in[17]; const float* b2r = (const float*)d_in[18];
  const float* att2 = (const float*)d_in[19]; const float* bias2 = (const float*)d_in[20];
  const float* W3l = (const float*)d_in[21]; const float* b3l = (const float*)d_in[22];
  const float* W3r = (const float*)d_in[23]; const float* b3r = (const float*)d_in[24];
  const float* att3 = (const float*)d_in[25]; const float* bias3 = (const float*)d_in[26];

  if (ws_size < 110000000) return;  // need ~104.4 MiB scratch

  char* w = (char*)d_ws;
  float* adj   = (float*)(w + 0);
  float* adjS  = (float*)(w + 10240000);
  float* meanv = (float*)(w + 20480000);
  float* stdv  = (float*)(w + 20531200);
  float* tau   = (float*)(w + 20582400);
  float* x0    = (float*)(w + 20582656);
  int* cnt1    = (int*)(w + 21401856);
  int* cnt2    = (int*)(w + 21453056);
  unsigned char* list1 = (unsigned char*)(w + 21504256);
  unsigned char* list2 = (unsigned char*)(w + 24064256);
  _Float16* bufA = (_Float16*)(w + 26624256);   // xl1 / xl2 / xl3
  _Float16* bufB = (_Float16*)(w + 52838656);   // xr1 / xr2 / xr3
  _Float16* bufC = (_Float16*)(w + 79053056);   // x2 / x3
  float* psum = (float*)(w + 105267456);

  const int SMEM_L1 = 110400;   // 51200+51200+6400+1600
  const int SMEM_L2 = 161600;   // 102400+51200+6400+1600
  const int SMEM_L3 = 105600;   // 51200+12800+40000+1600
  hipFuncSetAttribute((const void*)gat_layer<128, 200, 1, 1024>,
                      hipFuncAttributeMaxDynamicSharedMemorySize, SMEM_L1);
  hipFuncSetAttribute((const void*)gat_layer<256, 100, 2, 1024>,
                      hipFuncAttributeMaxDynamicSharedMemorySize, SMEM_L2);
  hipFuncSetAttribute((const void*)gat_l3,
                      hipFuncAttributeMaxDynamicSharedMemorySize, SMEM_L3);

  build_adj<<<625, 256, 0, stream>>>(raw_fc, gbW, gbb, adj);
  symmetrize<<<10000, 256, 0, stream>>>(adj, adjS);
  rowstats<<<3200, 256, 0, stream>>>(adjS, meanv, stdv);
  radix_select<<<64, 256, 0, stream>>>(adjS, tau);
  node_mlp<<<50, 256, 0, stream>>>(meanv, stdv, feW1, feb1, feW2, feb2, ln_g, ln_b, x0);
  build_lists<<<64, 256, 0, stream>>>(adjS, tau, cnt1, cnt2, list1, list2);
  lin16<<<6400, 256, 0, stream>>>(x0, W1l, b1l, bufA);
  lin16<<<6400, 256, 0, stream>>>(x0, W1r, b1r, bufB);
  gat_layer<128, 200, 1, 1024><<<dim3(64, 8), 512, SMEM_L1, stream>>>(
      bufA, bufB, att1, bias1, cnt1, list1, bufC);
  gemm_f16<<<dim3(100, 16), 256, 0, stream>>>(bufC, W2l, W2r, b2l, b2r, bufA, bufB, 1024, 8);
  gat_layer<256, 100, 2, 1024><<<dim3(64, 8), 512, SMEM_L2, stream>>>(
      bufA, bufB, att2, bias2, cnt2, list2, bufC);
  gemm_f16<<<dim3(100, 8), 256, 0, stream>>>(bufC, W3l, W3r, b3l, b3r, bufA, bufB, 512, 4);
  gat_l3<<<dim3(64, 4), 512, SMEM_L3, stream>>>(bufA, bufB, att3, bias3, cnt2, list2, psum);
  finalize<<<128, 256, 0, stream>>>(psum, (float*)d_out);
}

// Round 2
// 1299.132 us; speedup vs baseline: 1.1452x; 1.1452x over previous
//
#include <hip/hip_runtime.h>
#include <hip/hip_fp16.h>
#include <math.h>
#include <cstdint>
#include <cstddef>

#define NGRAPH 64
#define NN 200
#define ADJN 40000
#define DIN 4000
#define NNODE 12800

typedef float    f32x4 __attribute__((ext_vector_type(4)));
typedef _Float16 f16x8 __attribute__((ext_vector_type(8)));
typedef _Float16 f16x4 __attribute__((ext_vector_type(4)));
typedef _Float16 f16x2 __attribute__((ext_vector_type(2)));
typedef short    bf8v  __attribute__((ext_vector_type(8)));
typedef short    bf4v  __attribute__((ext_vector_type(4)));

union BF8U  { bf8v v; bf4v h[2]; };
union F16X8U{ f16x8 v; f16x4 h[2]; f16x2 p[4]; };

__device__ __forceinline__ unsigned short f2bf(float f) {
  unsigned u = __float_as_uint(f);
  return (unsigned short)((u + 0x7fffu + ((u >> 16) & 1u)) >> 16);
}
__device__ __forceinline__ float bf2f(unsigned short s) {
  return __uint_as_float(((unsigned)s) << 16);
}
__device__ __forceinline__ float gelu_f(float x) {
  return x * 0.5f * (1.0f + erff(x * 0.70710678118654752f));
}

#if defined(__has_builtin)
#if __has_builtin(__builtin_amdgcn_fdot2)
#define FDOT2(a, b, c) __builtin_amdgcn_fdot2((a), (b), (c), false)
#endif
#endif
#ifndef FDOT2
#define FDOT2(a, b, c) ((c) + (float)(a)[0] * (float)(b)[0] + (float)(a)[1] * (float)(b)[1])
#endif

// ---------------------------------------------------------------------------
// K0: raw_fc -> hi/lo bf16 split (done once; A-fragments then read from global)
// ---------------------------------------------------------------------------
__global__ __launch_bounds__(256) void prep_A(const float* __restrict__ A,
                                              short* __restrict__ Ahi,
                                              short* __restrict__ Alo) {
  const int i = blockIdx.x * 256 + threadIdx.x;  // 256000 exact
  const float v = A[i];
  const unsigned short h = f2bf(v);
  Ahi[i] = (short)h;
  Alo[i] = (short)f2bf(v - bf2f(h));
}

// ---------------------------------------------------------------------------
// K0b: transpose-convert W[k][n] f32 -> Wt[n][k] f16 (once per GEMM weight)
// ---------------------------------------------------------------------------
__global__ __launch_bounds__(256) void transp_f16(const float* __restrict__ src,
                                                  _Float16* __restrict__ dst,
                                                  int K, int N) {
  __shared__ float tile[32][33];
  const int bk = blockIdx.x * 32, bn = blockIdx.y * 32;
  const int tx = threadIdx.x & 31, ty = threadIdx.x >> 5;
#pragma unroll
  for (int r = 0; r < 32; r += 8) tile[ty + r][tx] = src[(size_t)(bk + ty + r) * N + bn + tx];
  __syncthreads();
#pragma unroll
  for (int r = 0; r < 32; r += 8)
    dst[(size_t)(bn + ty + r) * K + bk + tx] = (_Float16)tile[tx][ty + r];
}

// ---------------------------------------------------------------------------
// K1: adj = sigmoid(raw_fc @ gbW + gbb); split-bf16 MFMA (3-term hi/lo)
// v2: A-frags direct from global (hi/lo precomputed); W LDS double-buffered
// with 1-iter register prefetch; single sync per K-step.
// ---------------------------------------------------------------------------
__global__ __launch_bounds__(256) void build_adj(
    const short* __restrict__ Ahi, const short* __restrict__ Alo,
    const float* __restrict__ W, const float* __restrict__ bias,
    float* __restrict__ adj) {
  __shared__ short Wh[2][64 * 44], Wl[2][64 * 44];
  const int t = threadIdx.x, wave = t >> 6, lane = t & 63;
  const int n0 = blockIdx.x * 64;
  const int wk = t >> 3, wnc = (t & 7) * 8;
  const int kb = (lane >> 4) * 8;
  const int arow = wave * 16 + (lane & 15);
  f32x4 acc[4] = {};
  // prefetch iter 0
  float4 w0 = *(const float4*)(W + (size_t)wk * ADJN + n0 + wnc);
  float4 w1 = *(const float4*)(W + (size_t)wk * ADJN + n0 + wnc + 4);
  bf8v ah = *(const bf8v*)(Ahi + (size_t)arow * DIN + kb);
  bf8v al = *(const bf8v*)(Alo + (size_t)arow * DIN + kb);
  for (int it = 0; it < 125; ++it) {
    const int p = it & 1;
    {  // convert + store current W regs (transposed, padded stride 44)
      float wv[8] = {w0.x, w0.y, w0.z, w0.w, w1.x, w1.y, w1.z, w1.w};
#pragma unroll
      for (int q = 0; q < 8; ++q) {
        unsigned short hh = f2bf(wv[q]);
        Wh[p][(wnc + q) * 44 + wk] = (short)hh;
        Wl[p][(wnc + q) * 44 + wk] = (short)f2bf(wv[q] - bf2f(hh));
      }
    }
    const bf8v ahc = ah, alc = al;
    if (it < 124) {  // issue next-iter global loads (overlap with MFMA below)
      const int k0 = (it + 1) * 32;
      w0 = *(const float4*)(W + (size_t)(k0 + wk) * ADJN + n0 + wnc);
      w1 = *(const float4*)(W + (size_t)(k0 + wk) * ADJN + n0 + wnc + 4);
      ah = *(const bf8v*)(Ahi + (size_t)arow * DIN + k0 + kb);
      al = *(const bf8v*)(Alo + (size_t)arow * DIN + k0 + kb);
    }
    __syncthreads();  // stores to buf p visible; buf p readers (it-2) drained at sync(it-1)
#pragma unroll
    for (int j = 0; j < 4; ++j) {
      const int bc = (j * 16 + (lane & 15)) * 44 + kb;
      BF8U bh, bl;
      bh.h[0] = *(const bf4v*)(Wh[p] + bc); bh.h[1] = *(const bf4v*)(Wh[p] + bc + 4);
      bl.h[0] = *(const bf4v*)(Wl[p] + bc); bl.h[1] = *(const bf4v*)(Wl[p] + bc + 4);
      acc[j] = __builtin_amdgcn_mfma_f32_16x16x32_bf16(ahc, bh.v, acc[j], 0, 0, 0);
      acc[j] = __builtin_amdgcn_mfma_f32_16x16x32_bf16(ahc, bl.v, acc[j], 0, 0, 0);
      acc[j] = __builtin_amdgcn_mfma_f32_16x16x32_bf16(alc, bh.v, acc[j], 0, 0, 0);
    }
  }
#pragma unroll
  for (int j = 0; j < 4; ++j) {
    const int col = n0 + j * 16 + (lane & 15);
    const float bb = bias[col];
#pragma unroll
    for (int vv = 0; vv < 4; ++vv) {
      const int row = wave * 16 + (lane >> 4) * 4 + vv;
      float x = acc[j][vv] + bb;
      adj[(size_t)row * ADJN + col] = 1.0f / (1.0f + __expf(-x));
    }
  }
}

// ---------------------------------------------------------------------------
// K2: adjS = 0.5*(adj + adj^T) per graph
// ---------------------------------------------------------------------------
__global__ void symmetrize(const float* __restrict__ adj, float* __restrict__ adjS) {
  const int idx = blockIdx.x * 256 + threadIdx.x;  // 2,560,000 exact
  const int b = idx / ADJN, r = idx % ADJN;
  const int i = r / NN, j = r % NN;
  adjS[idx] = 0.5f * (adj[(size_t)b * ADJN + i * NN + j] + adj[(size_t)b * ADJN + j * NN + i]);
}

// ---------------------------------------------------------------------------
// K2b: per-row mean / std(ddof=1)
// ---------------------------------------------------------------------------
__global__ __launch_bounds__(256) void rowstats(const float* __restrict__ adjS,
                                                float* __restrict__ meanv,
                                                float* __restrict__ stdv) {
  const int row = blockIdx.x * 4 + (threadIdx.x >> 6);
  const int lane = threadIdx.x & 63;
  const float* r = adjS + (size_t)row * NN;
  float s = 0.f, q = 0.f;
#pragma unroll
  for (int k = 0; k < 4; ++k) {
    int i = k * 64 + lane;
    if (i < NN) { float v = r[i]; s += v; q += v * v; }
  }
#pragma unroll
  for (int off = 32; off > 0; off >>= 1) { s += __shfl_xor(s, off); q += __shfl_xor(q, off); }
  if (lane == 0) {
    float m = s * (1.0f / 200.0f);
    float var = (q - 200.0f * m * m) * (1.0f / 199.0f);
    var = fmaxf(var, 0.f);
    meanv[row] = m;
    stdv[row] = sqrtf(var) + 1e-6f;
  }
}

// ---------------------------------------------------------------------------
// K3: exact 10000th-largest per graph via fp32-bit radix select
// ---------------------------------------------------------------------------
__global__ __launch_bounds__(256) void radix_select(const float* __restrict__ adjS,
                                                    float* __restrict__ tau) {
  __shared__ unsigned hist[2048];
  __shared__ unsigned s_pref, s_cA;
  const int g = blockIdx.x, t = threadIdx.x;
  const float* v = adjS + (size_t)g * ADJN;
  unsigned prefix = 0, pmask = 0, cA = 0;
  const int shifts[3] = {20, 9, 0};
  const int widths[3] = {2048, 2048, 512};
  for (int pass = 0; pass < 3; ++pass) {
    const int nb = widths[pass], sh = shifts[pass];
    for (int i = t; i < nb; i += 256) hist[i] = 0u;
    __syncthreads();
    for (int e = t; e < ADJN; e += 256) {
      unsigned u = __float_as_uint(v[e]);
      if ((u & pmask) == prefix) atomicAdd(&hist[(u >> sh) & (nb - 1)], 1u);
    }
    __syncthreads();
    if (t == 0) {
      unsigned cum = cA; int b = nb - 1;
      for (; b > 0; --b) { unsigned hb = hist[b]; if (cum + hb >= 10000u) break; cum += hb; }
      s_pref = prefix | ((unsigned)b << sh);
      s_cA = cum;
    }
    __syncthreads();
    prefix = s_pref; cA = s_cA;
    pmask |= (unsigned)(widths[pass] - 1) << sh;
    __syncthreads();
  }
  if (t == 0) tau[g] = __uint_as_float(prefix);
}

// ---------------------------------------------------------------------------
// K4: [mean,std] -> MLP(2->8 gelu ->16) -> LayerNorm(16) -> x0 f32
// ---------------------------------------------------------------------------
__global__ __launch_bounds__(256) void node_mlp(
    const float* __restrict__ meanv, const float* __restrict__ stdv,
    const float* __restrict__ feW1, const float* __restrict__ feb1,
    const float* __restrict__ feW2, const float* __restrict__ feb2,
    const float* __restrict__ ln_g, const float* __restrict__ ln_b,
    float* __restrict__ x0) {
  const int n = blockIdx.x * 256 + threadIdx.x;  // 12800 exact
  const float mu = meanv[n], sd = stdv[n];
  float h1[8];
#pragma unroll
  for (int o = 0; o < 8; ++o) h1[o] = gelu_f(mu * feW1[o] + sd * feW1[8 + o] + feb1[o]);
  float h2[16]; float s = 0.f;
#pragma unroll
  for (int o = 0; o < 16; ++o) {
    float a = feb2[o];
#pragma unroll
    for (int k = 0; k < 8; ++k) a += h1[k] * feW2[k * 16 + o];
    h2[o] = a; s += a;
  }
  s *= (1.0f / 16.0f);
  float var = 0.f;
#pragma unroll
  for (int o = 0; o < 16; ++o) { float d = h2[o] - s; var += d * d; }
  var *= (1.0f / 16.0f);
  const float inv = 1.0f / sqrtf(var + 1e-5f);
#pragma unroll
  for (int o = 0; o < 16; ++o) x0[(size_t)n * 16 + o] = (h2[o] - s) * inv * ln_g[o] + ln_b[o];
}

// ---------------------------------------------------------------------------
// K5: per-dst neighbor lists (row scan of symmetric adjS), ballot-compacted
// ---------------------------------------------------------------------------
__global__ __launch_bounds__(256) void build_lists(
    const float* __restrict__ adjS, const float* __restrict__ tau,
    int* __restrict__ cnt1, int* __restrict__ cnt2,
    unsigned char* __restrict__ list1, unsigned char* __restrict__ list2) {
  const int g = blockIdx.x;
  const float tv = tau[g];
  const int t = threadIdx.x, wave = t >> 6, lane = t & 63;
  for (int j = wave; j < NN; j += 4) {
    const float* row = adjS + (size_t)g * ADJN + (size_t)j * NN;
    unsigned char* l1 = list1 + ((size_t)g * NN + j) * NN;
    unsigned char* l2 = list2 + ((size_t)g * NN + j) * NN;
    int c1 = 0, c2 = 0;
#pragma unroll
    for (int r = 0; r < 4; ++r) {
      int i = r * 64 + lane;
      bool p1 = false, p2 = false;
      if (i < NN) { float v = row[i]; p1 = (v >= tv); p2 = p1 && (i != j); }
      unsigned long long b1 = __ballot(p1);
      unsigned long long b2 = __ballot(p2);
      unsigned long long below = (lane == 0) ? 0ull : ((~0ull) >> (64 - lane));
      if (p1) l1[c1 + __popcll(b1 & below)] = (unsigned char)i;
      if (p2) l2[c2 + __popcll(b2 & below)] = (unsigned char)i;
      c1 += (int)__popcll(b1); c2 += (int)__popcll(b2);
    }
    if (lane == 0) {
      l2[c2] = (unsigned char)j;
      cnt1[g * NN + j] = c1;
      cnt2[g * NN + j] = c2 + 1;
    }
  }
}

// ---------------------------------------------------------------------------
// K6: xl1/xr1 = x0[12800,16] @ W[16,1024] + b  (K=16, VALU), out f16
// ---------------------------------------------------------------------------
__global__ __launch_bounds__(256) void lin16(const float* __restrict__ x0,
                                             const float* __restrict__ W,
                                             const float* __restrict__ bias,
                                             _Float16* __restrict__ out) {
  const int idx = blockIdx.x * 256 + threadIdx.x;  // 12800*128
  const int n = idx >> 7, oc = (idx & 127) * 8;
  float xr[16];
#pragma unroll
  for (int k = 0; k < 4; ++k) {
    float4 v = *(const float4*)(x0 + (size_t)n * 16 + k * 4);
    xr[4 * k] = v.x; xr[4 * k + 1] = v.y; xr[4 * k + 2] = v.z; xr[4 * k + 3] = v.w;
  }
  float acc[8] = {};
#pragma unroll
  for (int k = 0; k < 16; ++k) {
    float4 w0 = *(const float4*)(W + (size_t)k * 1024 + oc);
    float4 w1 = *(const float4*)(W + (size_t)k * 1024 + oc + 4);
    acc[0] += xr[k] * w0.x; acc[1] += xr[k] * w0.y;
    acc[2] += xr[k] * w0.z; acc[3] += xr[k] * w0.w;
    acc[4] += xr[k] * w1.x; acc[5] += xr[k] * w1.y;
    acc[6] += xr[k] * w1.z; acc[7] += xr[k] * w1.w;
  }
  f16x8 o;
#pragma unroll
  for (int q = 0; q < 8; ++q) o[q] = (_Float16)(acc[q] + bias[oc + q]);
  *(f16x8*)(out + (size_t)n * 1024 + oc) = o;
}

// ---------------------------------------------------------------------------
// K9: NT-GEMM: C[12800,Nhalf] = A[12800,1024]f16 @ Bt[Nhalf,1024]f16 + bias
// 128x128 tile, BK=64, double-buffered LDS, XOR-swizzled, 1 sync/iter.
// ---------------------------------------------------------------------------
__global__ __launch_bounds__(256, 2) void gemm_nt(
    const _Float16* __restrict__ A,
    const _Float16* __restrict__ Bt0, const _Float16* __restrict__ Bt1,
    const float* __restrict__ b0, const float* __restrict__ b1,
    _Float16* __restrict__ out0, _Float16* __restrict__ out1,
    int Nhalf, int tilesPerHalf) {
  __shared__ _Float16 As[2][128 * 64];
  __shared__ _Float16 Bs[2][128 * 64];
  const int mbase = blockIdx.x * 128;
  const int hsel = blockIdx.y / tilesPerHalf;
  const int ncol0 = (blockIdx.y % tilesPerHalf) * 128;
  const _Float16* Bt = hsel ? Bt1 : Bt0;
  const float* bias = hsel ? b1 : b0;
  _Float16* out = hsel ? out1 : out0;
  const int t = threadIdx.x, wave = t >> 6, lane = t & 63;
  const int wm = wave >> 1, wn = wave & 1;
  f32x4 acc[4][4] = {};
  int crow[4], gco[4], sto[4];
#pragma unroll
  for (int q = 0; q < 4; ++q) {
    const int c = q * 256 + t;
    crow[q] = c >> 3;
    const int sl = c & 7;
    gco[q] = sl * 8;
    sto[q] = crow[q] * 64 + ((sl ^ (crow[q] & 7)) << 3);
  }
  f16x8 ra[4], rb[4];
#pragma unroll
  for (int q = 0; q < 4; ++q) {
    ra[q] = *(const f16x8*)(A + (size_t)(mbase + crow[q]) * 1024 + gco[q]);
    rb[q] = *(const f16x8*)(Bt + (size_t)(ncol0 + crow[q]) * 1024 + gco[q]);
  }
  for (int kt = 0; kt < 16; ++kt) {
    const int p = kt & 1;
#pragma unroll
    for (int q = 0; q < 4; ++q) {
      *(f16x8*)(As[p] + sto[q]) = ra[q];
      *(f16x8*)(Bs[p] + sto[q]) = rb[q];
    }
    if (kt < 15) {
      const int k0 = (kt + 1) * 64;
#pragma unroll
      for (int q = 0; q < 4; ++q) {
        ra[q] = *(const f16x8*)(A + (size_t)(mbase + crow[q]) * 1024 + k0 + gco[q]);
        rb[q] = *(const f16x8*)(Bt + (size_t)(ncol0 + crow[q]) * 1024 + k0 + gco[q]);
      }
    }
    __syncthreads();
#pragma unroll
    for (int ks = 0; ks < 2; ++ks) {
      F16X8U af[4], bfv[4];
#pragma unroll
      for (int m = 0; m < 4; ++m) {
        const int row = wm * 64 + m * 16 + (lane & 15);
        const int kk = ks * 32 + (lane >> 4) * 8;
        af[m].v = *(const f16x8*)(As[p] + row * 64 + (kk ^ ((row & 7) << 3)));
      }
#pragma unroll
      for (int j = 0; j < 4; ++j) {
        const int row = wn * 64 + j * 16 + (lane & 15);
        const int kk = ks * 32 + (lane >> 4) * 8;
        bfv[j].v = *(const f16x8*)(Bs[p] + row * 64 + (kk ^ ((row & 7) << 3)));
      }
#pragma unroll
      for (int j = 0; j < 4; ++j)
#pragma unroll
        for (int m = 0; m < 4; ++m)
          acc[m][j] = __builtin_amdgcn_mfma_f32_16x16x32_f16(af[m].v, bfv[j].v, acc[m][j], 0, 0, 0);
    }
  }
#pragma unroll
  for (int j = 0; j < 4; ++j) {
    const int col = ncol0 + wn * 64 + j * 16 + (lane & 15);
    const float bb = bias[col];
#pragma unroll
    for (int m = 0; m < 4; ++m) {
#pragma unroll
      for (int vv = 0; vv < 4; ++vv) {
        const int row = mbase + wm * 64 + m * 16 + (lane >> 4) * 4 + vv;
        out[(size_t)row * Nhalf + col] = (_Float16)(acc[m][j][vv] + bb);
      }
    }
  }
}

// ---------------------------------------------------------------------------
// K7: GATv2 layer (L1: C=128,H=8; L2: C=256,H=4 in 2 dst-ranges)
// ---------------------------------------------------------------------------
template <int C, int NR, int NSPLIT, int HC>
__global__ __launch_bounds__(512, 2) void gat_layer(
    const _Float16* __restrict__ xlb, const _Float16* __restrict__ xrb,
    const float* __restrict__ attw, const float* __restrict__ biasw,
    const int* __restrict__ cnts, const unsigned char* __restrict__ lists,
    _Float16* __restrict__ outb) {
  extern __shared__ char smem[];
  constexpr int XLB = 200 * C * 2;
  constexpr int XRB = NR * C * 2;
  _Float16* xr_s = (_Float16*)(smem + XLB);
  float* aw = (float*)(smem + XLB + XRB);
  unsigned char* ll = (unsigned char*)(smem + XLB + XRB + 8 * 200 * 4);
  const int g = blockIdx.x;
  const int hd = blockIdx.y / NSPLIT;
  const int range = blockIdx.y % NSPLIT;
  const int r0 = range * NR;
  const int t = threadIdx.x, wave = t >> 6, lane = t & 63;

  for (int ch = t; ch < 200 * (C / 8); ch += 512) {
    const int node = ch / (C / 8), cc = (ch % (C / 8)) * 8;
    f16x8 v = *(const f16x8*)(xlb + (size_t)(g * 200 + node) * HC + hd * C + cc);
    *(f16x8*)(smem + (((node * C + cc) * 2) ^ ((node & 15) << 4))) = v;
  }
  for (int ch = t; ch < NR * (C / 8); ch += 512) {
    const int node = ch / (C / 8), cc = (ch % (C / 8)) * 8;
    *(f16x8*)(xr_s + node * C + cc) =
        *(const f16x8*)(xrb + (size_t)(g * 200 + r0 + node) * HC + hd * C + cc);
  }
  unsigned attr[C / 2];
#pragma unroll
  for (int i = 0; i < C / 2; ++i) {
    f16x2 a;
    a[0] = (_Float16)attw[hd * C + 2 * i];
    a[1] = (_Float16)attw[hd * C + 2 * i + 1];
    attr[i] = __builtin_bit_cast(unsigned, a);
  }
  __syncthreads();

  for (int jj = wave; jj < NR; jj += 8) {
    const int j = r0 + jj;
    const int gn = g * 200 + j;
    const int cnt = cnts[gn];
    const unsigned char* lst = lists + (size_t)gn * NN;
    float lg[4] = {-INFINITY, -INFINITY, -INFINITY, -INFINITY};
#pragma unroll
    for (int r = 0; r < 4; ++r) {
      const int e = (r << 6) + lane;
      if (e < cnt) {
        const int s = lst[e];
        ll[wave * 200 + e] = (unsigned char)s;
        const int swz = (s & 15) << 4;
        float accv[4] = {0.f, 0.f, 0.f, 0.f};
#pragma unroll
        for (int c0 = 0; c0 < C; c0 += 16) {
          const int ai = ((c0 >> 4) & 1) * 2;
          F16X8U xa, xb, raa, rbb;
          xa.v = *(const f16x8*)(smem + (((s * C + c0) * 2) ^ swz));
          xb.v = *(const f16x8*)(smem + (((s * C + c0 + 8) * 2) ^ swz));
          raa.v = *(const f16x8*)(xr_s + jj * C + c0);
          rbb.v = *(const f16x8*)(xr_s + jj * C + c0 + 8);
#pragma unroll
          for (int pq = 0; pq < 4; ++pq) {
            f16x2 z = xa.p[pq] + raa.p[pq];
            f16x2 zs = z * (_Float16)0.2f;
            f16x2 m = __builtin_elementwise_max(z, zs);
            accv[ai] = FDOT2(__builtin_bit_cast(f16x2, attr[c0 / 2 + pq]), m, accv[ai]);
            f16x2 z2 = xb.p[pq] + rbb.p[pq];
            f16x2 zs2 = z2 * (_Float16)0.2f;
            f16x2 m2 = __builtin_elementwise_max(z2, zs2);
            accv[ai + 1] = FDOT2(__builtin_bit_cast(f16x2, attr[c0 / 2 + 4 + pq]), m2, accv[ai + 1]);
          }
        }
        lg[r] = (accv[0] + accv[1]) + (accv[2] + accv[3]);
      }
    }
    float mloc = fmaxf(fmaxf(lg[0], lg[1]), fmaxf(lg[2], lg[3]));
#pragma unroll
    for (int off = 32; off > 0; off >>= 1) mloc = fmaxf(mloc, __shfl_xor(mloc, off));
    float ex[4]; float ps = 0.f;
#pragma unroll
    for (int r = 0; r < 4; ++r) { ex[r] = __expf(lg[r] - mloc); ps += ex[r]; }
#pragma unroll
    for (int off = 32; off > 0; off >>= 1) ps += __shfl_xor(ps, off);
    const float denom = ps + 1e-16f;
#pragma unroll
    for (int r = 0; r < 4; ++r) {
      const int e = (r << 6) + lane;
      if (e < cnt) aw[wave * 200 + e] = ex[r] / denom;
    }
    constexpr int CPL = C / 64;
    float o[CPL] = {};
#pragma unroll 2
    for (int e = 0; e < cnt; ++e) {
      const float a = aw[wave * 200 + e];
      const int s = ll[wave * 200 + e];
      const int swz = (s & 15) << 4;
      if constexpr (CPL == 2) {
        f16x2 xv = *(const f16x2*)(smem + (((s * C + lane * 2) * 2) ^ swz));
        o[0] += a * (float)xv[0];
        o[1] += a * (float)xv[1];
      } else {
        f16x4 xv = *(const f16x4*)(smem + (((s * C + lane * 4) * 2) ^ swz));
        o[0] += a * (float)xv[0];
        o[1] += a * (float)xv[1];
        o[2] += a * (float)xv[2];
        o[3] += a * (float)xv[3];
      }
    }
    const int colb = hd * C + lane * CPL;
#pragma unroll
    for (int q = 0; q < CPL; ++q) {
      float val = o[q] + biasw[colb + q];
      outb[(size_t)gn * HC + colb + q] = (_Float16)gelu_f(val);
    }
  }
}

// ---------------------------------------------------------------------------
// K7-L3: GATv2 (H=1, C=512) channel-chunked; fused bias+gelu+partial mean pool
// ---------------------------------------------------------------------------
__global__ __launch_bounds__(512, 2) void gat_l3(
    const _Float16* __restrict__ xlb, const _Float16* __restrict__ xrb,
    const float* __restrict__ attw, const float* __restrict__ biasw,
    const int* __restrict__ cnts, const unsigned char* __restrict__ lists,
    float* __restrict__ psum) {
  extern __shared__ char smem[];
  _Float16* xr_s = (_Float16*)(smem + 51200);
  float* plog = (float*)(smem + 64000);
  unsigned char* ll = (unsigned char*)(smem + 104000);
  const int g = blockIdx.x, range = blockIdx.y, r0 = range * 50;
  const int t = threadIdx.x, wave = t >> 6, lane = t & 63;

  for (int chunk = 0; chunk < 4; ++chunk) {
    if (chunk) __syncthreads();
    for (int ch = t; ch < 200 * 16; ch += 512) {
      const int node = ch >> 4, cc = (ch & 15) * 8;
      *(f16x8*)(smem + (((node * 128 + cc) * 2) ^ ((node & 15) << 4))) =
          *(const f16x8*)(xlb + (size_t)(g * 200 + node) * 512 + chunk * 128 + cc);
    }
    for (int ch = t; ch < 50 * 16; ch += 512) {
      const int node = ch >> 4, cc = (ch & 15) * 8;
      *(f16x8*)(xr_s + node * 128 + cc) =
          *(const f16x8*)(xrb + (size_t)(g * 200 + r0 + node) * 512 + chunk * 128 + cc);
    }
    unsigned attr[64];
#pragma unroll
    for (int i = 0; i < 64; ++i) {
      f16x2 a;
      a[0] = (_Float16)attw[chunk * 128 + 2 * i];
      a[1] = (_Float16)attw[chunk * 128 + 2 * i + 1];
      attr[i] = __builtin_bit_cast(unsigned, a);
    }
    __syncthreads();
    for (int jj = wave; jj < 50; jj += 8) {
      const int gn = g * 200 + r0 + jj;
      const int cnt = cnts[gn];
      const unsigned char* lst = lists + (size_t)gn * NN;
#pragma unroll
      for (int r = 0; r < 4; ++r) {
        const int e = (r << 6) + lane;
        if (e < cnt) {
          const int s = lst[e];
          if (chunk == 0) ll[wave * 200 + e] = (unsigned char)s;
          const int swz = (s & 15) << 4;
          float accv[4] = {0.f, 0.f, 0.f, 0.f};
#pragma unroll
          for (int c0 = 0; c0 < 128; c0 += 16) {
            const int ai = ((c0 >> 4) & 1) * 2;
            F16X8U xa, xb, raa, rbb;
            xa.v = *(const f16x8*)(smem + (((s * 128 + c0) * 2) ^ swz));
            xb.v = *(const f16x8*)(smem + (((s * 128 + c0 + 8) * 2) ^ swz));
            raa.v = *(const f16x8*)(xr_s + jj * 128 + c0);
            rbb.v = *(const f16x8*)(xr_s + jj * 128 + c0 + 8);
#pragma unroll
            for (int pq = 0; pq < 4; ++pq) {
              f16x2 z = xa.p[pq] + raa.p[pq];
              f16x2 zs = z * (_Float16)0.2f;
              f16x2 m = __builtin_elementwise_max(z, zs);
              accv[ai] = FDOT2(__builtin_bit_cast(f16x2, attr[c0 / 2 + pq]), m, accv[ai]);
              f16x2 z2 = xb.p[pq] + rbb.p[pq];
              f16x2 zs2 = z2 * (_Float16)0.2f;
              f16x2 m2 = __builtin_elementwise_max(z2, zs2);
              accv[ai + 1] = FDOT2(__builtin_bit_cast(f16x2, attr[c0 / 2 + 4 + pq]), m2, accv[ai + 1]);
            }
          }
          const float acc = (accv[0] + accv[1]) + (accv[2] + accv[3]);
          if (chunk == 0) plog[jj * 200 + e] = acc;
          else plog[jj * 200 + e] += acc;
        }
      }
    }
  }
  __syncthreads();
  for (int jj = wave; jj < 50; jj += 8) {
    const int gn = g * 200 + r0 + jj;
    const int cnt = cnts[gn];
    float lg[4] = {-INFINITY, -INFINITY, -INFINITY, -INFINITY};
#pragma unroll
    for (int r = 0; r < 4; ++r) {
      const int e = (r << 6) + lane;
      if (e < cnt) lg[r] = plog[jj * 200 + e];
    }
    float mloc = fmaxf(fmaxf(lg[0], lg[1]), fmaxf(lg[2], lg[3]));
#pragma unroll
    for (int off = 32; off > 0; off >>= 1) mloc = fmaxf(mloc, __shfl_xor(mloc, off));
    float ex[4]; float ps = 0.f;
#pragma unroll
    for (int r = 0; r < 4; ++r) { ex[r] = __expf(lg[r] - mloc); ps += ex[r]; }
#pragma unroll
    for (int off = 32; off > 0; off >>= 1) ps += __shfl_xor(ps, off);
    const float denom = ps + 1e-16f;
#pragma unroll
    for (int r = 0; r < 4; ++r) {
      const int e = (r << 6) + lane;
      if (e < cnt) plog[jj * 200 + e] = ex[r] / denom;
    }
  }
  for (int chunk = 0; chunk < 4; ++chunk) {
    __syncthreads();
    for (int ch = t; ch < 200 * 16; ch += 512) {
      const int node = ch >> 4, cc = (ch & 15) * 8;
      *(f16x8*)(smem + (((node * 128 + cc) * 2) ^ ((node & 15) << 4))) =
          *(const f16x8*)(xlb + (size_t)(g * 200 + node) * 512 + chunk * 128 + cc);
    }
    __syncthreads();
    float p0 = 0.f, p1 = 0.f;
    for (int jj = wave; jj < 50; jj += 8) {
      const int gn = g * 200 + r0 + jj;
      const int cnt = cnts[gn];
      float o0 = 0.f, o1 = 0.f;
#pragma unroll 2
      for (int e = 0; e < cnt; ++e) {
        const float a = plog[jj * 200 + e];
        const int s = ll[wave * 200 + e];
        f16x2 xv = *(const f16x2*)(smem + (((s * 128 + lane * 2) * 2) ^ ((s & 15) << 4)));
        o0 += a * (float)xv[0];
        o1 += a * (float)xv[1];
      }
      const int col = chunk * 128 + lane * 2;
      p0 += gelu_f(o0 + biasw[col]);
      p1 += gelu_f(o1 + biasw[col + 1]);
    }
    const int slot = range * 8 + wave;
    const int col = chunk * 128 + lane * 2;
    psum[((size_t)slot * 64 + g) * 512 + col] = p0;
    psum[((size_t)slot * 64 + g) * 512 + col + 1] = p1;
  }
}

// ---------------------------------------------------------------------------
// K10: d_out[b][c] = (1/200) * sum over 32 partial slots
// ---------------------------------------------------------------------------
__global__ void finalize(const float* __restrict__ psum, float* __restrict__ out) {
  const int idx = blockIdx.x * 256 + threadIdx.x;  // 32768 exact
  float s = 0.f;
#pragma unroll
  for (int k = 0; k < 32; ++k) s += psum[(size_t)k * 32768 + idx];
  out[idx] = s * 0.005f;
}

// ---------------------------------------------------------------------------
extern "C" void kernel_launch(void* const* d_in, const int* in_sizes, int n_in,
                              void* d_out, int out_size, void* d_ws, size_t ws_size,
                              hipStream_t stream) {
  const float* raw_fc = (const float*)d_in[0];
  const float* gbW = (const float*)d_in[1];
  const float* gbb = (const float*)d_in[2];
  const float* feW1 = (const float*)d_in[3];
  const float* feb1 = (const float*)d_in[4];
  const float* feW2 = (const float*)d_in[5];
  const float* feb2 = (const float*)d_in[6];
  const float* ln_g = (const float*)d_in[7];
  const float* ln_b = (const float*)d_in[8];
  const float* W1l = (const float*)d_in[9];  const float* b1l = (const float*)d_in[10];
  const float* W1r = (const float*)d_in[11]; const float* b1r = (const float*)d_in[12];
  const float* att1 = (const float*)d_in[13]; const float* bias1 = (const float*)d_in[14];
  const float* W2l = (const float*)d_in[15]; const float* b2l = (const float*)d_in[16];
  const float* W2r = (const float*)d_in[17]; const float* b2r = (const float*)d_in[18];
  const float* att2 = (const float*)d_in[19]; const float* bias2 = (const float*)d_in[20];
  const float* W3l = (const float*)d_in[21]; const float* b3l = (const float*)d_in[22];
  const float* W3r = (const float*)d_in[23]; const float* b3r = (const float*)d_in[24];
  const float* att3 = (const float*)d_in[25]; const float* bias3 = (const float*)d_in[26];

  if (ws_size < 117000000) return;  // need ~112 MiB scratch

  char* w = (char*)d_ws;
  float* adj   = (float*)(w + 0);
  float* adjS  = (float*)(w + 10240000);
  float* meanv = (float*)(w + 20480000);
  float* stdv  = (float*)(w + 20531200);
  float* tau   = (float*)(w + 20582400);
  float* x0    = (float*)(w + 20582656);
  int* cnt1    = (int*)(w + 21401856);
  int* cnt2    = (int*)(w + 21453056);
  unsigned char* list1 = (unsigned char*)(w + 21504256);
  unsigned char* list2 = (unsigned char*)(w + 24064256);
  _Float16* bufA = (_Float16*)(w + 26624256);   // xl1 / xl2 / xl3
  _Float16* bufB = (_Float16*)(w + 52838656);   // xr1 / xr2 / xr3
  _Float16* bufC = (_Float16*)(w + 79053056);   // x2 / x3
  float* psum = (float*)(w + 105267456);        // 4,194,304 B
  short* Ahi  = (short*)(w + 109461760);
  short* Alo  = (short*)(w + 109973760);
  _Float16* Wt2l = (_Float16*)(w + 110485760);
  _Float16* Wt2r = (_Float16*)(w + 112582912);
  _Float16* Wt3l = (_Float16*)(w + 114680064);
  _Float16* Wt3r = (_Float16*)(w + 115728640);

  const int SMEM_L1 = 110400;
  const int SMEM_L2 = 161600;
  const int SMEM_L3 = 105600;
  hipFuncSetAttribute((const void*)gat_layer<128, 200, 1, 1024>,
                      hipFuncAttributeMaxDynamicSharedMemorySize, SMEM_L1);
  hipFuncSetAttribute((const void*)gat_layer<256, 100, 2, 1024>,
                      hipFuncAttributeMaxDynamicSharedMemorySize, SMEM_L2);
  hipFuncSetAttribute((const void*)gat_l3,
                      hipFuncAttributeMaxDynamicSharedMemorySize, SMEM_L3);

  prep_A<<<1000, 256, 0, stream>>>(raw_fc, Ahi, Alo);
  transp_f16<<<dim3(32, 32), 256, 0, stream>>>(W2l, Wt2l, 1024, 1024);
  transp_f16<<<dim3(32, 32), 256, 0, stream>>>(W2r, Wt2r, 1024, 1024);
  transp_f16<<<dim3(32, 16), 256, 0, stream>>>(W3l, Wt3l, 1024, 512);
  transp_f16<<<dim3(32, 16), 256, 0, stream>>>(W3r, Wt3r, 1024, 512);
  build_adj<<<625, 256, 0, stream>>>(Ahi, Alo, gbW, gbb, adj);
  symmetrize<<<10000, 256, 0, stream>>>(adj, adjS);
  rowstats<<<3200, 256, 0, stream>>>(adjS, meanv, stdv);
  radix_select<<<64, 256, 0, stream>>>(adjS, tau);
  node_mlp<<<50, 256, 0, stream>>>(meanv, stdv, feW1, feb1, feW2, feb2, ln_g, ln_b, x0);
  build_lists<<<64, 256, 0, stream>>>(adjS, tau, cnt1, cnt2, list1, list2);
  lin16<<<6400, 256, 0, stream>>>(x0, W1l, b1l, bufA);
  lin16<<<6400, 256, 0, stream>>>(x0, W1r, b1r, bufB);
  gat_layer<128, 200, 1, 1024><<<dim3(64, 8), 512, SMEM_L1, stream>>>(
      bufA, bufB, att1, bias1, cnt1, list1, bufC);
  gemm_nt<<<dim3(100, 16), 256, 0, stream>>>(bufC, Wt2l, Wt2r, b2l, b2r, bufA, bufB, 1024, 8);
  gat_layer<256, 100, 2, 1024><<<dim3(64, 8), 512, SMEM_L2, stream>>>(
      bufA, bufB, att2, bias2, cnt2, list2, bufC);
  gemm_nt<<<dim3(100, 8), 256, 0, stream>>>(bufC, Wt3l, Wt3r, b3l, b3r, bufA, bufB, 512, 4);
  gat_l3<<<dim3(64, 4), 512, SMEM_L3, stream>>>(bufA, bufB, att3, bias3, cnt2, list2, psum);
  finalize<<<128, 256, 0, stream>>>(psum, (float*)d_out);
}

// Round 3
// 1140.564 us; speedup vs baseline: 1.3044x; 1.1390x over previous
//
#include <hip/hip_runtime.h>
#include <hip/hip_fp16.h>
#include <math.h>
#include <cstdint>
#include <cstddef>

#define NGRAPH 64
#define NN 200
#define ADJN 40000
#define DIN 4000
#define NNODE 12800

typedef float    f32x4 __attribute__((ext_vector_type(4)));
typedef _Float16 f16x8 __attribute__((ext_vector_type(8)));
typedef _Float16 f16x4 __attribute__((ext_vector_type(4)));
typedef _Float16 f16x2 __attribute__((ext_vector_type(2)));
typedef short    bf8v  __attribute__((ext_vector_type(8)));
typedef short    bf4v  __attribute__((ext_vector_type(4)));

union BF8U  { bf8v v; bf4v h[2]; };
union F16X8U{ f16x8 v; f16x4 h[2]; f16x2 p[4]; };

__device__ __forceinline__ unsigned short f2bf(float f) {
  unsigned u = __float_as_uint(f);
  return (unsigned short)((u + 0x7fffu + ((u >> 16) & 1u)) >> 16);
}
__device__ __forceinline__ float bf2f(unsigned short s) {
  return __uint_as_float(((unsigned)s) << 16);
}
__device__ __forceinline__ float gelu_f(float x) {
  return x * 0.5f * (1.0f + erff(x * 0.70710678118654752f));
}

#if defined(__has_builtin)
#if __has_builtin(__builtin_amdgcn_fdot2)
#define FDOT2(a, b, c) __builtin_amdgcn_fdot2((a), (b), (c), false)
#endif
#endif
#ifndef FDOT2
#define FDOT2(a, b, c) ((c) + (float)(a)[0] * (float)(b)[0] + (float)(a)[1] * (float)(b)[1])
#endif

// ---------------------------------------------------------------------------
// K0: raw_fc -> hi/lo bf16 split
// ---------------------------------------------------------------------------
__global__ __launch_bounds__(256) void prep_A(const float* __restrict__ A,
                                              short* __restrict__ Ahi,
                                              short* __restrict__ Alo) {
  const int i = blockIdx.x * 256 + threadIdx.x;  // 256000 exact
  const float v = A[i];
  const unsigned short h = f2bf(v);
  Ahi[i] = (short)h;
  Alo[i] = (short)f2bf(v - bf2f(h));
}

// ---------------------------------------------------------------------------
// K0b: all 4 GEMM weights: W[k][n] f32 -> Wt[n][k] f16 (fused, blockIdx.z)
// ---------------------------------------------------------------------------
__global__ __launch_bounds__(256) void transp_all(
    const float* __restrict__ W2l, const float* __restrict__ W2r,
    const float* __restrict__ W3l, const float* __restrict__ W3r,
    _Float16* __restrict__ T2l, _Float16* __restrict__ T2r,
    _Float16* __restrict__ T3l, _Float16* __restrict__ T3r) {
  __shared__ float tile[32][33];
  const int z = blockIdx.z;
  if (z >= 2 && blockIdx.y >= 16) return;
  const float* src = (z == 0) ? W2l : (z == 1) ? W2r : (z == 2) ? W3l : W3r;
  _Float16* dst = (z == 0) ? T2l : (z == 1) ? T2r : (z == 2) ? T3l : T3r;
  const int N = (z < 2) ? 1024 : 512;
  const int K = 1024;
  const int bk = blockIdx.x * 32, bn = blockIdx.y * 32;
  const int tx = threadIdx.x & 31, ty = threadIdx.x >> 5;
#pragma unroll
  for (int r = 0; r < 32; r += 8) tile[ty + r][tx] = src[(size_t)(bk + ty + r) * N + bn + tx];
  __syncthreads();
#pragma unroll
  for (int r = 0; r < 32; r += 8)
    dst[(size_t)(bn + ty + r) * K + bk + tx] = (_Float16)tile[tx][ty + r];
}

// ---------------------------------------------------------------------------
// K1: adj = sigmoid(raw_fc @ gbW + gbb); split-bf16 MFMA, 2-deep prefetch
// ---------------------------------------------------------------------------
#define BA_STEP(P, IT, W0, W1, AH, AL)                                          \
  {                                                                             \
    float wv[8] = {W0.x, W0.y, W0.z, W0.w, W1.x, W1.y, W1.z, W1.w};             \
    _Pragma("unroll") for (int q = 0; q < 8; ++q) {                             \
      unsigned short hh = f2bf(wv[q]);                                          \
      Wh[P][(wnc + q) * 44 + wk] = (short)hh;                                   \
      Wl[P][(wnc + q) * 44 + wk] = (short)f2bf(wv[q] - bf2f(hh));               \
    }                                                                           \
    const bf8v ahc = AH, alc = AL;                                              \
    if ((IT) + 2 < 125) {                                                       \
      const int k0 = ((IT) + 2) * 32;                                           \
      W0 = *(const float4*)(W + (size_t)(k0 + wk) * ADJN + n0 + wnc);           \
      W1 = *(const float4*)(W + (size_t)(k0 + wk) * ADJN + n0 + wnc + 4);       \
      AH = *(const bf8v*)(Ahi + (size_t)arow * DIN + k0 + kb);                  \
      AL = *(const bf8v*)(Alo + (size_t)arow * DIN + k0 + kb);                  \
    }                                                                           \
    __syncthreads();                                                            \
    _Pragma("unroll") for (int j = 0; j < 4; ++j) {                             \
      const int bc = (j * 16 + (lane & 15)) * 44 + kb;                          \
      BF8U bh, bl;                                                              \
      bh.h[0] = *(const bf4v*)(Wh[P] + bc);                                     \
      bh.h[1] = *(const bf4v*)(Wh[P] + bc + 4);                                 \
      bl.h[0] = *(const bf4v*)(Wl[P] + bc);                                     \
      bl.h[1] = *(const bf4v*)(Wl[P] + bc + 4);                                 \
      acc[j] = __builtin_amdgcn_mfma_f32_16x16x32_bf16(ahc, bh.v, acc[j], 0, 0, 0); \
      acc[j] = __builtin_amdgcn_mfma_f32_16x16x32_bf16(ahc, bl.v, acc[j], 0, 0, 0); \
      acc[j] = __builtin_amdgcn_mfma_f32_16x16x32_bf16(alc, bh.v, acc[j], 0, 0, 0); \
    }                                                                           \
  }

__global__ __launch_bounds__(256) void build_adj(
    const short* __restrict__ Ahi, const short* __restrict__ Alo,
    const float* __restrict__ W, const float* __restrict__ bias,
    float* __restrict__ adj) {
  __shared__ short Wh[2][64 * 44], Wl[2][64 * 44];
  const int t = threadIdx.x, wave = t >> 6, lane = t & 63;
  const int n0 = blockIdx.x * 64;
  const int wk = t >> 3, wnc = (t & 7) * 8;
  const int kb = (lane >> 4) * 8;
  const int arow = wave * 16 + (lane & 15);
  f32x4 acc[4] = {};
  // prologue: tiles 0 (set a) and 1 (set b)
  float4 w0a = *(const float4*)(W + (size_t)wk * ADJN + n0 + wnc);
  float4 w1a = *(const float4*)(W + (size_t)wk * ADJN + n0 + wnc + 4);
  bf8v aha = *(const bf8v*)(Ahi + (size_t)arow * DIN + kb);
  bf8v ala = *(const bf8v*)(Alo + (size_t)arow * DIN + kb);
  float4 w0b = *(const float4*)(W + (size_t)(32 + wk) * ADJN + n0 + wnc);
  float4 w1b = *(const float4*)(W + (size_t)(32 + wk) * ADJN + n0 + wnc + 4);
  bf8v ahb = *(const bf8v*)(Ahi + (size_t)arow * DIN + 32 + kb);
  bf8v alb = *(const bf8v*)(Alo + (size_t)arow * DIN + 32 + kb);
  for (int it = 0; it < 124; it += 2) {
    BA_STEP(0, it, w0a, w1a, aha, ala)
    BA_STEP(1, it + 1, w0b, w1b, ahb, alb)
  }
  BA_STEP(0, 124, w0a, w1a, aha, ala)
#pragma unroll
  for (int j = 0; j < 4; ++j) {
    const int col = n0 + j * 16 + (lane & 15);
    const float bb = bias[col];
#pragma unroll
    for (int vv = 0; vv < 4; ++vv) {
      const int row = wave * 16 + (lane >> 4) * 4 + vv;
      float x = acc[j][vv] + bb;
      adj[(size_t)row * ADJN + col] = 1.0f / (1.0f + __expf(-x));
    }
  }
}

// ---------------------------------------------------------------------------
// K2: adjS = 0.5*(adj + adj^T), LDS-tiled (coalesced both operands)
// ---------------------------------------------------------------------------
__global__ __launch_bounds__(256) void symmetrize(const float* __restrict__ adj,
                                                  float* __restrict__ adjS) {
  __shared__ float tl[64][65];
  const int g = blockIdx.x;
  const int i0 = (blockIdx.y >> 2) * 64, j0 = (blockIdx.y & 3) * 64;
  const int tx = threadIdx.x & 63, ty = threadIdx.x >> 6;
  const float* ag = adj + (size_t)g * ADJN;
#pragma unroll
  for (int r = 0; r < 64; r += 4) {
    const int jr = j0 + ty + r;
    tl[ty + r][tx] = (jr < NN && i0 + tx < NN) ? ag[jr * NN + i0 + tx] : 0.f;
  }
  __syncthreads();
#pragma unroll
  for (int r = 0; r < 64; r += 4) {
    const int i = i0 + ty + r, j = j0 + tx;
    if (i < NN && j < NN)
      adjS[(size_t)g * ADJN + i * NN + j] = 0.5f * (ag[i * NN + j] + tl[tx][ty + r]);
  }
}

// ---------------------------------------------------------------------------
// K2b: per-row mean / std(ddof=1)
// ---------------------------------------------------------------------------
__global__ __launch_bounds__(256) void rowstats(const float* __restrict__ adjS,
                                                float* __restrict__ meanv,
                                                float* __restrict__ stdv) {
  const int row = blockIdx.x * 4 + (threadIdx.x >> 6);
  const int lane = threadIdx.x & 63;
  const float* r = adjS + (size_t)row * NN;
  float s = 0.f, q = 0.f;
#pragma unroll
  for (int k = 0; k < 4; ++k) {
    int i = k * 64 + lane;
    if (i < NN) { float v = r[i]; s += v; q += v * v; }
  }
#pragma unroll
  for (int off = 32; off > 0; off >>= 1) { s += __shfl_xor(s, off); q += __shfl_xor(q, off); }
  if (lane == 0) {
    float m = s * (1.0f / 200.0f);
    float var = (q - 200.0f * m * m) * (1.0f / 199.0f);
    var = fmaxf(var, 0.f);
    meanv[row] = m;
    stdv[row] = sqrtf(var) + 1e-6f;
  }
}

// ---------------------------------------------------------------------------
// K3: exact 10000th-largest per graph via fp32-bit radix select (512 thr)
// ---------------------------------------------------------------------------
__global__ __launch_bounds__(512) void radix_select(const float* __restrict__ adjS,
                                                    float* __restrict__ tau) {
  __shared__ unsigned hist[2048];
  __shared__ unsigned s_pref, s_cA;
  const int g = blockIdx.x, t = threadIdx.x;
  const float* v = adjS + (size_t)g * ADJN;
  unsigned prefix = 0, pmask = 0, cA = 0;
  const int shifts[3] = {20, 9, 0};
  const int widths[3] = {2048, 2048, 512};
  for (int pass = 0; pass < 3; ++pass) {
    const int nb = widths[pass], sh = shifts[pass];
    for (int i = t; i < nb; i += 512) hist[i] = 0u;
    __syncthreads();
    for (int e = t; e < ADJN; e += 512) {
      unsigned u = __float_as_uint(v[e]);
      if ((u & pmask) == prefix) atomicAdd(&hist[(u >> sh) & (nb - 1)], 1u);
    }
    __syncthreads();
    if (t == 0) {
      unsigned cum = cA; int b = nb - 1;
      for (; b > 0; --b) { unsigned hb = hist[b]; if (cum + hb >= 10000u) break; cum += hb; }
      s_pref = prefix | ((unsigned)b << sh);
      s_cA = cum;
    }
    __syncthreads();
    prefix = s_pref; cA = s_cA;
    pmask |= (unsigned)(widths[pass] - 1) << sh;
    __syncthreads();
  }
  if (t == 0) tau[g] = __uint_as_float(prefix);
}

// ---------------------------------------------------------------------------
// K4: [mean,std] -> MLP(2->8 gelu ->16) -> LayerNorm(16) -> x0 f32
// ---------------------------------------------------------------------------
__global__ __launch_bounds__(256) void node_mlp(
    const float* __restrict__ meanv, const float* __restrict__ stdv,
    const float* __restrict__ feW1, const float* __restrict__ feb1,
    const float* __restrict__ feW2, const float* __restrict__ feb2,
    const float* __restrict__ ln_g, const float* __restrict__ ln_b,
    float* __restrict__ x0) {
  const int n = blockIdx.x * 256 + threadIdx.x;  // 12800 exact
  const float mu = meanv[n], sd = stdv[n];
  float h1[8];
#pragma unroll
  for (int o = 0; o < 8; ++o) h1[o] = gelu_f(mu * feW1[o] + sd * feW1[8 + o] + feb1[o]);
  float h2[16]; float s = 0.f;
#pragma unroll
  for (int o = 0; o < 16; ++o) {
    float a = feb2[o];
#pragma unroll
    for (int k = 0; k < 8; ++k) a += h1[k] * feW2[k * 16 + o];
    h2[o] = a; s += a;
  }
  s *= (1.0f / 16.0f);
  float var = 0.f;
#pragma unroll
  for (int o = 0; o < 16; ++o) { float d = h2[o] - s; var += d * d; }
  var *= (1.0f / 16.0f);
  const float inv = 1.0f / sqrtf(var + 1e-5f);
#pragma unroll
  for (int o = 0; o < 16; ++o) x0[(size_t)n * 16 + o] = (h2[o] - s) * inv * ln_g[o] + ln_b[o];
}

// ---------------------------------------------------------------------------
// K5: per-dst neighbor lists; 4 blocks per graph (50 rows each)
// ---------------------------------------------------------------------------
__global__ __launch_bounds__(256) void build_lists(
    const float* __restrict__ adjS, const float* __restrict__ tau,
    int* __restrict__ cnt1, int* __restrict__ cnt2,
    unsigned char* __restrict__ list1, unsigned char* __restrict__ list2) {
  const int g = blockIdx.x >> 2, quad = blockIdx.x & 3;
  const float tv = tau[g];
  const int t = threadIdx.x, wave = t >> 6, lane = t & 63;
  for (int jj = wave; jj < 50; jj += 4) {
    const int j = quad * 50 + jj;
    const float* row = adjS + (size_t)g * ADJN + (size_t)j * NN;
    unsigned char* l1 = list1 + ((size_t)g * NN + j) * NN;
    unsigned char* l2 = list2 + ((size_t)g * NN + j) * NN;
    int c1 = 0, c2 = 0;
#pragma unroll
    for (int r = 0; r < 4; ++r) {
      int i = r * 64 + lane;
      bool p1 = false, p2 = false;
      if (i < NN) { float v = row[i]; p1 = (v >= tv); p2 = p1 && (i != j); }
      unsigned long long b1 = __ballot(p1);
      unsigned long long b2 = __ballot(p2);
      unsigned long long below = (lane == 0) ? 0ull : ((~0ull) >> (64 - lane));
      if (p1) l1[c1 + __popcll(b1 & below)] = (unsigned char)i;
      if (p2) l2[c2 + __popcll(b2 & below)] = (unsigned char)i;
      c1 += (int)__popcll(b1); c2 += (int)__popcll(b2);
    }
    if (lane == 0) {
      l2[c2] = (unsigned char)j;
      cnt1[g * NN + j] = c1;
      cnt2[g * NN + j] = c2 + 1;
    }
  }
}

// ---------------------------------------------------------------------------
// K6: xl1 AND xr1 = x0[12800,16] @ {W1l,W1r} + b (fused, reads x0 once)
// ---------------------------------------------------------------------------
__global__ __launch_bounds__(256) void lin16_2(
    const float* __restrict__ x0,
    const float* __restrict__ Wl, const float* __restrict__ bl,
    const float* __restrict__ Wr, const float* __restrict__ br,
    _Float16* __restrict__ outl, _Float16* __restrict__ outr) {
  const int idx = blockIdx.x * 256 + threadIdx.x;  // 12800*128
  const int n = idx >> 7, oc = (idx & 127) * 8;
  float xr[16];
#pragma unroll
  for (int k = 0; k < 4; ++k) {
    float4 v = *(const float4*)(x0 + (size_t)n * 16 + k * 4);
    xr[4 * k] = v.x; xr[4 * k + 1] = v.y; xr[4 * k + 2] = v.z; xr[4 * k + 3] = v.w;
  }
  float accl[8] = {}, accr[8] = {};
#pragma unroll
  for (int k = 0; k < 16; ++k) {
    float4 w0 = *(const float4*)(Wl + (size_t)k * 1024 + oc);
    float4 w1 = *(const float4*)(Wl + (size_t)k * 1024 + oc + 4);
    accl[0] += xr[k] * w0.x; accl[1] += xr[k] * w0.y;
    accl[2] += xr[k] * w0.z; accl[3] += xr[k] * w0.w;
    accl[4] += xr[k] * w1.x; accl[5] += xr[k] * w1.y;
    accl[6] += xr[k] * w1.z; accl[7] += xr[k] * w1.w;
    float4 u0 = *(const float4*)(Wr + (size_t)k * 1024 + oc);
    float4 u1 = *(const float4*)(Wr + (size_t)k * 1024 + oc + 4);
    accr[0] += xr[k] * u0.x; accr[1] += xr[k] * u0.y;
    accr[2] += xr[k] * u0.z; accr[3] += xr[k] * u0.w;
    accr[4] += xr[k] * u1.x; accr[5] += xr[k] * u1.y;
    accr[6] += xr[k] * u1.z; accr[7] += xr[k] * u1.w;
  }
  f16x8 ol, orr;
#pragma unroll
  for (int q = 0; q < 8; ++q) {
    ol[q] = (_Float16)(accl[q] + bl[oc + q]);
    orr[q] = (_Float16)(accr[q] + br[oc + q]);
  }
  *(f16x8*)(outl + (size_t)n * 1024 + oc) = ol;
  *(f16x8*)(outr + (size_t)n * 1024 + oc) = orr;
}

// ---------------------------------------------------------------------------
// K9: NT-GEMM 128x128 tile, BK=64, dbuf LDS, XOR-swizzle, 1 sync/iter
// ---------------------------------------------------------------------------
__global__ __launch_bounds__(256, 2) void gemm_nt(
    const _Float16* __restrict__ A,
    const _Float16* __restrict__ Bt0, const _Float16* __restrict__ Bt1,
    const float* __restrict__ b0, const float* __restrict__ b1,
    _Float16* __restrict__ out0, _Float16* __restrict__ out1,
    int Nhalf, int tilesPerHalf) {
  __shared__ _Float16 As[2][128 * 64];
  __shared__ _Float16 Bs[2][128 * 64];
  const int mbase = blockIdx.x * 128;
  const int hsel = blockIdx.y / tilesPerHalf;
  const int ncol0 = (blockIdx.y % tilesPerHalf) * 128;
  const _Float16* Bt = hsel ? Bt1 : Bt0;
  const float* bias = hsel ? b1 : b0;
  _Float16* out = hsel ? out1 : out0;
  const int t = threadIdx.x, wave = t >> 6, lane = t & 63;
  const int wm = wave >> 1, wn = wave & 1;
  f32x4 acc[4][4] = {};
  int crow[4], gco[4], sto[4];
#pragma unroll
  for (int q = 0; q < 4; ++q) {
    const int c = q * 256 + t;
    crow[q] = c >> 3;
    const int sl = c & 7;
    gco[q] = sl * 8;
    sto[q] = crow[q] * 64 + ((sl ^ (crow[q] & 7)) << 3);
  }
  f16x8 ra[4], rb[4];
#pragma unroll
  for (int q = 0; q < 4; ++q) {
    ra[q] = *(const f16x8*)(A + (size_t)(mbase + crow[q]) * 1024 + gco[q]);
    rb[q] = *(const f16x8*)(Bt + (size_t)(ncol0 + crow[q]) * 1024 + gco[q]);
  }
  for (int kt = 0; kt < 16; ++kt) {
    const int p = kt & 1;
#pragma unroll
    for (int q = 0; q < 4; ++q) {
      *(f16x8*)(As[p] + sto[q]) = ra[q];
      *(f16x8*)(Bs[p] + sto[q]) = rb[q];
    }
    if (kt < 15) {
      const int k0 = (kt + 1) * 64;
#pragma unroll
      for (int q = 0; q < 4; ++q) {
        ra[q] = *(const f16x8*)(A + (size_t)(mbase + crow[q]) * 1024 + k0 + gco[q]);
        rb[q] = *(const f16x8*)(Bt + (size_t)(ncol0 + crow[q]) * 1024 + k0 + gco[q]);
      }
    }
    __syncthreads();
#pragma unroll
    for (int ks = 0; ks < 2; ++ks) {
      F16X8U af[4], bfv[4];
#pragma unroll
      for (int m = 0; m < 4; ++m) {
        const int row = wm * 64 + m * 16 + (lane & 15);
        const int kk = ks * 32 + (lane >> 4) * 8;
        af[m].v = *(const f16x8*)(As[p] + row * 64 + (kk ^ ((row & 7) << 3)));
      }
#pragma unroll
      for (int j = 0; j < 4; ++j) {
        const int row = wn * 64 + j * 16 + (lane & 15);
        const int kk = ks * 32 + (lane >> 4) * 8;
        bfv[j].v = *(const f16x8*)(Bs[p] + row * 64 + (kk ^ ((row & 7) << 3)));
      }
#pragma unroll
      for (int j = 0; j < 4; ++j)
#pragma unroll
        for (int m = 0; m < 4; ++m)
          acc[m][j] = __builtin_amdgcn_mfma_f32_16x16x32_f16(af[m].v, bfv[j].v, acc[m][j], 0, 0, 0);
    }
  }
#pragma unroll
  for (int j = 0; j < 4; ++j) {
    const int col = ncol0 + wn * 64 + j * 16 + (lane & 15);
    const float bb = bias[col];
#pragma unroll
    for (int m = 0; m < 4; ++m) {
#pragma unroll
      for (int vv = 0; vv < 4; ++vv) {
        const int row = mbase + wm * 64 + m * 16 + (lane >> 4) * 4 + vv;
        out[(size_t)row * Nhalf + col] = (_Float16)(acc[m][j][vv] + bb);
      }
    }
  }
}

// ---------------------------------------------------------------------------
// K7: GATv2 layer, 1024 threads (16 waves), att in LDS, alpha f16 in LDS
// ---------------------------------------------------------------------------
template <int C, int NR, int NSPLIT, int HC, bool USE_LL>
__global__ __launch_bounds__(1024, 4) void gat_layer(
    const _Float16* __restrict__ xlb, const _Float16* __restrict__ xrb,
    const float* __restrict__ attw, const float* __restrict__ biasw,
    const int* __restrict__ cnts, const unsigned char* __restrict__ lists,
    _Float16* __restrict__ outb) {
  extern __shared__ char smem[];
  constexpr int XLB = 200 * C * 2;
  constexpr int XRB = NR * C * 2;
  constexpr int AWB = 16 * 200 * 2;
  _Float16* xr_s = (_Float16*)(smem + XLB);
  _Float16* aw = (_Float16*)(smem + XLB + XRB);
  unsigned char* ll = (unsigned char*)(smem + XLB + XRB + AWB);
  unsigned* att_s = (unsigned*)(smem + XLB + XRB + AWB + (USE_LL ? 3200 : 0));
  const int g = blockIdx.x;
  const int hd = blockIdx.y / NSPLIT;
  const int range = blockIdx.y % NSPLIT;
  const int r0 = range * NR;
  const int t = threadIdx.x, wave = t >> 6, lane = t & 63;

  for (int ch = t; ch < 200 * (C / 8); ch += 1024) {
    const int node = ch / (C / 8), cc = (ch % (C / 8)) * 8;
    f16x8 v = *(const f16x8*)(xlb + (size_t)(g * 200 + node) * HC + hd * C + cc);
    *(f16x8*)(smem + (((node * C + cc) * 2) ^ ((node & 15) << 4))) = v;
  }
  for (int ch = t; ch < NR * (C / 8); ch += 1024) {
    const int node = ch / (C / 8), cc = (ch % (C / 8)) * 8;
    *(f16x8*)(xr_s + node * C + cc) =
        *(const f16x8*)(xrb + (size_t)(g * 200 + r0 + node) * HC + hd * C + cc);
  }
  for (int i = t; i < C / 2; i += 1024) {
    f16x2 a;
    a[0] = (_Float16)attw[hd * C + 2 * i];
    a[1] = (_Float16)attw[hd * C + 2 * i + 1];
    att_s[i] = __builtin_bit_cast(unsigned, a);
  }
  __syncthreads();

  for (int jj = wave; jj < NR; jj += 16) {
    const int j = r0 + jj;
    const int gn = g * 200 + j;
    const int cnt = cnts[gn];
    const unsigned char* lst = lists + (size_t)gn * NN;
    float lg[4] = {-INFINITY, -INFINITY, -INFINITY, -INFINITY};
#pragma unroll
    for (int r = 0; r < 4; ++r) {
      const int e = (r << 6) + lane;
      if (e < cnt) {
        const int s = lst[e];
        if constexpr (USE_LL) ll[wave * 200 + e] = (unsigned char)s;
        const int swz = (s & 15) << 4;
        float accv[4] = {0.f, 0.f, 0.f, 0.f};
#pragma unroll
        for (int c0 = 0; c0 < C; c0 += 16) {
          const int ai = ((c0 >> 4) & 1) * 2;
          const unsigned* ap = att_s + c0 / 2;
          F16X8U xa, xb, raa, rbb;
          xa.v = *(const f16x8*)(smem + (((s * C + c0) * 2) ^ swz));
          xb.v = *(const f16x8*)(smem + (((s * C + c0 + 8) * 2) ^ swz));
          raa.v = *(const f16x8*)(xr_s + jj * C + c0);
          rbb.v = *(const f16x8*)(xr_s + jj * C + c0 + 8);
#pragma unroll
          for (int pq = 0; pq < 4; ++pq) {
            f16x2 z = xa.p[pq] + raa.p[pq];
            f16x2 zs = z * (_Float16)0.2f;
            f16x2 m = __builtin_elementwise_max(z, zs);
            accv[ai] = FDOT2(__builtin_bit_cast(f16x2, ap[pq]), m, accv[ai]);
            f16x2 z2 = xb.p[pq] + rbb.p[pq];
            f16x2 zs2 = z2 * (_Float16)0.2f;
            f16x2 m2 = __builtin_elementwise_max(z2, zs2);
            accv[ai + 1] = FDOT2(__builtin_bit_cast(f16x2, ap[4 + pq]), m2, accv[ai + 1]);
          }
        }
        lg[r] = (accv[0] + accv[1]) + (accv[2] + accv[3]);
      }
    }
    float mloc = fmaxf(fmaxf(lg[0], lg[1]), fmaxf(lg[2], lg[3]));
#pragma unroll
    for (int off = 32; off > 0; off >>= 1) mloc = fmaxf(mloc, __shfl_xor(mloc, off));
    float ex[4]; float ps = 0.f;
#pragma unroll
    for (int r = 0; r < 4; ++r) { ex[r] = __expf(lg[r] - mloc); ps += ex[r]; }
#pragma unroll
    for (int off = 32; off > 0; off >>= 1) ps += __shfl_xor(ps, off);
    const float denom = ps + 1e-16f;
#pragma unroll
    for (int r = 0; r < 4; ++r) {
      const int e = (r << 6) + lane;
      if (e < cnt) aw[wave * 200 + e] = (_Float16)(ex[r] / denom);
    }
    constexpr int CPL = C / 64;
    float o[CPL] = {};
#pragma unroll 2
    for (int e = 0; e < cnt; ++e) {
      const float a = (float)aw[wave * 200 + e];
      int s;
      if constexpr (USE_LL) s = ll[wave * 200 + e]; else s = lst[e];
      const int swz = (s & 15) << 4;
      if constexpr (CPL == 2) {
        f16x2 xv = *(const f16x2*)(smem + (((s * C + lane * 2) * 2) ^ swz));
        o[0] += a * (float)xv[0];
        o[1] += a * (float)xv[1];
      } else {
        f16x4 xv = *(const f16x4*)(smem + (((s * C + lane * 4) * 2) ^ swz));
        o[0] += a * (float)xv[0];
        o[1] += a * (float)xv[1];
        o[2] += a * (float)xv[2];
        o[3] += a * (float)xv[3];
      }
    }
    const int colb = hd * C + lane * CPL;
#pragma unroll
    for (int q = 0; q < CPL; ++q) {
      float val = o[q] + biasw[colb + q];
      outb[(size_t)gn * HC + colb + q] = (_Float16)gelu_f(val);
    }
  }
}

// ---------------------------------------------------------------------------
// K7-L3: GATv2 (H=1,C=512) chunked; 1024 thr; fused bias+gelu+partial pool
// ---------------------------------------------------------------------------
__global__ __launch_bounds__(1024, 4) void gat_l3(
    const _Float16* __restrict__ xlb, const _Float16* __restrict__ xrb,
    const float* __restrict__ attw, const float* __restrict__ biasw,
    const int* __restrict__ cnts, const unsigned char* __restrict__ lists,
    float* __restrict__ psum) {
  extern __shared__ char smem[];
  _Float16* xr_s = (_Float16*)(smem + 51200);
  float* plog = (float*)(smem + 64000);
  unsigned char* ll = (unsigned char*)(smem + 104000);
  unsigned* att_s = (unsigned*)(smem + 107200);
  const int g = blockIdx.x, range = blockIdx.y, r0 = range * 50;
  const int t = threadIdx.x, wave = t >> 6, lane = t & 63;

  for (int chunk = 0; chunk < 4; ++chunk) {
    if (chunk) __syncthreads();
    for (int ch = t; ch < 200 * 16; ch += 1024) {
      const int node = ch >> 4, cc = (ch & 15) * 8;
      *(f16x8*)(smem + (((node * 128 + cc) * 2) ^ ((node & 15) << 4))) =
          *(const f16x8*)(xlb + (size_t)(g * 200 + node) * 512 + chunk * 128 + cc);
    }
    for (int ch = t; ch < 50 * 16; ch += 1024) {
      const int node = ch >> 4, cc = (ch & 15) * 8;
      *(f16x8*)(xr_s + node * 128 + cc) =
          *(const f16x8*)(xrb + (size_t)(g * 200 + r0 + node) * 512 + chunk * 128 + cc);
    }
    for (int i = t; i < 64; i += 1024) {
      f16x2 a;
      a[0] = (_Float16)attw[chunk * 128 + 2 * i];
      a[1] = (_Float16)attw[chunk * 128 + 2 * i + 1];
      att_s[i] = __builtin_bit_cast(unsigned, a);
    }
    __syncthreads();
    for (int jj = wave; jj < 50; jj += 16) {
      const int gn = g * 200 + r0 + jj;
      const int cnt = cnts[gn];
      const unsigned char* lst = lists + (size_t)gn * NN;
#pragma unroll
      for (int r = 0; r < 4; ++r) {
        const int e = (r << 6) + lane;
        if (e < cnt) {
          const int s = lst[e];
          if (chunk == 0) ll[wave * 200 + e] = (unsigned char)s;
          const int swz = (s & 15) << 4;
          float accv[4] = {0.f, 0.f, 0.f, 0.f};
#pragma unroll
          for (int c0 = 0; c0 < 128; c0 += 16) {
            const int ai = ((c0 >> 4) & 1) * 2;
            const unsigned* ap = att_s + c0 / 2;
            F16X8U xa, xb, raa, rbb;
            xa.v = *(const f16x8*)(smem + (((s * 128 + c0) * 2) ^ swz));
            xb.v = *(const f16x8*)(smem + (((s * 128 + c0 + 8) * 2) ^ swz));
            raa.v = *(const f16x8*)(xr_s + jj * 128 + c0);
            rbb.v = *(const f16x8*)(xr_s + jj * 128 + c0 + 8);
#pragma unroll
            for (int pq = 0; pq < 4; ++pq) {
              f16x2 z = xa.p[pq] + raa.p[pq];
              f16x2 zs = z * (_Float16)0.2f;
              f16x2 m = __builtin_elementwise_max(z, zs);
              accv[ai] = FDOT2(__builtin_bit_cast(f16x2, ap[pq]), m, accv[ai]);
              f16x2 z2 = xb.p[pq] + rbb.p[pq];
              f16x2 zs2 = z2 * (_Float16)0.2f;
              f16x2 m2 = __builtin_elementwise_max(z2, zs2);
              accv[ai + 1] = FDOT2(__builtin_bit_cast(f16x2, ap[4 + pq]), m2, accv[ai + 1]);
            }
          }
          const float acc = (accv[0] + accv[1]) + (accv[2] + accv[3]);
          if (chunk == 0) plog[jj * 200 + e] = acc;
          else plog[jj * 200 + e] += acc;
        }
      }
    }
  }
  __syncthreads();
  for (int jj = wave; jj < 50; jj += 16) {
    const int gn = g * 200 + r0 + jj;
    const int cnt = cnts[gn];
    float lg[4] = {-INFINITY, -INFINITY, -INFINITY, -INFINITY};
#pragma unroll
    for (int r = 0; r < 4; ++r) {
      const int e = (r << 6) + lane;
      if (e < cnt) lg[r] = plog[jj * 200 + e];
    }
    float mloc = fmaxf(fmaxf(lg[0], lg[1]), fmaxf(lg[2], lg[3]));
#pragma unroll
    for (int off = 32; off > 0; off >>= 1) mloc = fmaxf(mloc, __shfl_xor(mloc, off));
    float ex[4]; float ps = 0.f;
#pragma unroll
    for (int r = 0; r < 4; ++r) { ex[r] = __expf(lg[r] - mloc); ps += ex[r]; }
#pragma unroll
    for (int off = 32; off > 0; off >>= 1) ps += __shfl_xor(ps, off);
    const float denom = ps + 1e-16f;
#pragma unroll
    for (int r = 0; r < 4; ++r) {
      const int e = (r << 6) + lane;
      if (e < cnt) plog[jj * 200 + e] = ex[r] / denom;
    }
  }
  for (int chunk = 0; chunk < 4; ++chunk) {
    __syncthreads();
    for (int ch = t; ch < 200 * 16; ch += 1024) {
      const int node = ch >> 4, cc = (ch & 15) * 8;
      *(f16x8*)(smem + (((node * 128 + cc) * 2) ^ ((node & 15) << 4))) =
          *(const f16x8*)(xlb + (size_t)(g * 200 + node) * 512 + chunk * 128 + cc);
    }
    __syncthreads();
    float p0 = 0.f, p1 = 0.f;
    for (int jj = wave; jj < 50; jj += 16) {
      const int gn = g * 200 + r0 + jj;
      const int cnt = cnts[gn];
      float o0 = 0.f, o1 = 0.f;
#pragma unroll 2
      for (int e = 0; e < cnt; ++e) {
        const float a = plog[jj * 200 + e];
        const int s = ll[wave * 200 + e];
        f16x2 xv = *(const f16x2*)(smem + (((s * 128 + lane * 2) * 2) ^ ((s & 15) << 4)));
        o0 += a * (float)xv[0];
        o1 += a * (float)xv[1];
      }
      const int col = chunk * 128 + lane * 2;
      p0 += gelu_f(o0 + biasw[col]);
      p1 += gelu_f(o1 + biasw[col + 1]);
    }
    const int slot = range * 16 + wave;
    const int col = chunk * 128 + lane * 2;
    psum[((size_t)slot * 64 + g) * 512 + col] = p0;
    psum[((size_t)slot * 64 + g) * 512 + col + 1] = p1;
  }
}

// ---------------------------------------------------------------------------
// K10: d_out[b][c] = (1/200) * sum over 64 partial slots
// ---------------------------------------------------------------------------
__global__ void finalize(const float* __restrict__ psum, float* __restrict__ out) {
  const int idx = blockIdx.x * 256 + threadIdx.x;  // 32768 exact
  float s = 0.f;
#pragma unroll
  for (int k = 0; k < 64; ++k) s += psum[(size_t)k * 32768 + idx];
  out[idx] = s * 0.005f;
}

// ---------------------------------------------------------------------------
extern "C" void kernel_launch(void* const* d_in, const int* in_sizes, int n_in,
                              void* d_out, int out_size, void* d_ws, size_t ws_size,
                              hipStream_t stream) {
  const float* raw_fc = (const float*)d_in[0];
  const float* gbW = (const float*)d_in[1];
  const float* gbb = (const float*)d_in[2];
  const float* feW1 = (const float*)d_in[3];
  const float* feb1 = (const float*)d_in[4];
  const float* feW2 = (const float*)d_in[5];
  const float* feb2 = (const float*)d_in[6];
  const float* ln_g = (const float*)d_in[7];
  const float* ln_b = (const float*)d_in[8];
  const float* W1l = (const float*)d_in[9];  const float* b1l = (const float*)d_in[10];
  const float* W1r = (const float*)d_in[11]; const float* b1r = (const float*)d_in[12];
  const float* att1 = (const float*)d_in[13]; const float* bias1 = (const float*)d_in[14];
  const float* W2l = (const float*)d_in[15]; const float* b2l = (const float*)d_in[16];
  const float* W2r = (const float*)d_in[17]; const float* b2r = (const float*)d_in[18];
  const float* att2 = (const float*)d_in[19]; const float* bias2 = (const float*)d_in[20];
  const float* W3l = (const float*)d_in[21]; const float* b3l = (const float*)d_in[22];
  const float* W3r = (const float*)d_in[23]; const float* b3r = (const float*)d_in[24];
  const float* att3 = (const float*)d_in[25]; const float* bias3 = (const float*)d_in[26];

  if (ws_size < 121000000) return;  // need ~115.4 MiB scratch

  char* w = (char*)d_ws;
  float* adj   = (float*)(w + 0);
  float* adjS  = (float*)(w + 10240000);
  float* meanv = (float*)(w + 20480000);
  float* stdv  = (float*)(w + 20531200);
  float* tau   = (float*)(w + 20582400);
  float* x0    = (float*)(w + 20582656);
  int* cnt1    = (int*)(w + 21401856);
  int* cnt2    = (int*)(w + 21453056);
  unsigned char* list1 = (unsigned char*)(w + 21504256);
  unsigned char* list2 = (unsigned char*)(w + 24064256);
  _Float16* bufA = (_Float16*)(w + 26624256);   // xl1 / xl2 / xl3
  _Float16* bufB = (_Float16*)(w + 52838656);   // xr1 / xr2 / xr3
  _Float16* bufC = (_Float16*)(w + 79053056);   // x2 / x3
  float* psum = (float*)(w + 105267456);        // 8,388,608 B (64 slots)
  short* Ahi  = (short*)(w + 113656064);
  short* Alo  = (short*)(w + 114168064);
  _Float16* Wt2l = (_Float16*)(w + 114680064);
  _Float16* Wt2r = (_Float16*)(w + 116777216);
  _Float16* Wt3l = (_Float16*)(w + 118874368);
  _Float16* Wt3r = (_Float16*)(w + 119922944);

  const int SMEM_L1 = 112256;   // 51200+51200+6400+3200+256
  const int SMEM_L2 = 160512;   // 102400+51200+6400+512
  const int SMEM_L3 = 107456;   // 51200+12800+40000+3200+256
  hipFuncSetAttribute((const void*)gat_layer<128, 200, 1, 1024, true>,
                      hipFuncAttributeMaxDynamicSharedMemorySize, SMEM_L1);
  hipFuncSetAttribute((const void*)gat_layer<256, 100, 2, 1024, false>,
                      hipFuncAttributeMaxDynamicSharedMemorySize, SMEM_L2);
  hipFuncSetAttribute((const void*)gat_l3,
                      hipFuncAttributeMaxDynamicSharedMemorySize, SMEM_L3);

  prep_A<<<1000, 256, 0, stream>>>(raw_fc, Ahi, Alo);
  transp_all<<<dim3(32, 32, 4), 256, 0, stream>>>(W2l, W2r, W3l, W3r, Wt2l, Wt2r, Wt3l, Wt3r);
  build_adj<<<625, 256, 0, stream>>>(Ahi, Alo, gbW, gbb, adj);
  symmetrize<<<dim3(64, 16), 256, 0, stream>>>(adj, adjS);
  rowstats<<<3200, 256, 0, stream>>>(adjS, meanv, stdv);
  radix_select<<<64, 512, 0, stream>>>(adjS, tau);
  node_mlp<<<50, 256, 0, stream>>>(meanv, stdv, feW1, feb1, feW2, feb2, ln_g, ln_b, x0);
  build_lists<<<256, 256, 0, stream>>>(adjS, tau, cnt1, cnt2, list1, list2);
  lin16_2<<<6400, 256, 0, stream>>>(x0, W1l, b1l, W1r, b1r, bufA, bufB);
  gat_layer<128, 200, 1, 1024, true><<<dim3(64, 8), 1024, SMEM_L1, stream>>>(
      bufA, bufB, att1, bias1, cnt1, list1, bufC);
  gemm_nt<<<dim3(100, 16), 256, 0, stream>>>(bufC, Wt2l, Wt2r, b2l, b2r, bufA, bufB, 1024, 8);
  gat_layer<256, 100, 2, 1024, false><<<dim3(64, 8), 1024, SMEM_L2, stream>>>(
      bufA, bufB, att2, bias2, cnt2, list2, bufC);
  gemm_nt<<<dim3(100, 8), 256, 0, stream>>>(bufC, Wt3l, Wt3r, b3l, b3r, bufA, bufB, 512, 4);
  gat_l3<<<dim3(64, 4), 1024, SMEM_L3, stream>>>(bufA, bufB, att3, bias3, cnt2, list2, psum);
  finalize<<<128, 256, 0, stream>>>(psum, (float*)d_out);
}

// Round 4
// 1008.868 us; speedup vs baseline: 1.4747x; 1.1305x over previous
//
#include <hip/hip_runtime.h>
#include <hip/hip_fp16.h>
#include <math.h>
#include <cstdint>
#include <cstddef>

#define NGRAPH 64
#define NN 200
#define ADJN 40000
#define DIN 4000
#define NNODE 12800

typedef float    f32x4 __attribute__((ext_vector_type(4)));
typedef _Float16 f16x8 __attribute__((ext_vector_type(8)));
typedef _Float16 f16x4 __attribute__((ext_vector_type(4)));
typedef _Float16 f16x2 __attribute__((ext_vector_type(2)));
typedef short    bf8v  __attribute__((ext_vector_type(8)));
typedef short    bf4v  __attribute__((ext_vector_type(4)));

union BF8U  { bf8v v; bf4v h[2]; };
union F16X8U{ f16x8 v; f16x4 h[2]; f16x2 p[4]; };

__device__ __forceinline__ unsigned short f2bf(float f) {
  unsigned u = __float_as_uint(f);
  return (unsigned short)((u + 0x7fffu + ((u >> 16) & 1u)) >> 16);
}
__device__ __forceinline__ float bf2f(unsigned short s) {
  return __uint_as_float(((unsigned)s) << 16);
}
__device__ __forceinline__ float gelu_f(float x) {
  return x * 0.5f * (1.0f + erff(x * 0.70710678118654752f));
}

#if defined(__has_builtin)
#if __has_builtin(__builtin_amdgcn_fdot2)
#define FDOT2(a, b, c) __builtin_amdgcn_fdot2((a), (b), (c), false)
#endif
#endif
#ifndef FDOT2
#define FDOT2(a, b, c) ((c) + (float)(a)[0] * (float)(b)[0] + (float)(a)[1] * (float)(b)[1])
#endif

// ---------------------------------------------------------------------------
// K0: raw_fc -> hi/lo bf16 split
// ---------------------------------------------------------------------------
__global__ __launch_bounds__(256) void prep_A(const float* __restrict__ A,
                                              short* __restrict__ Ahi,
                                              short* __restrict__ Alo) {
  const int i = blockIdx.x * 256 + threadIdx.x;  // 256000 exact
  const float v = A[i];
  const unsigned short h = f2bf(v);
  Ahi[i] = (short)h;
  Alo[i] = (short)f2bf(v - bf2f(h));
}

// ---------------------------------------------------------------------------
// K0b: all 4 GEMM weights: W[k][n] f32 -> Wt[n][k] f16 (fused, blockIdx.z)
// ---------------------------------------------------------------------------
__global__ __launch_bounds__(256) void transp_all(
    const float* __restrict__ W2l, const float* __restrict__ W2r,
    const float* __restrict__ W3l, const float* __restrict__ W3r,
    _Float16* __restrict__ T2l, _Float16* __restrict__ T2r,
    _Float16* __restrict__ T3l, _Float16* __restrict__ T3r) {
  __shared__ float tile[32][33];
  const int z = blockIdx.z;
  if (z >= 2 && blockIdx.y >= 16) return;
  const float* src = (z == 0) ? W2l : (z == 1) ? W2r : (z == 2) ? W3l : W3r;
  _Float16* dst = (z == 0) ? T2l : (z == 1) ? T2r : (z == 2) ? T3l : T3r;
  const int N = (z < 2) ? 1024 : 512;
  const int K = 1024;
  const int bk = blockIdx.x * 32, bn = blockIdx.y * 32;
  const int tx = threadIdx.x & 31, ty = threadIdx.x >> 5;
#pragma unroll
  for (int r = 0; r < 32; r += 8) tile[ty + r][tx] = src[(size_t)(bk + ty + r) * N + bn + tx];
  __syncthreads();
#pragma unroll
  for (int r = 0; r < 32; r += 8)
    dst[(size_t)(bn + ty + r) * K + bk + tx] = (_Float16)tile[tx][ty + r];
}

// ---------------------------------------------------------------------------
// K1: adj = sigmoid(raw_fc @ gbW + gbb); split-bf16 MFMA, 2-deep prefetch
// ---------------------------------------------------------------------------
#define BA_STEP(P, IT, W0, W1, AH, AL)                                          \
  {                                                                             \
    float wv[8] = {W0.x, W0.y, W0.z, W0.w, W1.x, W1.y, W1.z, W1.w};             \
    _Pragma("unroll") for (int q = 0; q < 8; ++q) {                             \
      unsigned short hh = f2bf(wv[q]);                                          \
      Wh[P][(wnc + q) * 44 + wk] = (short)hh;                                   \
      Wl[P][(wnc + q) * 44 + wk] = (short)f2bf(wv[q] - bf2f(hh));               \
    }                                                                           \
    const bf8v ahc = AH, alc = AL;                                              \
    if ((IT) + 2 < 125) {                                                       \
      const int k0 = ((IT) + 2) * 32;                                           \
      W0 = *(const float4*)(W + (size_t)(k0 + wk) * ADJN + n0 + wnc);           \
      W1 = *(const float4*)(W + (size_t)(k0 + wk) * ADJN + n0 + wnc + 4);       \
      AH = *(const bf8v*)(Ahi + (size_t)arow * DIN + k0 + kb);                  \
      AL = *(const bf8v*)(Alo + (size_t)arow * DIN + k0 + kb);                  \
    }                                                                           \
    __syncthreads();                                                            \
    _Pragma("unroll") for (int j = 0; j < 4; ++j) {                             \
      const int bc = (j * 16 + (lane & 15)) * 44 + kb;                          \
      BF8U bh, bl;                                                              \
      bh.h[0] = *(const bf4v*)(Wh[P] + bc);                                     \
      bh.h[1] = *(const bf4v*)(Wh[P] + bc + 4);                                 \
      bl.h[0] = *(const bf4v*)(Wl[P] + bc);                                     \
      bl.h[1] = *(const bf4v*)(Wl[P] + bc + 4);                                 \
      acc[j] = __builtin_amdgcn_mfma_f32_16x16x32_bf16(ahc, bh.v, acc[j], 0, 0, 0); \
      acc[j] = __builtin_amdgcn_mfma_f32_16x16x32_bf16(ahc, bl.v, acc[j], 0, 0, 0); \
      acc[j] = __builtin_amdgcn_mfma_f32_16x16x32_bf16(alc, bh.v, acc[j], 0, 0, 0); \
    }                                                                           \
  }

__global__ __launch_bounds__(256) void build_adj(
    const short* __restrict__ Ahi, const short* __restrict__ Alo,
    const float* __restrict__ W, const float* __restrict__ bias,
    float* __restrict__ adj) {
  __shared__ short Wh[2][64 * 44], Wl[2][64 * 44];
  const int t = threadIdx.x, wave = t >> 6, lane = t & 63;
  const int n0 = blockIdx.x * 64;
  const int wk = t >> 3, wnc = (t & 7) * 8;
  const int kb = (lane >> 4) * 8;
  const int arow = wave * 16 + (lane & 15);
  f32x4 acc[4] = {};
  float4 w0a = *(const float4*)(W + (size_t)wk * ADJN + n0 + wnc);
  float4 w1a = *(const float4*)(W + (size_t)wk * ADJN + n0 + wnc + 4);
  bf8v aha = *(const bf8v*)(Ahi + (size_t)arow * DIN + kb);
  bf8v ala = *(const bf8v*)(Alo + (size_t)arow * DIN + kb);
  float4 w0b = *(const float4*)(W + (size_t)(32 + wk) * ADJN + n0 + wnc);
  float4 w1b = *(const float4*)(W + (size_t)(32 + wk) * ADJN + n0 + wnc + 4);
  bf8v ahb = *(const bf8v*)(Ahi + (size_t)arow * DIN + 32 + kb);
  bf8v alb = *(const bf8v*)(Alo + (size_t)arow * DIN + 32 + kb);
  for (int it = 0; it < 124; it += 2) {
    BA_STEP(0, it, w0a, w1a, aha, ala)
    BA_STEP(1, it + 1, w0b, w1b, ahb, alb)
  }
  BA_STEP(0, 124, w0a, w1a, aha, ala)
#pragma unroll
  for (int j = 0; j < 4; ++j) {
    const int col = n0 + j * 16 + (lane & 15);
    const float bb = bias[col];
#pragma unroll
    for (int vv = 0; vv < 4; ++vv) {
      const int row = wave * 16 + (lane >> 4) * 4 + vv;
      float x = acc[j][vv] + bb;
      adj[(size_t)row * ADJN + col] = 1.0f / (1.0f + __expf(-x));
    }
  }
}

// ---------------------------------------------------------------------------
// K2: adjS = 0.5*(adj + adj^T), LDS-tiled
// ---------------------------------------------------------------------------
__global__ __launch_bounds__(256) void symmetrize(const float* __restrict__ adj,
                                                  float* __restrict__ adjS) {
  __shared__ float tl[64][65];
  const int g = blockIdx.x;
  const int i0 = (blockIdx.y >> 2) * 64, j0 = (blockIdx.y & 3) * 64;
  const int tx = threadIdx.x & 63, ty = threadIdx.x >> 6;
  const float* ag = adj + (size_t)g * ADJN;
#pragma unroll
  for (int r = 0; r < 64; r += 4) {
    const int jr = j0 + ty + r;
    tl[ty + r][tx] = (jr < NN && i0 + tx < NN) ? ag[jr * NN + i0 + tx] : 0.f;
  }
  __syncthreads();
#pragma unroll
  for (int r = 0; r < 64; r += 4) {
    const int i = i0 + ty + r, j = j0 + tx;
    if (i < NN && j < NN)
      adjS[(size_t)g * ADJN + i * NN + j] = 0.5f * (ag[i * NN + j] + tl[tx][ty + r]);
  }
}

// ---------------------------------------------------------------------------
// K2b: per-row mean / std(ddof=1)
// ---------------------------------------------------------------------------
__global__ __launch_bounds__(256) void rowstats(const float* __restrict__ adjS,
                                                float* __restrict__ meanv,
                                                float* __restrict__ stdv) {
  const int row = blockIdx.x * 4 + (threadIdx.x >> 6);
  const int lane = threadIdx.x & 63;
  const float* r = adjS + (size_t)row * NN;
  float s = 0.f, q = 0.f;
#pragma unroll
  for (int k = 0; k < 4; ++k) {
    int i = k * 64 + lane;
    if (i < NN) { float v = r[i]; s += v; q += v * v; }
  }
#pragma unroll
  for (int off = 32; off > 0; off >>= 1) { s += __shfl_xor(s, off); q += __shfl_xor(q, off); }
  if (lane == 0) {
    float m = s * (1.0f / 200.0f);
    float var = (q - 200.0f * m * m) * (1.0f / 199.0f);
    var = fmaxf(var, 0.f);
    meanv[row] = m;
    stdv[row] = sqrtf(var) + 1e-6f;
  }
}

// ---------------------------------------------------------------------------
// K3: exact 10000th-largest per graph; wave-parallel suffix scan per pass
// ---------------------------------------------------------------------------
__global__ __launch_bounds__(512) void radix_select(const float* __restrict__ adjS,
                                                    float* __restrict__ tau) {
  __shared__ unsigned hist[2048];
  __shared__ unsigned s_pref, s_cA;
  const int g = blockIdx.x, t = threadIdx.x, lane = t & 63;
  const float* v = adjS + (size_t)g * ADJN;
  unsigned prefix = 0, pmask = 0, cA = 0;
  const int shifts[3] = {20, 9, 0};
  const int widths[3] = {2048, 2048, 512};
  for (int pass = 0; pass < 3; ++pass) {
    const int nb = widths[pass], sh = shifts[pass];
    for (int i = t; i < nb; i += 512) hist[i] = 0u;
    __syncthreads();
    for (int e = t; e < ADJN; e += 512) {
      unsigned u = __float_as_uint(v[e]);
      if ((u & pmask) == prefix) atomicAdd(&hist[(u >> sh) & (nb - 1)], 1u);
    }
    __syncthreads();
    if (t < 64) {
      const int CH = nb >> 6;
      unsigned lsum = 0;
      for (int i = 0; i < CH; ++i) lsum += hist[t * CH + i];
      unsigned s = lsum;
#pragma unroll
      for (int off = 1; off < 64; off <<= 1) {
        unsigned o = __shfl_down(s, off);
        if (lane + off < 64) s += o;
      }
      const unsigned need = 10000u - cA;
      unsigned sn = __shfl_down(s, 1);
      const unsigned snext = (lane == 63) ? 0u : sn;
      if (s >= need && snext < need) {
        unsigned cum = snext;
        int b = t * CH;
        for (int i = CH - 1; i >= 0; --i) {
          unsigned hb = hist[t * CH + i];
          if (cum + hb >= need) { b = t * CH + i; break; }
          cum += hb;
        }
        s_pref = prefix | ((unsigned)b << sh);
        s_cA = cA + cum;
      }
    }
    __syncthreads();
    prefix = s_pref; cA = s_cA;
    pmask |= (unsigned)(widths[pass] - 1) << sh;
    __syncthreads();
  }
  if (t == 0) tau[g] = __uint_as_float(prefix);
}

// ---------------------------------------------------------------------------
// K4: [mean,std] -> MLP(2->8 gelu ->16) -> LayerNorm(16) -> x0 f32
// ---------------------------------------------------------------------------
__global__ __launch_bounds__(256) void node_mlp(
    const float* __restrict__ meanv, const float* __restrict__ stdv,
    const float* __restrict__ feW1, const float* __restrict__ feb1,
    const float* __restrict__ feW2, const float* __restrict__ feb2,
    const float* __restrict__ ln_g, const float* __restrict__ ln_b,
    float* __restrict__ x0) {
  const int n = blockIdx.x * 256 + threadIdx.x;  // 12800 exact
  const float mu = meanv[n], sd = stdv[n];
  float h1[8];
#pragma unroll
  for (int o = 0; o < 8; ++o) h1[o] = gelu_f(mu * feW1[o] + sd * feW1[8 + o] + feb1[o]);
  float h2[16]; float s = 0.f;
#pragma unroll
  for (int o = 0; o < 16; ++o) {
    float a = feb2[o];
#pragma unroll
    for (int k = 0; k < 8; ++k) a += h1[k] * feW2[k * 16 + o];
    h2[o] = a; s += a;
  }
  s *= (1.0f / 16.0f);
  float var = 0.f;
#pragma unroll
  for (int o = 0; o < 16; ++o) { float d = h2[o] - s; var += d * d; }
  var *= (1.0f / 16.0f);
  const float inv = 1.0f / sqrtf(var + 1e-5f);
#pragma unroll
  for (int o = 0; o < 16; ++o) x0[(size_t)n * 16 + o] = (h2[o] - s) * inv * ln_g[o] + ln_b[o];
}

// ---------------------------------------------------------------------------
// K5: per-dst neighbor lists; 4 blocks per graph (50 rows each)
// ---------------------------------------------------------------------------
__global__ __launch_bounds__(256) void build_lists(
    const float* __restrict__ adjS, const float* __restrict__ tau,
    int* __restrict__ cnt1, int* __restrict__ cnt2,
    unsigned char* __restrict__ list1, unsigned char* __restrict__ list2) {
  const int g = blockIdx.x >> 2, quad = blockIdx.x & 3;
  const float tv = tau[g];
  const int t = threadIdx.x, wave = t >> 6, lane = t & 63;
  for (int jj = wave; jj < 50; jj += 4) {
    const int j = quad * 50 + jj;
    const float* row = adjS + (size_t)g * ADJN + (size_t)j * NN;
    unsigned char* l1 = list1 + ((size_t)g * NN + j) * NN;
    unsigned char* l2 = list2 + ((size_t)g * NN + j) * NN;
    int c1 = 0, c2 = 0;
#pragma unroll
    for (int r = 0; r < 4; ++r) {
      int i = r * 64 + lane;
      bool p1 = false, p2 = false;
      if (i < NN) { float v = row[i]; p1 = (v >= tv); p2 = p1 && (i != j); }
      unsigned long long b1 = __ballot(p1);
      unsigned long long b2 = __ballot(p2);
      unsigned long long below = (lane == 0) ? 0ull : ((~0ull) >> (64 - lane));
      if (p1) l1[c1 + __popcll(b1 & below)] = (unsigned char)i;
      if (p2) l2[c2 + __popcll(b2 & below)] = (unsigned char)i;
      c1 += (int)__popcll(b1); c2 += (int)__popcll(b2);
    }
    if (lane == 0) {
      l2[c2] = (unsigned char)j;
      cnt1[g * NN + j] = c1;
      cnt2[g * NN + j] = c2 + 1;
    }
  }
}

// ---------------------------------------------------------------------------
// K6: xl1/xr1 via MFMA 16x16x32_f16 (K=16 zero-padded); W transposed in LDS
// ---------------------------------------------------------------------------
__global__ __launch_bounds__(256) void lin16_mfma(
    const float* __restrict__ x0,
    const float* __restrict__ Wl, const float* __restrict__ bl,
    const float* __restrict__ Wr, const float* __restrict__ br,
    _Float16* __restrict__ outl, _Float16* __restrict__ outr) {
  __shared__ _Float16 Wt[2][1024 * 20];  // [n][k], stride 20 (bank-friendly)
  const int t = threadIdx.x, wave = t >> 6, lane = t & 63;
  const int mbase = blockIdx.x * 16;  // 800 blocks
  for (int i = t; i < 8192; i += 256) {
    const int mat = i >> 12, r = i & 4095;
    const int k = r >> 8, n4 = (r & 255) * 4;
    const float* Wsrc = mat ? Wr : Wl;
    float4 wv = *(const float4*)(Wsrc + (size_t)k * 1024 + n4);
    Wt[mat][(n4 + 0) * 20 + k] = (_Float16)wv.x;
    Wt[mat][(n4 + 1) * 20 + k] = (_Float16)wv.y;
    Wt[mat][(n4 + 2) * 20 + k] = (_Float16)wv.z;
    Wt[mat][(n4 + 3) * 20 + k] = (_Float16)wv.w;
  }
  const int mrow = lane & 15, kg = lane >> 4;
  F16X8U af;
#pragma unroll
  for (int q = 0; q < 8; ++q) af.v[q] = (_Float16)0.f;
  if (kg < 2) {
    const float* xp = x0 + (size_t)(mbase + mrow) * 16 + kg * 8;
    float4 v0 = *(const float4*)xp;
    float4 v1 = *(const float4*)(xp + 4);
    af.v[0] = (_Float16)v0.x; af.v[1] = (_Float16)v0.y;
    af.v[2] = (_Float16)v0.z; af.v[3] = (_Float16)v0.w;
    af.v[4] = (_Float16)v1.x; af.v[5] = (_Float16)v1.y;
    af.v[6] = (_Float16)v1.z; af.v[7] = (_Float16)v1.w;
  }
  __syncthreads();
#pragma unroll
  for (int mat = 0; mat < 2; ++mat) {
    const float* bias = mat ? br : bl;
    _Float16* out = mat ? outr : outl;
#pragma unroll
    for (int nt = 0; nt < 16; ++nt) {
      const int n0 = wave * 256 + nt * 16;
      F16X8U bfv;
#pragma unroll
      for (int q = 0; q < 8; ++q) bfv.v[q] = (_Float16)0.f;
      if (kg < 2) bfv.v = *(const f16x8*)(Wt[mat] + (n0 + mrow) * 20 + kg * 8);
      f32x4 acc = {};
      acc = __builtin_amdgcn_mfma_f32_16x16x32_f16(af.v, bfv.v, acc, 0, 0, 0);
      const int col = n0 + mrow;
      const float bb = bias[col];
#pragma unroll
      for (int j = 0; j < 4; ++j)
        out[(size_t)(mbase + kg * 4 + j) * 1024 + col] = (_Float16)(acc[j] + bb);
    }
  }
}

// ---------------------------------------------------------------------------
// K9: NT-GEMM 128x128 tile, BK=64, dbuf LDS, XOR-swizzle; grid (n, m)
// ---------------------------------------------------------------------------
__global__ __launch_bounds__(256, 2) void gemm_nt(
    const _Float16* __restrict__ A,
    const _Float16* __restrict__ Bt0, const _Float16* __restrict__ Bt1,
    const float* __restrict__ b0, const float* __restrict__ b1,
    _Float16* __restrict__ out0, _Float16* __restrict__ out1,
    int Nhalf, int tilesPerHalf) {
  __shared__ _Float16 As[2][128 * 64];
  __shared__ _Float16 Bs[2][128 * 64];
  const int mbase = blockIdx.y * 128;
  const int hsel = blockIdx.x / tilesPerHalf;
  const int ncol0 = (blockIdx.x % tilesPerHalf) * 128;
  const _Float16* Bt = hsel ? Bt1 : Bt0;
  const float* bias = hsel ? b1 : b0;
  _Float16* out = hsel ? out1 : out0;
  const int t = threadIdx.x, wave = t >> 6, lane = t & 63;
  const int wm = wave >> 1, wn = wave & 1;
  f32x4 acc[4][4] = {};
  int crow[4], gco[4], sto[4];
#pragma unroll
  for (int q = 0; q < 4; ++q) {
    const int c = q * 256 + t;
    crow[q] = c >> 3;
    const int sl = c & 7;
    gco[q] = sl * 8;
    sto[q] = crow[q] * 64 + ((sl ^ (crow[q] & 7)) << 3);
  }
  f16x8 ra[4], rb[4];
#pragma unroll
  for (int q = 0; q < 4; ++q) {
    ra[q] = *(const f16x8*)(A + (size_t)(mbase + crow[q]) * 1024 + gco[q]);
    rb[q] = *(const f16x8*)(Bt + (size_t)(ncol0 + crow[q]) * 1024 + gco[q]);
  }
  for (int kt = 0; kt < 16; ++kt) {
    const int p = kt & 1;
#pragma unroll
    for (int q = 0; q < 4; ++q) {
      *(f16x8*)(As[p] + sto[q]) = ra[q];
      *(f16x8*)(Bs[p] + sto[q]) = rb[q];
    }
    if (kt < 15) {
      const int k0 = (kt + 1) * 64;
#pragma unroll
      for (int q = 0; q < 4; ++q) {
        ra[q] = *(const f16x8*)(A + (size_t)(mbase + crow[q]) * 1024 + k0 + gco[q]);
        rb[q] = *(const f16x8*)(Bt + (size_t)(ncol0 + crow[q]) * 1024 + k0 + gco[q]);
      }
    }
    __syncthreads();
#pragma unroll
    for (int ks = 0; ks < 2; ++ks) {
      F16X8U af[4], bfv[4];
#pragma unroll
      for (int m = 0; m < 4; ++m) {
        const int row = wm * 64 + m * 16 + (lane & 15);
        const int kk = ks * 32 + (lane >> 4) * 8;
        af[m].v = *(const f16x8*)(As[p] + row * 64 + (kk ^ ((row & 7) << 3)));
      }
#pragma unroll
      for (int j = 0; j < 4; ++j) {
        const int row = wn * 64 + j * 16 + (lane & 15);
        const int kk = ks * 32 + (lane >> 4) * 8;
        bfv[j].v = *(const f16x8*)(Bs[p] + row * 64 + (kk ^ ((row & 7) << 3)));
      }
#pragma unroll
      for (int j = 0; j < 4; ++j)
#pragma unroll
        for (int m = 0; m < 4; ++m)
          acc[m][j] = __builtin_amdgcn_mfma_f32_16x16x32_f16(af[m].v, bfv[j].v, acc[m][j], 0, 0, 0);
    }
  }
#pragma unroll
  for (int j = 0; j < 4; ++j) {
    const int col = ncol0 + wn * 64 + j * 16 + (lane & 15);
    const float bb = bias[col];
#pragma unroll
    for (int m = 0; m < 4; ++m) {
#pragma unroll
      for (int vv = 0; vv < 4; ++vv) {
        const int row = mbase + wm * 64 + m * 16 + (lane >> 4) * 4 + vv;
        out[(size_t)row * Nhalf + col] = (_Float16)(acc[m][j][vv] + bb);
      }
    }
  }
}

// ---------------------------------------------------------------------------
// K7: GATv2 layer; parallel-edge-group aggregation
// ---------------------------------------------------------------------------
template <int C, int NR, int NSPLIT, int HC, bool USE_LL>
__global__ __launch_bounds__(1024, 4) void gat_layer(
    const _Float16* __restrict__ xlb, const _Float16* __restrict__ xrb,
    const float* __restrict__ attw, const float* __restrict__ biasw,
    const int* __restrict__ cnts, const unsigned char* __restrict__ lists,
    _Float16* __restrict__ outb) {
  extern __shared__ char smem[];
  constexpr int XLB = 200 * C * 2;
  constexpr int XRB = NR * C * 2;
  constexpr int AWB = 16 * 200 * 2;
  _Float16* xr_s = (_Float16*)(smem + XLB);
  _Float16* aw = (_Float16*)(smem + XLB + XRB);
  unsigned char* ll = (unsigned char*)(smem + XLB + XRB + AWB);
  unsigned* att_s = (unsigned*)(smem + XLB + XRB + AWB + (USE_LL ? 3200 : 0));
  const int g = blockIdx.x;
  const int hd = blockIdx.y / NSPLIT;
  const int range = blockIdx.y % NSPLIT;
  const int r0 = range * NR;
  const int t = threadIdx.x, wave = t >> 6, lane = t & 63;
  constexpr int GRP = (C == 128) ? 16 : 32;
  constexpr int NG = 64 / GRP;
  const int grp = lane / GRP, li = lane % GRP;

  for (int ch = t; ch < 200 * (C / 8); ch += 1024) {
    const int node = ch / (C / 8), cc = (ch % (C / 8)) * 8;
    f16x8 v = *(const f16x8*)(xlb + (size_t)(g * 200 + node) * HC + hd * C + cc);
    *(f16x8*)(smem + (((node * C + cc) * 2) ^ ((node & 15) << 4))) = v;
  }
  for (int ch = t; ch < NR * (C / 8); ch += 1024) {
    const int node = ch / (C / 8), cc = (ch % (C / 8)) * 8;
    *(f16x8*)(xr_s + node * C + cc) =
        *(const f16x8*)(xrb + (size_t)(g * 200 + r0 + node) * HC + hd * C + cc);
  }
  for (int i = t; i < C / 2; i += 1024) {
    f16x2 a;
    a[0] = (_Float16)attw[hd * C + 2 * i];
    a[1] = (_Float16)attw[hd * C + 2 * i + 1];
    att_s[i] = __builtin_bit_cast(unsigned, a);
  }
  __syncthreads();

  for (int jj = wave; jj < NR; jj += 16) {
    const int j = r0 + jj;
    const int gn = g * 200 + j;
    const int cnt = cnts[gn];
    const unsigned char* lst = lists + (size_t)gn * NN;
    float lg[4] = {-INFINITY, -INFINITY, -INFINITY, -INFINITY};
#pragma unroll
    for (int r = 0; r < 4; ++r) {
      const int e = (r << 6) + lane;
      if (e < cnt) {
        const int s = lst[e];
        if constexpr (USE_LL) ll[wave * 200 + e] = (unsigned char)s;
        const int swz = (s & 15) << 4;
        float accv[4] = {0.f, 0.f, 0.f, 0.f};
#pragma unroll
        for (int c0 = 0; c0 < C; c0 += 16) {
          const int ai = ((c0 >> 4) & 1) * 2;
          const unsigned* ap = att_s + c0 / 2;
          F16X8U xa, xb, raa, rbb;
          xa.v = *(const f16x8*)(smem + (((s * C + c0) * 2) ^ swz));
          xb.v = *(const f16x8*)(smem + (((s * C + c0 + 8) * 2) ^ swz));
          raa.v = *(const f16x8*)(xr_s + jj * C + c0);
          rbb.v = *(const f16x8*)(xr_s + jj * C + c0 + 8);
#pragma unroll
          for (int pq = 0; pq < 4; ++pq) {
            f16x2 z = xa.p[pq] + raa.p[pq];
            f16x2 zs = z * (_Float16)0.2f;
            f16x2 m = __builtin_elementwise_max(z, zs);
            accv[ai] = FDOT2(__builtin_bit_cast(f16x2, ap[pq]), m, accv[ai]);
            f16x2 z2 = xb.p[pq] + rbb.p[pq];
            f16x2 zs2 = z2 * (_Float16)0.2f;
            f16x2 m2 = __builtin_elementwise_max(z2, zs2);
            accv[ai + 1] = FDOT2(__builtin_bit_cast(f16x2, ap[4 + pq]), m2, accv[ai + 1]);
          }
        }
        lg[r] = (accv[0] + accv[1]) + (accv[2] + accv[3]);
      }
    }
    float mloc = fmaxf(fmaxf(lg[0], lg[1]), fmaxf(lg[2], lg[3]));
#pragma unroll
    for (int off = 32; off > 0; off >>= 1) mloc = fmaxf(mloc, __shfl_xor(mloc, off));
    float ex[4]; float ps = 0.f;
#pragma unroll
    for (int r = 0; r < 4; ++r) { ex[r] = __expf(lg[r] - mloc); ps += ex[r]; }
#pragma unroll
    for (int off = 32; off > 0; off >>= 1) ps += __shfl_xor(ps, off);
    const float denom = ps + 1e-16f;
#pragma unroll
    for (int r = 0; r < 4; ++r) {
      const int e = (r << 6) + lane;
      if (e < cnt) aw[wave * 200 + e] = (_Float16)(ex[r] / denom);
    }
    // parallel-edge-group aggregation: NG edges at a time, GRP lanes/edge
    float o[8] = {};
    for (int e0 = 0; e0 < cnt; e0 += NG) {
      const int e = e0 + grp;
      if (e < cnt) {
        const float a = (float)aw[wave * 200 + e];
        int s;
        if constexpr (USE_LL) s = ll[wave * 200 + e]; else s = lst[e];
        const int swz = (s & 15) << 4;
        f16x8 xv = *(const f16x8*)(smem + (((s * C + li * 8) * 2) ^ swz));
#pragma unroll
        for (int q = 0; q < 8; ++q) o[q] += a * (float)xv[q];
      }
    }
#pragma unroll
    for (int q = 0; q < 8; ++q) {
      if constexpr (GRP == 16) o[q] += __shfl_xor(o[q], 16);
      o[q] += __shfl_xor(o[q], 32);
    }
    if (grp == 0) {
      const int colb = hd * C + li * 8;
      f16x8 ov;
#pragma unroll
      for (int q = 0; q < 8; ++q) ov[q] = (_Float16)gelu_f(o[q] + biasw[colb + q]);
      *(f16x8*)(outb + (size_t)gn * HC + colb) = ov;
    }
  }
}

// ---------------------------------------------------------------------------
// K7-L3: GATv2 (H=1,C=512) chunked; group-parallel agg; fused pool
// ---------------------------------------------------------------------------
__global__ __launch_bounds__(1024, 4) void gat_l3(
    const _Float16* __restrict__ xlb, const _Float16* __restrict__ xrb,
    const float* __restrict__ attw, const float* __restrict__ biasw,
    const int* __restrict__ cnts, const unsigned char* __restrict__ lists,
    float* __restrict__ psum) {
  extern __shared__ char smem[];
  _Float16* xr_s = (_Float16*)(smem + 51200);
  float* plog = (float*)(smem + 64000);
  unsigned* att_s = (unsigned*)(smem + 104000);
  const int g = blockIdx.x, range = blockIdx.y, r0 = range * 50;
  const int t = threadIdx.x, wave = t >> 6, lane = t & 63;
  const int grp = lane >> 4, li = lane & 15;

  for (int chunk = 0; chunk < 4; ++chunk) {
    if (chunk) __syncthreads();
    for (int ch = t; ch < 200 * 16; ch += 1024) {
      const int node = ch >> 4, cc = (ch & 15) * 8;
      *(f16x8*)(smem + (((node * 128 + cc) * 2) ^ ((node & 15) << 4))) =
          *(const f16x8*)(xlb + (size_t)(g * 200 + node) * 512 + chunk * 128 + cc);
    }
    for (int ch = t; ch < 50 * 16; ch += 1024) {
      const int node = ch >> 4, cc = (ch & 15) * 8;
      *(f16x8*)(xr_s + node * 128 + cc) =
          *(const f16x8*)(xrb + (size_t)(g * 200 + r0 + node) * 512 + chunk * 128 + cc);
    }
    for (int i = t; i < 64; i += 1024) {
      f16x2 a;
      a[0] = (_Float16)attw[chunk * 128 + 2 * i];
      a[1] = (_Float16)attw[chunk * 128 + 2 * i + 1];
      att_s[i] = __builtin_bit_cast(unsigned, a);
    }
    __syncthreads();
    for (int jj = wave; jj < 50; jj += 16) {
      const int gn = g * 200 + r0 + jj;
      const int cnt = cnts[gn];
      const unsigned char* lst = lists + (size_t)gn * NN;
#pragma unroll
      for (int r = 0; r < 4; ++r) {
        const int e = (r << 6) + lane;
        if (e < cnt) {
          const int s = lst[e];
          const int swz = (s & 15) << 4;
          float accv[4] = {0.f, 0.f, 0.f, 0.f};
#pragma unroll
          for (int c0 = 0; c0 < 128; c0 += 16) {
            const int ai = ((c0 >> 4) & 1) * 2;
            const unsigned* ap = att_s + c0 / 2;
            F16X8U xa, xb, raa, rbb;
            xa.v = *(const f16x8*)(smem + (((s * 128 + c0) * 2) ^ swz));
            xb.v = *(const f16x8*)(smem + (((s * 128 + c0 + 8) * 2) ^ swz));
            raa.v = *(const f16x8*)(xr_s + jj * 128 + c0);
            rbb.v = *(const f16x8*)(xr_s + jj * 128 + c0 + 8);
#pragma unroll
            for (int pq = 0; pq < 4; ++pq) {
              f16x2 z = xa.p[pq] + raa.p[pq];
              f16x2 zs = z * (_Float16)0.2f;
              f16x2 m = __builtin_elementwise_max(z, zs);
              accv[ai] = FDOT2(__builtin_bit_cast(f16x2, ap[pq]), m, accv[ai]);
              f16x2 z2 = xb.p[pq] + rbb.p[pq];
              f16x2 zs2 = z2 * (_Float16)0.2f;
              f16x2 m2 = __builtin_elementwise_max(z2, zs2);
              accv[ai + 1] = FDOT2(__builtin_bit_cast(f16x2, ap[4 + pq]), m2, accv[ai + 1]);
            }
          }
          const float acc = (accv[0] + accv[1]) + (accv[2] + accv[3]);
          if (chunk == 0) plog[jj * 200 + e] = acc;
          else plog[jj * 200 + e] += acc;
        }
      }
    }
  }
  __syncthreads();
  for (int jj = wave; jj < 50; jj += 16) {
    const int gn = g * 200 + r0 + jj;
    const int cnt = cnts[gn];
    float lg[4] = {-INFINITY, -INFINITY, -INFINITY, -INFINITY};
#pragma unroll
    for (int r = 0; r < 4; ++r) {
      const int e = (r << 6) + lane;
      if (e < cnt) lg[r] = plog[jj * 200 + e];
    }
    float mloc = fmaxf(fmaxf(lg[0], lg[1]), fmaxf(lg[2], lg[3]));
#pragma unroll
    for (int off = 32; off > 0; off >>= 1) mloc = fmaxf(mloc, __shfl_xor(mloc, off));
    float ex[4]; float ps = 0.f;
#pragma unroll
    for (int r = 0; r < 4; ++r) { ex[r] = __expf(lg[r] - mloc); ps += ex[r]; }
#pragma unroll
    for (int off = 32; off > 0; off >>= 1) ps += __shfl_xor(ps, off);
    const float denom = ps + 1e-16f;
#pragma unroll
    for (int r = 0; r < 4; ++r) {
      const int e = (r << 6) + lane;
      if (e < cnt) plog[jj * 200 + e] = ex[r] / denom;
    }
  }
  for (int chunk = 0; chunk < 4; ++chunk) {
    __syncthreads();
    for (int ch = t; ch < 200 * 16; ch += 1024) {
      const int node = ch >> 4, cc = (ch & 15) * 8;
      *(f16x8*)(smem + (((node * 128 + cc) * 2) ^ ((node & 15) << 4))) =
          *(const f16x8*)(xlb + (size_t)(g * 200 + node) * 512 + chunk * 128 + cc);
    }
    __syncthreads();
    float p[8] = {};
    for (int jj = wave; jj < 50; jj += 16) {
      const int gn = g * 200 + r0 + jj;
      const int cnt = cnts[gn];
      const unsigned char* lst = lists + (size_t)gn * NN;
      float o[8] = {};
      for (int e0 = 0; e0 < cnt; e0 += 4) {
        const int e = e0 + grp;
        if (e < cnt) {
          const float a = plog[jj * 200 + e];
          const int s = lst[e];
          const int swz = (s & 15) << 4;
          f16x8 xv = *(const f16x8*)(smem + (((s * 128 + li * 8) * 2) ^ swz));
#pragma unroll
          for (int q = 0; q < 8; ++q) o[q] += a * (float)xv[q];
        }
      }
#pragma unroll
      for (int q = 0; q < 8; ++q) {
        o[q] += __shfl_xor(o[q], 16);
        o[q] += __shfl_xor(o[q], 32);
      }
      if (grp == 0) {
        const int colb = chunk * 128 + li * 8;
#pragma unroll
        for (int q = 0; q < 8; ++q) p[q] += gelu_f(o[q] + biasw[colb + q]);
      }
    }
    if (grp == 0) {
      const int slot = range * 16 + wave;
      float* pd = psum + ((size_t)slot * 64 + g) * 512 + chunk * 128 + li * 8;
      float4 a0 = {p[0], p[1], p[2], p[3]};
      float4 a1 = {p[4], p[5], p[6], p[7]};
      *(float4*)pd = a0;
      *(float4*)(pd + 4) = a1;
    }
  }
}

// ---------------------------------------------------------------------------
// K10: d_out[b][c] = (1/200) * sum over 64 partial slots
// ---------------------------------------------------------------------------
__global__ void finalize(const float* __restrict__ psum, float* __restrict__ out) {
  const int idx = blockIdx.x * 256 + threadIdx.x;  // 32768 exact
  float s = 0.f;
#pragma unroll
  for (int k = 0; k < 64; ++k) s += psum[(size_t)k * 32768 + idx];
  out[idx] = s * 0.005f;
}

// ---------------------------------------------------------------------------
extern "C" void kernel_launch(void* const* d_in, const int* in_sizes, int n_in,
                              void* d_out, int out_size, void* d_ws, size_t ws_size,
                              hipStream_t stream) {
  const float* raw_fc = (const float*)d_in[0];
  const float* gbW = (const float*)d_in[1];
  const float* gbb = (const float*)d_in[2];
  const float* feW1 = (const float*)d_in[3];
  const float* feb1 = (const float*)d_in[4];
  const float* feW2 = (const float*)d_in[5];
  const float* feb2 = (const float*)d_in[6];
  const float* ln_g = (const float*)d_in[7];
  const float* ln_b = (const float*)d_in[8];
  const float* W1l = (const float*)d_in[9];  const float* b1l = (const float*)d_in[10];
  const float* W1r = (const float*)d_in[11]; const float* b1r = (const float*)d_in[12];
  const float* att1 = (const float*)d_in[13]; const float* bias1 = (const float*)d_in[14];
  const float* W2l = (const float*)d_in[15]; const float* b2l = (const float*)d_in[16];
  const float* W2r = (const float*)d_in[17]; const float* b2r = (const float*)d_in[18];
  const float* att2 = (const float*)d_in[19]; const float* bias2 = (const float*)d_in[20];
  const float* W3l = (const float*)d_in[21]; const float* b3l = (const float*)d_in[22];
  const float* W3r = (const float*)d_in[23]; const float* b3r = (const float*)d_in[24];
  const float* att3 = (const float*)d_in[25]; const float* bias3 = (const float*)d_in[26];

  if (ws_size < 121000000) return;  // need ~115.4 MiB scratch

  char* w = (char*)d_ws;
  float* adj   = (float*)(w + 0);
  float* adjS  = (float*)(w + 10240000);
  float* meanv = (float*)(w + 20480000);
  float* stdv  = (float*)(w + 20531200);
  float* tau   = (float*)(w + 20582400);
  float* x0    = (float*)(w + 20582656);
  int* cnt1    = (int*)(w + 21401856);
  int* cnt2    = (int*)(w + 21453056);
  unsigned char* list1 = (unsigned char*)(w + 21504256);
  unsigned char* list2 = (unsigned char*)(w + 24064256);
  _Float16* bufA = (_Float16*)(w + 26624256);   // xl1 / xl2 / xl3
  _Float16* bufB = (_Float16*)(w + 52838656);   // xr1 / xr2 / xr3
  _Float16* bufC = (_Float16*)(w + 79053056);   // x2 / x3
  float* psum = (float*)(w + 105267456);        // 8,388,608 B (64 slots)
  short* Ahi  = (short*)(w + 113656064);
  short* Alo  = (short*)(w + 114168064);
  _Float16* Wt2l = (_Float16*)(w + 114680064);
  _Float16* Wt2r = (_Float16*)(w + 116777216);
  _Float16* Wt3l = (_Float16*)(w + 118874368);
  _Float16* Wt3r = (_Float16*)(w + 119922944);

  const int SMEM_L1 = 112256;   // 51200+51200+6400+3200+256
  const int SMEM_L2 = 160512;   // 102400+51200+6400+512
  const int SMEM_L3 = 104256;   // 51200+12800+40000+256
  hipFuncSetAttribute((const void*)gat_layer<128, 200, 1, 1024, true>,
                      hipFuncAttributeMaxDynamicSharedMemorySize, SMEM_L1);
  hipFuncSetAttribute((const void*)gat_layer<256, 100, 2, 1024, false>,
                      hipFuncAttributeMaxDynamicSharedMemorySize, SMEM_L2);
  hipFuncSetAttribute((const void*)gat_l3,
                      hipFuncAttributeMaxDynamicSharedMemorySize, SMEM_L3);

  prep_A<<<1000, 256, 0, stream>>>(raw_fc, Ahi, Alo);
  transp_all<<<dim3(32, 32, 4), 256, 0, stream>>>(W2l, W2r, W3l, W3r, Wt2l, Wt2r, Wt3l, Wt3r);
  build_adj<<<625, 256, 0, stream>>>(Ahi, Alo, gbW, gbb, adj);
  symmetrize<<<dim3(64, 16), 256, 0, stream>>>(adj, adjS);
  rowstats<<<3200, 256, 0, stream>>>(adjS, meanv, stdv);
  radix_select<<<64, 512, 0, stream>>>(adjS, tau);
  node_mlp<<<50, 256, 0, stream>>>(meanv, stdv, feW1, feb1, feW2, feb2, ln_g, ln_b, x0);
  build_lists<<<256, 256, 0, stream>>>(adjS, tau, cnt1, cnt2, list1, list2);
  lin16_mfma<<<800, 256, 0, stream>>>(x0, W1l, b1l, W1r, b1r, bufA, bufB);
  gat_layer<128, 200, 1, 1024, true><<<dim3(64, 8), 1024, SMEM_L1, stream>>>(
      bufA, bufB, att1, bias1, cnt1, list1, bufC);
  gemm_nt<<<dim3(16, 100), 256, 0, stream>>>(bufC, Wt2l, Wt2r, b2l, b2r, bufA, bufB, 1024, 8);
  gat_layer<256, 100, 2, 1024, false><<<dim3(64, 8), 1024, SMEM_L2, stream>>>(
      bufA, bufB, att2, bias2, cnt2, list2, bufC);
  gemm_nt<<<dim3(8, 100), 256, 0, stream>>>(bufC, Wt3l, Wt3r, b3l, b3r, bufA, bufB, 512, 4);
  gat_l3<<<dim3(64, 4), 1024, SMEM_L3, stream>>>(bufA, bufB, att3, bias3, cnt2, list2, psum);
  finalize<<<128, 256, 0, stream>>>(psum, (float*)d_out);
}

// Round 5
// 976.703 us; speedup vs baseline: 1.5232x; 1.0329x over previous
//
#include <hip/hip_runtime.h>
#include <hip/hip_fp16.h>
#include <math.h>
#include <cstdint>
#include <cstddef>

#define NGRAPH 64
#define NN 200
#define ADJN 40000
#define DIN 4000
#define NNODE 12800

typedef float    f32x4 __attribute__((ext_vector_type(4)));
typedef _Float16 f16x8 __attribute__((ext_vector_type(8)));
typedef _Float16 f16x4 __attribute__((ext_vector_type(4)));
typedef _Float16 f16x2 __attribute__((ext_vector_type(2)));
typedef short    bf8v  __attribute__((ext_vector_type(8)));
typedef short    bf4v  __attribute__((ext_vector_type(4)));

union BF8U  { bf8v v; bf4v h[2]; };
union F16X8U{ f16x8 v; f16x4 h[2]; f16x2 p[4]; };

__device__ __forceinline__ unsigned short f2bf(float f) {
  unsigned u = __float_as_uint(f);
  return (unsigned short)((u + 0x7fffu + ((u >> 16) & 1u)) >> 16);
}
__device__ __forceinline__ float bf2f(unsigned short s) {
  return __uint_as_float(((unsigned)s) << 16);
}
__device__ __forceinline__ float gelu_f(float x) {
  return x * 0.5f * (1.0f + erff(x * 0.70710678118654752f));
}

#if defined(__has_builtin)
#if __has_builtin(__builtin_amdgcn_fdot2)
#define FDOT2(a, b, c) __builtin_amdgcn_fdot2((a), (b), (c), false)
#endif
#endif
#ifndef FDOT2
#define FDOT2(a, b, c) ((c) + (float)(a)[0] * (float)(b)[0] + (float)(a)[1] * (float)(b)[1])
#endif

// ---------------------------------------------------------------------------
// K0: raw_fc -> hi/lo bf16 split
// ---------------------------------------------------------------------------
__global__ __launch_bounds__(256) void prep_A(const float* __restrict__ A,
                                              short* __restrict__ Ahi,
                                              short* __restrict__ Alo) {
  const int i = blockIdx.x * 256 + threadIdx.x;  // 256000 exact
  const float v = A[i];
  const unsigned short h = f2bf(v);
  Ahi[i] = (short)h;
  Alo[i] = (short)f2bf(v - bf2f(h));
}

// ---------------------------------------------------------------------------
// K0b: all 4 GEMM weights: W[k][n] f32 -> Wt[n][k] f16 (fused, blockIdx.z)
// ---------------------------------------------------------------------------
__global__ __launch_bounds__(256) void transp_all(
    const float* __restrict__ W2l, const float* __restrict__ W2r,
    const float* __restrict__ W3l, const float* __restrict__ W3r,
    _Float16* __restrict__ T2l, _Float16* __restrict__ T2r,
    _Float16* __restrict__ T3l, _Float16* __restrict__ T3r) {
  __shared__ float tile[32][33];
  const int z = blockIdx.z;
  if (z >= 2 && blockIdx.y >= 16) return;
  const float* src = (z == 0) ? W2l : (z == 1) ? W2r : (z == 2) ? W3l : W3r;
  _Float16* dst = (z == 0) ? T2l : (z == 1) ? T2r : (z == 2) ? T3l : T3r;
  const int N = (z < 2) ? 1024 : 512;
  const int K = 1024;
  const int bk = blockIdx.x * 32, bn = blockIdx.y * 32;
  const int tx = threadIdx.x & 31, ty = threadIdx.x >> 5;
#pragma unroll
  for (int r = 0; r < 32; r += 8) tile[ty + r][tx] = src[(size_t)(bk + ty + r) * N + bn + tx];
  __syncthreads();
#pragma unroll
  for (int r = 0; r < 32; r += 8)
    dst[(size_t)(bn + ty + r) * K + bk + tx] = (_Float16)tile[tx][ty + r];
}

// ---------------------------------------------------------------------------
// K1: adj = sigmoid(raw_fc @ gbW + gbb); split-bf16 MFMA.
// v3 pipeline: sync -> issue(it+2) -> MFMA(buf p) -> convert(it+1)->buf p^1.
// Loads issued right AFTER the barrier fly for a full iteration before the
// next barrier's vmcnt(0) drain (the pre-barrier issue of v2 was drained
// immediately -> ~900cy exposed per iter).
// ---------------------------------------------------------------------------
#define BA_CONV(PB, W0, W1)                                                     \
  { float wv[8] = {W0.x, W0.y, W0.z, W0.w, W1.x, W1.y, W1.z, W1.w};             \
    _Pragma("unroll") for (int q = 0; q < 8; ++q) {                             \
      unsigned short hh = f2bf(wv[q]);                                          \
      Wh[PB][(wnc + q) * 44 + wk] = (short)hh;                                  \
      Wl[PB][(wnc + q) * 44 + wk] = (short)f2bf(wv[q] - bf2f(hh));              \
    } }

#define BA_MFMA(PB, AHC, ALC)                                                   \
  _Pragma("unroll") for (int j = 0; j < 4; ++j) {                               \
    const int bc = (j * 16 + (lane & 15)) * 44 + kb;                            \
    BF8U bh, bl;                                                                \
    bh.h[0] = *(const bf4v*)(Wh[PB] + bc);                                      \
    bh.h[1] = *(const bf4v*)(Wh[PB] + bc + 4);                                  \
    bl.h[0] = *(const bf4v*)(Wl[PB] + bc);                                      \
    bl.h[1] = *(const bf4v*)(Wl[PB] + bc + 4);                                  \
    acc[j] = __builtin_amdgcn_mfma_f32_16x16x32_bf16(AHC, bh.v, acc[j], 0, 0, 0); \
    acc[j] = __builtin_amdgcn_mfma_f32_16x16x32_bf16(AHC, bl.v, acc[j], 0, 0, 0); \
    acc[j] = __builtin_amdgcn_mfma_f32_16x16x32_bf16(ALC, bh.v, acc[j], 0, 0, 0); \
  }

#define BA_LOADW(W0, W1, K0)                                                    \
  W0 = *(const float4*)(W + (size_t)((K0) + wk) * ADJN + n0 + wnc);             \
  W1 = *(const float4*)(W + (size_t)((K0) + wk) * ADJN + n0 + wnc + 4);

#define BA_LOADA(AH, AL, K0)                                                    \
  AH = *(const bf8v*)(Ahi + (size_t)arow * DIN + (K0) + kb);                    \
  AL = *(const bf8v*)(Alo + (size_t)arow * DIN + (K0) + kb);

__global__ __launch_bounds__(256) void build_adj(
    const short* __restrict__ Ahi, const short* __restrict__ Alo,
    const float* __restrict__ W, const float* __restrict__ bias,
    float* __restrict__ adj) {
  __shared__ short Wh[2][64 * 44], Wl[2][64 * 44];
  const int t = threadIdx.x, wave = t >> 6, lane = t & 63;
  const int n0 = blockIdx.x * 64;
  const int wk = t >> 3, wnc = (t & 7) * 8;
  const int kb = (lane >> 4) * 8;
  const int arow = wave * 16 + (lane & 15);
  f32x4 acc[4] = {};
  float4 w0s0, w1s0, w0s1, w1s1;
  bf8v ahs0, als0, ahs1, als1;
  // prologue: issue tiles 0 (set0) and 1 (set1); convert tile0 -> buf0
  BA_LOADW(w0s0, w1s0, 0)
  BA_LOADA(ahs0, als0, 0)
  BA_LOADW(w0s1, w1s1, 32)
  BA_LOADA(ahs1, als1, 32)
  BA_CONV(0, w0s0, w1s0)
  for (int it = 0; it < 124; it += 2) {
    // even body: tile it, buf 0
    __syncthreads();
    {
      const bf8v ahc = ahs0, alc = als0;
      if (it + 2 < 125) {
        const int k2 = (it + 2) * 32;
        BA_LOADW(w0s0, w1s0, k2)
        BA_LOADA(ahs0, als0, k2)
      }
      BA_MFMA(0, ahc, alc)
      BA_CONV(1, w0s1, w1s1)          // tile it+1 -> buf1 (always exists)
    }
    // odd body: tile it+1, buf 1
    __syncthreads();
    {
      const bf8v ahc = ahs1, alc = als1;
      if (it + 3 < 125) {
        const int k2 = (it + 3) * 32;
        BA_LOADW(w0s1, w1s1, k2)
        BA_LOADA(ahs1, als1, k2)
      }
      BA_MFMA(1, ahc, alc)
      if (it + 2 < 125) BA_CONV(0, w0s0, w1s0)   // tile it+2 -> buf0
    }
  }
  // tail: tile 124, buf 0
  __syncthreads();
  BA_MFMA(0, ahs0, als0)
#pragma unroll
  for (int j = 0; j < 4; ++j) {
    const int col = n0 + j * 16 + (lane & 15);
    const float bb = bias[col];
#pragma unroll
    for (int vv = 0; vv < 4; ++vv) {
      const int row = wave * 16 + (lane >> 4) * 4 + vv;
      float x = acc[j][vv] + bb;
      adj[(size_t)row * ADJN + col] = 1.0f / (1.0f + __expf(-x));
    }
  }
}

// ---------------------------------------------------------------------------
// K2: adjS = 0.5*(adj + adj^T), LDS-tiled
// ---------------------------------------------------------------------------
__global__ __launch_bounds__(256) void symmetrize(const float* __restrict__ adj,
                                                  float* __restrict__ adjS) {
  __shared__ float tl[64][65];
  const int g = blockIdx.x;
  const int i0 = (blockIdx.y >> 2) * 64, j0 = (blockIdx.y & 3) * 64;
  const int tx = threadIdx.x & 63, ty = threadIdx.x >> 6;
  const float* ag = adj + (size_t)g * ADJN;
#pragma unroll
  for (int r = 0; r < 64; r += 4) {
    const int jr = j0 + ty + r;
    tl[ty + r][tx] = (jr < NN && i0 + tx < NN) ? ag[jr * NN + i0 + tx] : 0.f;
  }
  __syncthreads();
#pragma unroll
  for (int r = 0; r < 64; r += 4) {
    const int i = i0 + ty + r, j = j0 + tx;
    if (i < NN && j < NN)
      adjS[(size_t)g * ADJN + i * NN + j] = 0.5f * (ag[i * NN + j] + tl[tx][ty + r]);
  }
}

// ---------------------------------------------------------------------------
// K2b: per-row mean / std(ddof=1)
// ---------------------------------------------------------------------------
__global__ __launch_bounds__(256) void rowstats(const float* __restrict__ adjS,
                                                float* __restrict__ meanv,
                                                float* __restrict__ stdv) {
  const int row = blockIdx.x * 4 + (threadIdx.x >> 6);
  const int lane = threadIdx.x & 63;
  const float* r = adjS + (size_t)row * NN;
  float s = 0.f, q = 0.f;
#pragma unroll
  for (int k = 0; k < 4; ++k) {
    int i = k * 64 + lane;
    if (i < NN) { float v = r[i]; s += v; q += v * v; }
  }
#pragma unroll
  for (int off = 32; off > 0; off >>= 1) { s += __shfl_xor(s, off); q += __shfl_xor(q, off); }
  if (lane == 0) {
    float m = s * (1.0f / 200.0f);
    float var = (q - 200.0f * m * m) * (1.0f / 199.0f);
    var = fmaxf(var, 0.f);
    meanv[row] = m;
    stdv[row] = sqrtf(var) + 1e-6f;
  }
}

// ---------------------------------------------------------------------------
// K3: fused radix-select (4-copy hist) + per-dst neighbor lists. 64 blocks.
// ---------------------------------------------------------------------------
__global__ __launch_bounds__(1024) void radix_lists(
    const float* __restrict__ adjS,
    int* __restrict__ cnt1, int* __restrict__ cnt2,
    unsigned char* __restrict__ list1, unsigned char* __restrict__ list2) {
  __shared__ unsigned hist[4 * 2048];
  __shared__ unsigned s_pref, s_cA;
  const int g = blockIdx.x, t = threadIdx.x, lane = t & 63, wave = t >> 6;
  const float* v = adjS + (size_t)g * ADJN;
  unsigned prefix = 0, pmask = 0, cA = 0;
  const int shifts[3] = {20, 9, 0};
  const int widths[3] = {2048, 2048, 512};
  for (int pass = 0; pass < 3; ++pass) {
    const int nb = widths[pass], sh = shifts[pass];
    for (int i = t; i < 8192; i += 1024) hist[i] = 0u;
    __syncthreads();
    const int cpy = (lane & 3) * 2048;
    for (int e = t; e < ADJN; e += 1024) {
      unsigned u = __float_as_uint(v[e]);
      if ((u & pmask) == prefix) atomicAdd(&hist[cpy + ((u >> sh) & (nb - 1))], 1u);
    }
    __syncthreads();
    if (t < 64) {
      const int CH = nb >> 6;
      unsigned lsum = 0;
      for (int i = 0; i < CH; ++i) {
        const int b = t * CH + i;
        lsum += hist[b] + hist[2048 + b] + hist[4096 + b] + hist[6144 + b];
      }
      unsigned s = lsum;
#pragma unroll
      for (int off = 1; off < 64; off <<= 1) {
        unsigned o = __shfl_down(s, off);
        if (lane + off < 64) s += o;
      }
      const unsigned need = 10000u - cA;
      unsigned sn = __shfl_down(s, 1);
      const unsigned snext = (lane == 63) ? 0u : sn;
      if (s >= need && snext < need) {
        unsigned cum = snext;
        int bsel = t * CH;
        for (int i = CH - 1; i >= 0; --i) {
          const int b = t * CH + i;
          unsigned hb = hist[b] + hist[2048 + b] + hist[4096 + b] + hist[6144 + b];
          if (cum + hb >= need) { bsel = b; break; }
          cum += hb;
        }
        s_pref = prefix | ((unsigned)bsel << sh);
        s_cA = cA + cum;
      }
    }
    __syncthreads();
    prefix = s_pref; cA = s_cA;
    pmask |= (unsigned)(widths[pass] - 1) << sh;
    __syncthreads();
  }
  const float tv = __uint_as_float(prefix);
  // lists: 200 rows across 16 waves
  for (int j = wave; j < NN; j += 16) {
    const float* row = adjS + (size_t)g * ADJN + (size_t)j * NN;
    unsigned char* l1 = list1 + ((size_t)g * NN + j) * NN;
    unsigned char* l2 = list2 + ((size_t)g * NN + j) * NN;
    int c1 = 0, c2 = 0;
#pragma unroll
    for (int r = 0; r < 4; ++r) {
      int i = r * 64 + lane;
      bool p1 = false, p2 = false;
      if (i < NN) { float vv = row[i]; p1 = (vv >= tv); p2 = p1 && (i != j); }
      unsigned long long b1 = __ballot(p1);
      unsigned long long b2 = __ballot(p2);
      unsigned long long below = (lane == 0) ? 0ull : ((~0ull) >> (64 - lane));
      if (p1) l1[c1 + __popcll(b1 & below)] = (unsigned char)i;
      if (p2) l2[c2 + __popcll(b2 & below)] = (unsigned char)i;
      c1 += (int)__popcll(b1); c2 += (int)__popcll(b2);
    }
    if (lane == 0) {
      l2[c2] = (unsigned char)j;
      cnt1[g * NN + j] = c1;
      cnt2[g * NN + j] = c2 + 1;
    }
  }
}

// ---------------------------------------------------------------------------
// K6: fused node-MLP(2->8 gelu ->16)+LN(16) -> xl1/xr1 via MFMA (K=16 padded)
// One weight matrix staged at a time (40KB LDS) -> >=2 blocks/CU.
// ---------------------------------------------------------------------------
__global__ __launch_bounds__(256) void lin16_fused(
    const float* __restrict__ meanv, const float* __restrict__ stdv,
    const float* __restrict__ feW1, const float* __restrict__ feb1,
    const float* __restrict__ feW2, const float* __restrict__ feb2,
    const float* __restrict__ ln_g, const float* __restrict__ ln_b,
    const float* __restrict__ Wl, const float* __restrict__ bl,
    const float* __restrict__ Wr, const float* __restrict__ br,
    _Float16* __restrict__ outl, _Float16* __restrict__ outr) {
  __shared__ _Float16 Wt[1024 * 20];   // [n][k] stride 20
  __shared__ float x0s[16][17];
  const int t = threadIdx.x, wave = t >> 6, lane = t & 63;
  const int mbase = blockIdx.x * 16;   // 800 blocks
  // node MLP + LN: t = n*16 + o
  {
    const int n = t >> 4, o = t & 15;
    const float mu = meanv[mbase + n], sd = stdv[mbase + n];
    float h1[8];
#pragma unroll
    for (int k = 0; k < 8; ++k) h1[k] = gelu_f(mu * feW1[k] + sd * feW1[8 + k] + feb1[k]);
    float h2 = feb2[o];
#pragma unroll
    for (int k = 0; k < 8; ++k) h2 += h1[k] * feW2[k * 16 + o];
    float s = h2;
#pragma unroll
    for (int off = 1; off < 16; off <<= 1) s += __shfl_xor(s, off);
    s *= (1.0f / 16.0f);
    const float d = h2 - s;
    float vv = d * d;
#pragma unroll
    for (int off = 1; off < 16; off <<= 1) vv += __shfl_xor(vv, off);
    vv *= (1.0f / 16.0f);
    x0s[n][o] = d * (1.0f / sqrtf(vv + 1e-5f)) * ln_g[o] + ln_b[o];
  }
  __syncthreads();
  const int mrow = lane & 15, kg = lane >> 4;
  F16X8U af;
#pragma unroll
  for (int q = 0; q < 8; ++q) af.v[q] = (_Float16)0.f;
  if (kg < 2) {
#pragma unroll
    for (int q = 0; q < 8; ++q) af.v[q] = (_Float16)x0s[mrow][kg * 8 + q];
  }
#pragma unroll
  for (int mat = 0; mat < 2; ++mat) {
    if (mat) __syncthreads();
    const float* Wsrc = mat ? Wr : Wl;
    for (int i = t; i < 4096; i += 256) {
      const int k = i >> 8, n4 = (i & 255) * 4;
      float4 wv = *(const float4*)(Wsrc + (size_t)k * 1024 + n4);
      Wt[(n4 + 0) * 20 + k] = (_Float16)wv.x;
      Wt[(n4 + 1) * 20 + k] = (_Float16)wv.y;
      Wt[(n4 + 2) * 20 + k] = (_Float16)wv.z;
      Wt[(n4 + 3) * 20 + k] = (_Float16)wv.w;
    }
    __syncthreads();
    const float* bias = mat ? br : bl;
    _Float16* out = mat ? outr : outl;
#pragma unroll
    for (int nt = 0; nt < 16; ++nt) {
      const int n0 = wave * 256 + nt * 16;
      F16X8U bfv;
#pragma unroll
      for (int q = 0; q < 8; ++q) bfv.v[q] = (_Float16)0.f;
      if (kg < 2) bfv.v = *(const f16x8*)(Wt + (n0 + mrow) * 20 + kg * 8);
      f32x4 acc = {};
      acc = __builtin_amdgcn_mfma_f32_16x16x32_f16(af.v, bfv.v, acc, 0, 0, 0);
      const int col = n0 + mrow;
      const float bb = bias[col];
#pragma unroll
      for (int j = 0; j < 4; ++j)
        out[(size_t)(mbase + kg * 4 + j) * 1024 + col] = (_Float16)(acc[j] + bb);
    }
  }
}

// ---------------------------------------------------------------------------
// K9: NT-GEMM 128x128 tile, BK=64, dbuf LDS, XOR-swizzle.
// sync moved BEFORE prefetch-issue so loads fly across the compute phase.
// ---------------------------------------------------------------------------
__global__ __launch_bounds__(256, 2) void gemm_nt(
    const _Float16* __restrict__ A,
    const _Float16* __restrict__ Bt0, const _Float16* __restrict__ Bt1,
    const float* __restrict__ b0, const float* __restrict__ b1,
    _Float16* __restrict__ out0, _Float16* __restrict__ out1,
    int Nhalf, int tilesPerHalf) {
  __shared__ _Float16 As[2][128 * 64];
  __shared__ _Float16 Bs[2][128 * 64];
  const int mbase = blockIdx.y * 128;
  const int hsel = blockIdx.x / tilesPerHalf;
  const int ncol0 = (blockIdx.x % tilesPerHalf) * 128;
  const _Float16* Bt = hsel ? Bt1 : Bt0;
  const float* bias = hsel ? b1 : b0;
  _Float16* out = hsel ? out1 : out0;
  const int t = threadIdx.x, wave = t >> 6, lane = t & 63;
  const int wm = wave >> 1, wn = wave & 1;
  f32x4 acc[4][4] = {};
  int crow[4], gco[4], sto[4];
#pragma unroll
  for (int q = 0; q < 4; ++q) {
    const int c = q * 256 + t;
    crow[q] = c >> 3;
    const int sl = c & 7;
    gco[q] = sl * 8;
    sto[q] = crow[q] * 64 + ((sl ^ (crow[q] & 7)) << 3);
  }
  f16x8 ra[4], rb[4];
#pragma unroll
  for (int q = 0; q < 4; ++q) {
    ra[q] = *(const f16x8*)(A + (size_t)(mbase + crow[q]) * 1024 + gco[q]);
    rb[q] = *(const f16x8*)(Bt + (size_t)(ncol0 + crow[q]) * 1024 + gco[q]);
  }
  for (int kt = 0; kt < 16; ++kt) {
    const int p = kt & 1;
#pragma unroll
    for (int q = 0; q < 4; ++q) {
      *(f16x8*)(As[p] + sto[q]) = ra[q];
      *(f16x8*)(Bs[p] + sto[q]) = rb[q];
    }
    __syncthreads();
    if (kt < 15) {
      const int k0 = (kt + 1) * 64;
#pragma unroll
      for (int q = 0; q < 4; ++q) {
        ra[q] = *(const f16x8*)(A + (size_t)(mbase + crow[q]) * 1024 + k0 + gco[q]);
        rb[q] = *(const f16x8*)(Bt + (size_t)(ncol0 + crow[q]) * 1024 + k0 + gco[q]);
      }
    }
#pragma unroll
    for (int ks = 0; ks < 2; ++ks) {
      F16X8U af[4], bfv[4];
#pragma unroll
      for (int m = 0; m < 4; ++m) {
        const int row = wm * 64 + m * 16 + (lane & 15);
        const int kk = ks * 32 + (lane >> 4) * 8;
        af[m].v = *(const f16x8*)(As[p] + row * 64 + (kk ^ ((row & 7) << 3)));
      }
#pragma unroll
      for (int j = 0; j < 4; ++j) {
        const int row = wn * 64 + j * 16 + (lane & 15);
        const int kk = ks * 32 + (lane >> 4) * 8;
        bfv[j].v = *(const f16x8*)(Bs[p] + row * 64 + (kk ^ ((row & 7) << 3)));
      }
#pragma unroll
      for (int j = 0; j < 4; ++j)
#pragma unroll
        for (int m = 0; m < 4; ++m)
          acc[m][j] = __builtin_amdgcn_mfma_f32_16x16x32_f16(af[m].v, bfv[j].v, acc[m][j], 0, 0, 0);
    }
  }
#pragma unroll
  for (int j = 0; j < 4; ++j) {
    const int col = ncol0 + wn * 64 + j * 16 + (lane & 15);
    const float bb = bias[col];
#pragma unroll
    for (int m = 0; m < 4; ++m) {
#pragma unroll
      for (int vv = 0; vv < 4; ++vv) {
        const int row = mbase + wm * 64 + m * 16 + (lane >> 4) * 4 + vv;
        out[(size_t)row * Nhalf + col] = (_Float16)(acc[m][j][vv] + bb);
      }
    }
  }
}

// ---------------------------------------------------------------------------
// K7: GATv2 layer; per-wave xr slot (pipelined global load), no xr staging.
// ---------------------------------------------------------------------------
template <int C, int HC, bool USE_LL>
__global__ __launch_bounds__(1024, 4) void gat_layer(
    const _Float16* __restrict__ xlb, const _Float16* __restrict__ xrb,
    const float* __restrict__ attw, const float* __restrict__ biasw,
    const int* __restrict__ cnts, const unsigned char* __restrict__ lists,
    _Float16* __restrict__ outb) {
  extern __shared__ char smem[];
  constexpr int XLB = 200 * C * 2;
  constexpr int XRW = 16 * C * 2;
  _Float16* xr_s = (_Float16*)(smem + XLB);
  _Float16* aw = (_Float16*)(smem + XLB + XRW);
  unsigned char* ll = (unsigned char*)(smem + XLB + XRW + 6400);
  unsigned* att_s = (unsigned*)(smem + XLB + XRW + 6400 + (USE_LL ? 3200 : 0));
  const int g = blockIdx.x;
  const int hd = blockIdx.y;
  const int t = threadIdx.x, wave = t >> 6, lane = t & 63;
  constexpr int GRP = (C == 128) ? 16 : 32;
  constexpr int NG = 64 / GRP;
  const int grp = lane / GRP, li = lane % GRP;

  for (int ch = t; ch < 200 * (C / 8); ch += 1024) {
    const int node = ch / (C / 8), cc = (ch % (C / 8)) * 8;
    f16x8 v = *(const f16x8*)(xlb + (size_t)(g * 200 + node) * HC + hd * C + cc);
    *(f16x8*)(smem + (((node * C + cc) * 2) ^ ((node & 15) << 4))) = v;
  }
  for (int i = t; i < C / 2; i += 1024) {
    f16x2 a;
    a[0] = (_Float16)attw[hd * C + 2 * i];
    a[1] = (_Float16)attw[hd * C + 2 * i + 1];
    att_s[i] = __builtin_bit_cast(unsigned, a);
  }
  __syncthreads();

  _Float16* xr_w = xr_s + wave * C;
  f16x8 xrreg;
  if (lane < C / 8)
    xrreg = *(const f16x8*)(xrb + (size_t)(g * 200 + wave) * HC + hd * C + lane * 8);

  for (int jj = wave; jj < 200; jj += 16) {
    const int gn = g * 200 + jj;
    const int cnt = cnts[gn];
    const unsigned char* lst = lists + (size_t)gn * NN;
    if (lane < C / 8) {
      *(f16x8*)(xr_w + lane * 8) = xrreg;
      if (jj + 16 < 200)
        xrreg = *(const f16x8*)(xrb + (size_t)(gn + 16) * HC + hd * C + lane * 8);
    }
    float lg[4] = {-INFINITY, -INFINITY, -INFINITY, -INFINITY};
#pragma unroll
    for (int r = 0; r < 4; ++r) {
      const int e = (r << 6) + lane;
      if (e < cnt) {
        const int s = lst[e];
        if constexpr (USE_LL) ll[wave * 200 + e] = (unsigned char)s;
        const int swz = (s & 15) << 4;
        float accv[4] = {0.f, 0.f, 0.f, 0.f};
#pragma unroll
        for (int c0 = 0; c0 < C; c0 += 16) {
          const int ai = ((c0 >> 4) & 1) * 2;
          const unsigned* ap = att_s + c0 / 2;
          F16X8U xa, xb, raa, rbb;
          xa.v = *(const f16x8*)(smem + (((s * C + c0) * 2) ^ swz));
          xb.v = *(const f16x8*)(smem + (((s * C + c0 + 8) * 2) ^ swz));
          raa.v = *(const f16x8*)(xr_w + c0);
          rbb.v = *(const f16x8*)(xr_w + c0 + 8);
#pragma unroll
          for (int pq = 0; pq < 4; ++pq) {
            f16x2 z = xa.p[pq] + raa.p[pq];
            f16x2 zs = z * (_Float16)0.2f;
            f16x2 m = __builtin_elementwise_max(z, zs);
            accv[ai] = FDOT2(__builtin_bit_cast(f16x2, ap[pq]), m, accv[ai]);
            f16x2 z2 = xb.p[pq] + rbb.p[pq];
            f16x2 zs2 = z2 * (_Float16)0.2f;
            f16x2 m2 = __builtin_elementwise_max(z2, zs2);
            accv[ai + 1] = FDOT2(__builtin_bit_cast(f16x2, ap[4 + pq]), m2, accv[ai + 1]);
          }
        }
        lg[r] = (accv[0] + accv[1]) + (accv[2] + accv[3]);
      }
    }
    float mloc = fmaxf(fmaxf(lg[0], lg[1]), fmaxf(lg[2], lg[3]));
#pragma unroll
    for (int off = 32; off > 0; off >>= 1) mloc = fmaxf(mloc, __shfl_xor(mloc, off));
    float ex[4]; float ps = 0.f;
#pragma unroll
    for (int r = 0; r < 4; ++r) { ex[r] = __expf(lg[r] - mloc); ps += ex[r]; }
#pragma unroll
    for (int off = 32; off > 0; off >>= 1) ps += __shfl_xor(ps, off);
    const float denom = ps + 1e-16f;
#pragma unroll
    for (int r = 0; r < 4; ++r) {
      const int e = (r << 6) + lane;
      if (e < cnt) aw[wave * 200 + e] = (_Float16)(ex[r] / denom);
    }
    // parallel-edge-group aggregation: NG edges at a time, GRP lanes/edge
    float o[8] = {};
    for (int e0 = 0; e0 < cnt; e0 += NG) {
      const int e = e0 + grp;
      if (e < cnt) {
        const float a = (float)aw[wave * 200 + e];
        int s;
        if constexpr (USE_LL) s = ll[wave * 200 + e]; else s = lst[e];
        const int swz = (s & 15) << 4;
        f16x8 xv = *(const f16x8*)(smem + (((s * C + li * 8) * 2) ^ swz));
#pragma unroll
        for (int q = 0; q < 8; ++q) o[q] += a * (float)xv[q];
      }
    }
#pragma unroll
    for (int q = 0; q < 8; ++q) {
      if constexpr (GRP == 16) o[q] += __shfl_xor(o[q], 16);
      o[q] += __shfl_xor(o[q], 32);
    }
    if (grp == 0) {
      const int colb = hd * C + li * 8;
      f16x8 ov;
#pragma unroll
      for (int q = 0; q < 8; ++q) ov[q] = (_Float16)gelu_f(o[q] + biasw[colb + q]);
      *(f16x8*)(outb + (size_t)gn * HC + colb) = ov;
    }
  }
}

// ---------------------------------------------------------------------------
// K7-L3: GATv2 (H=1,C=512) chunked; group-parallel agg; fused pool
// ---------------------------------------------------------------------------
__global__ __launch_bounds__(1024, 4) void gat_l3(
    const _Float16* __restrict__ xlb, const _Float16* __restrict__ xrb,
    const float* __restrict__ attw, const float* __restrict__ biasw,
    const int* __restrict__ cnts, const unsigned char* __restrict__ lists,
    float* __restrict__ psum) {
  extern __shared__ char smem[];
  _Float16* xr_s = (_Float16*)(smem + 51200);
  float* plog = (float*)(smem + 64000);
  unsigned* att_s = (unsigned*)(smem + 104000);
  const int g = blockIdx.x, range = blockIdx.y, r0 = range * 50;
  const int t = threadIdx.x, wave = t >> 6, lane = t & 63;
  const int grp = lane >> 4, li = lane & 15;

  for (int chunk = 0; chunk < 4; ++chunk) {
    if (chunk) __syncthreads();
    for (int ch = t; ch < 200 * 16; ch += 1024) {
      const int node = ch >> 4, cc = (ch & 15) * 8;
      *(f16x8*)(smem + (((node * 128 + cc) * 2) ^ ((node & 15) << 4))) =
          *(const f16x8*)(xlb + (size_t)(g * 200 + node) * 512 + chunk * 128 + cc);
    }
    for (int ch = t; ch < 50 * 16; ch += 1024) {
      const int node = ch >> 4, cc = (ch & 15) * 8;
      *(f16x8*)(xr_s + node * 128 + cc) =
          *(const f16x8*)(xrb + (size_t)(g * 200 + r0 + node) * 512 + chunk * 128 + cc);
    }
    for (int i = t; i < 64; i += 1024) {
      f16x2 a;
      a[0] = (_Float16)attw[chunk * 128 + 2 * i];
      a[1] = (_Float16)attw[chunk * 128 + 2 * i + 1];
      att_s[i] = __builtin_bit_cast(unsigned, a);
    }
    __syncthreads();
    for (int jj = wave; jj < 50; jj += 16) {
      const int gn = g * 200 + r0 + jj;
      const int cnt = cnts[gn];
      const unsigned char* lst = lists + (size_t)gn * NN;
#pragma unroll
      for (int r = 0; r < 4; ++r) {
        const int e = (r << 6) + lane;
        if (e < cnt) {
          const int s = lst[e];
          const int swz = (s & 15) << 4;
          float accv[4] = {0.f, 0.f, 0.f, 0.f};
#pragma unroll
          for (int c0 = 0; c0 < 128; c0 += 16) {
            const int ai = ((c0 >> 4) & 1) * 2;
            const unsigned* ap = att_s + c0 / 2;
            F16X8U xa, xb, raa, rbb;
            xa.v = *(const f16x8*)(smem + (((s * 128 + c0) * 2) ^ swz));
            xb.v = *(const f16x8*)(smem + (((s * 128 + c0 + 8) * 2) ^ swz));
            raa.v = *(const f16x8*)(xr_s + jj * 128 + c0);
            rbb.v = *(const f16x8*)(xr_s + jj * 128 + c0 + 8);
#pragma unroll
            for (int pq = 0; pq < 4; ++pq) {
              f16x2 z = xa.p[pq] + raa.p[pq];
              f16x2 zs = z * (_Float16)0.2f;
              f16x2 m = __builtin_elementwise_max(z, zs);
              accv[ai] = FDOT2(__builtin_bit_cast(f16x2, ap[pq]), m, accv[ai]);
              f16x2 z2 = xb.p[pq] + rbb.p[pq];
              f16x2 zs2 = z2 * (_Float16)0.2f;
              f16x2 m2 = __builtin_elementwise_max(z2, zs2);
              accv[ai + 1] = FDOT2(__builtin_bit_cast(f16x2, ap[4 + pq]), m2, accv[ai + 1]);
            }
          }
          const float acc = (accv[0] + accv[1]) + (accv[2] + accv[3]);
          if (chunk == 0) plog[jj * 200 + e] = acc;
          else plog[jj * 200 + e] += acc;
        }
      }
    }
  }
  __syncthreads();
  for (int jj = wave; jj < 50; jj += 16) {
    const int gn = g * 200 + r0 + jj;
    const int cnt = cnts[gn];
    float lg[4] = {-INFINITY, -INFINITY, -INFINITY, -INFINITY};
#pragma unroll
    for (int r = 0; r < 4; ++r) {
      const int e = (r << 6) + lane;
      if (e < cnt) lg[r] = plog[jj * 200 + e];
    }
    float mloc = fmaxf(fmaxf(lg[0], lg[1]), fmaxf(lg[2], lg[3]));
#pragma unroll
    for (int off = 32; off > 0; off >>= 1) mloc = fmaxf(mloc, __shfl_xor(mloc, off));
    float ex[4]; float ps = 0.f;
#pragma unroll
    for (int r = 0; r < 4; ++r) { ex[r] = __expf(lg[r] - mloc); ps += ex[r]; }
#pragma unroll
    for (int off = 32; off > 0; off >>= 1) ps += __shfl_xor(ps, off);
    const float denom = ps + 1e-16f;
#pragma unroll
    for (int r = 0; r < 4; ++r) {
      const int e = (r << 6) + lane;
      if (e < cnt) plog[jj * 200 + e] = ex[r] / denom;
    }
  }
  for (int chunk = 0; chunk < 4; ++chunk) {
    __syncthreads();
    for (int ch = t; ch < 200 * 16; ch += 1024) {
      const int node = ch >> 4, cc = (ch & 15) * 8;
      *(f16x8*)(smem + (((node * 128 + cc) * 2) ^ ((node & 15) << 4))) =
          *(const f16x8*)(xlb + (size_t)(g * 200 + node) * 512 + chunk * 128 + cc);
    }
    __syncthreads();
    float p[8] = {};
    for (int jj = wave; jj < 50; jj += 16) {
      const int gn = g * 200 + r0 + jj;
      const int cnt = cnts[gn];
      const unsigned char* lst = lists + (size_t)gn * NN;
      float o[8] = {};
      for (int e0 = 0; e0 < cnt; e0 += 4) {
        const int e = e0 + grp;
        if (e < cnt) {
          const float a = plog[jj * 200 + e];
          const int s = lst[e];
          const int swz = (s & 15) << 4;
          f16x8 xv = *(const f16x8*)(smem + (((s * 128 + li * 8) * 2) ^ swz));
#pragma unroll
          for (int q = 0; q < 8; ++q) o[q] += a * (float)xv[q];
        }
      }
#pragma unroll
      for (int q = 0; q < 8; ++q) {
        o[q] += __shfl_xor(o[q], 16);
        o[q] += __shfl_xor(o[q], 32);
      }
      if (grp == 0) {
        const int colb = chunk * 128 + li * 8;
#pragma unroll
        for (int q = 0; q < 8; ++q) p[q] += gelu_f(o[q] + biasw[colb + q]);
      }
    }
    if (grp == 0) {
      const int slot = range * 16 + wave;
      float* pd = psum + ((size_t)slot * 64 + g) * 512 + chunk * 128 + li * 8;
      float4 a0 = {p[0], p[1], p[2], p[3]};
      float4 a1 = {p[4], p[5], p[6], p[7]};
      *(float4*)pd = a0;
      *(float4*)(pd + 4) = a1;
    }
  }
}

// ---------------------------------------------------------------------------
// K10: d_out[b][c] = (1/200) * sum over 64 partial slots
// ---------------------------------------------------------------------------
__global__ void finalize(const float* __restrict__ psum, float* __restrict__ out) {
  const int idx = blockIdx.x * 256 + threadIdx.x;  // 32768 exact
  float s = 0.f;
#pragma unroll
  for (int k = 0; k < 64; ++k) s += psum[(size_t)k * 32768 + idx];
  out[idx] = s * 0.005f;
}

// ---------------------------------------------------------------------------
extern "C" void kernel_launch(void* const* d_in, const int* in_sizes, int n_in,
                              void* d_out, int out_size, void* d_ws, size_t ws_size,
                              hipStream_t stream) {
  const float* raw_fc = (const float*)d_in[0];
  const float* gbW = (const float*)d_in[1];
  const float* gbb = (const float*)d_in[2];
  const float* feW1 = (const float*)d_in[3];
  const float* feb1 = (const float*)d_in[4];
  const float* feW2 = (const float*)d_in[5];
  const float* feb2 = (const float*)d_in[6];
  const float* ln_g = (const float*)d_in[7];
  const float* ln_b = (const float*)d_in[8];
  const float* W1l = (const float*)d_in[9];  const float* b1l = (const float*)d_in[10];
  const float* W1r = (const float*)d_in[11]; const float* b1r = (const float*)d_in[12];
  const float* att1 = (const float*)d_in[13]; const float* bias1 = (const float*)d_in[14];
  const float* W2l = (const float*)d_in[15]; const float* b2l = (const float*)d_in[16];
  const float* W2r = (const float*)d_in[17]; const float* b2r = (const float*)d_in[18];
  const float* att2 = (const float*)d_in[19]; const float* bias2 = (const float*)d_in[20];
  const float* W3l = (const float*)d_in[21]; const float* b3l = (const float*)d_in[22];
  const float* W3r = (const float*)d_in[23]; const float* b3r = (const float*)d_in[24];
  const float* att3 = (const float*)d_in[25]; const float* bias3 = (const float*)d_in[26];

  if (ws_size < 121000000) return;  // need ~115.4 MiB scratch

  char* w = (char*)d_ws;
  float* adj   = (float*)(w + 0);
  float* adjS  = (float*)(w + 10240000);
  float* meanv = (float*)(w + 20480000);
  float* stdv  = (float*)(w + 20531200);
  int* cnt1    = (int*)(w + 21401856);
  int* cnt2    = (int*)(w + 21453056);
  unsigned char* list1 = (unsigned char*)(w + 21504256);
  unsigned char* list2 = (unsigned char*)(w + 24064256);
  _Float16* bufA = (_Float16*)(w + 26624256);   // xl1 / xl2 / xl3
  _Float16* bufB = (_Float16*)(w + 52838656);   // xr1 / xr2 / xr3
  _Float16* bufC = (_Float16*)(w + 79053056);   // x2 / x3
  float* psum = (float*)(w + 105267456);        // 8,388,608 B (64 slots)
  short* Ahi  = (short*)(w + 113656064);
  short* Alo  = (short*)(w + 114168064);
  _Float16* Wt2l = (_Float16*)(w + 114680064);
  _Float16* Wt2r = (_Float16*)(w + 116777216);
  _Float16* Wt3l = (_Float16*)(w + 118874368);
  _Float16* Wt3r = (_Float16*)(w + 119922944);

  const int SMEM_L1 = 65152;    // 51200+4096+6400+3200+256
  const int SMEM_L2 = 117504;   // 102400+8192+6400+512
  const int SMEM_L3 = 104256;   // 51200+12800+40000+256
  hipFuncSetAttribute((const void*)gat_layer<128, 1024, true>,
                      hipFuncAttributeMaxDynamicSharedMemorySize, SMEM_L1);
  hipFuncSetAttribute((const void*)gat_layer<256, 1024, false>,
                      hipFuncAttributeMaxDynamicSharedMemorySize, SMEM_L2);
  hipFuncSetAttribute((const void*)gat_l3,
                      hipFuncAttributeMaxDynamicSharedMemorySize, SMEM_L3);

  prep_A<<<1000, 256, 0, stream>>>(raw_fc, Ahi, Alo);
  transp_all<<<dim3(32, 32, 4), 256, 0, stream>>>(W2l, W2r, W3l, W3r, Wt2l, Wt2r, Wt3l, Wt3r);
  build_adj<<<625, 256, 0, stream>>>(Ahi, Alo, gbW, gbb, adj);
  symmetrize<<<dim3(64, 16), 256, 0, stream>>>(adj, adjS);
  rowstats<<<3200, 256, 0, stream>>>(adjS, meanv, stdv);
  radix_lists<<<64, 1024, 0, stream>>>(adjS, cnt1, cnt2, list1, list2);
  lin16_fused<<<800, 256, 0, stream>>>(meanv, stdv, feW1, feb1, feW2, feb2, ln_g, ln_b,
                                       W1l, b1l, W1r, b1r, bufA, bufB);
  gat_layer<128, 1024, true><<<dim3(64, 8), 1024, SMEM_L1, stream>>>(
      bufA, bufB, att1, bias1, cnt1, list1, bufC);
  gemm_nt<<<dim3(16, 100), 256, 0, stream>>>(bufC, Wt2l, Wt2r, b2l, b2r, bufA, bufB, 1024, 8);
  gat_layer<256, 1024, false><<<dim3(64, 4), 1024, SMEM_L2, stream>>>(
      bufA, bufB, att2, bias2, cnt2, list2, bufC);
  gemm_nt<<<dim3(8, 100), 256, 0, stream>>>(bufC, Wt3l, Wt3r, b3l, b3r, bufA, bufB, 512, 4);
  gat_l3<<<dim3(64, 4), 1024, SMEM_L3, stream>>>(bufA, bufB, att3, bias3, cnt2, list2, psum);
  finalize<<<128, 256, 0, stream>>>(psum, (float*)d_out);
}

// Round 6
// 968.943 us; speedup vs baseline: 1.5354x; 1.0080x over previous
//
#include <hip/hip_runtime.h>
#include <hip/hip_fp16.h>
#include <math.h>
#include <cstdint>
#include <cstddef>

#define NGRAPH 64
#define NN 200
#define ADJN 40000
#define DIN 4000
#define NNODE 12800

typedef float    f32x4 __attribute__((ext_vector_type(4)));
typedef _Float16 f16x8 __attribute__((ext_vector_type(8)));
typedef _Float16 f16x4 __attribute__((ext_vector_type(4)));
typedef _Float16 f16x2 __attribute__((ext_vector_type(2)));
typedef short    bf8v  __attribute__((ext_vector_type(8)));
typedef short    bf4v  __attribute__((ext_vector_type(4)));

union BF8U  { bf8v v; bf4v h[2]; };
union F16X8U{ f16x8 v; f16x4 h[2]; f16x2 p[4]; };

__device__ __forceinline__ unsigned short f2bf(float f) {
  unsigned u = __float_as_uint(f);
  return (unsigned short)((u + 0x7fffu + ((u >> 16) & 1u)) >> 16);
}
__device__ __forceinline__ float bf2f(unsigned short s) {
  return __uint_as_float(((unsigned)s) << 16);
}
__device__ __forceinline__ float gelu_f(float x) {
  return x * 0.5f * (1.0f + erff(x * 0.70710678118654752f));
}

#if defined(__has_builtin)
#if __has_builtin(__builtin_amdgcn_fdot2)
#define FDOT2(a, b, c) __builtin_amdgcn_fdot2((a), (b), (c), false)
#endif
#endif
#ifndef FDOT2
#define FDOT2(a, b, c) ((c) + (float)(a)[0] * (float)(b)[0] + (float)(a)[1] * (float)(b)[1])
#endif

// async global->LDS, 16B per lane; lptr must be wave-uniform (HW adds lane*16)
__device__ __forceinline__ void glds16(const _Float16* g, _Float16* l) {
  __builtin_amdgcn_global_load_lds(
      (const __attribute__((address_space(1))) void*)g,
      (__attribute__((address_space(3))) void*)l, 16, 0, 0);
}

// ---------------------------------------------------------------------------
// K0: raw_fc -> hi/lo bf16 split
// ---------------------------------------------------------------------------
__global__ __launch_bounds__(256) void prep_A(const float* __restrict__ A,
                                              short* __restrict__ Ahi,
                                              short* __restrict__ Alo) {
  const int i = blockIdx.x * 256 + threadIdx.x;  // 256000 exact
  const float v = A[i];
  const unsigned short h = f2bf(v);
  Ahi[i] = (short)h;
  Alo[i] = (short)f2bf(v - bf2f(h));
}

// ---------------------------------------------------------------------------
// K0b: all 4 GEMM weights: W[k][n] f32 -> Wt[n][k] f16 (fused, blockIdx.z)
// ---------------------------------------------------------------------------
__global__ __launch_bounds__(256) void transp_all(
    const float* __restrict__ W2l, const float* __restrict__ W2r,
    const float* __restrict__ W3l, const float* __restrict__ W3r,
    _Float16* __restrict__ T2l, _Float16* __restrict__ T2r,
    _Float16* __restrict__ T3l, _Float16* __restrict__ T3r) {
  __shared__ float tile[32][33];
  const int z = blockIdx.z;
  if (z >= 2 && blockIdx.y >= 16) return;
  const float* src = (z == 0) ? W2l : (z == 1) ? W2r : (z == 2) ? W3l : W3r;
  _Float16* dst = (z == 0) ? T2l : (z == 1) ? T2r : (z == 2) ? T3l : T3r;
  const int N = (z < 2) ? 1024 : 512;
  const int K = 1024;
  const int bk = blockIdx.x * 32, bn = blockIdx.y * 32;
  const int tx = threadIdx.x & 31, ty = threadIdx.x >> 5;
#pragma unroll
  for (int r = 0; r < 32; r += 8) tile[ty + r][tx] = src[(size_t)(bk + ty + r) * N + bn + tx];
  __syncthreads();
#pragma unroll
  for (int r = 0; r < 32; r += 8)
    dst[(size_t)(bn + ty + r) * K + bk + tx] = (_Float16)tile[tx][ty + r];
}

// ---------------------------------------------------------------------------
// K1: adj = sigmoid(raw_fc @ gbW + gbb); split-bf16 MFMA.
// v4: W loaded transposed from global (per-k coalesced dwords) so each thread
// stores CONTIGUOUS b64 hi/lo rows -> kills the 8-way scalar-store conflicts.
// Schedule: sync -> issue(it+2) -> MFMA(buf p) -> convert(it+1) -> buf p^1.
// ---------------------------------------------------------------------------
#define BA_LOADW(WV, K0)                                                        \
  _Pragma("unroll") for (int q = 0; q < 8; ++q)                                 \
    WV[q] = W[(size_t)((K0) + kgrp * 8 + q) * ADJN + n0 + nn];

#define BA_CONV(PB, WV)                                                         \
  { bf4v h0, h1, l0, l1;                                                        \
    _Pragma("unroll") for (int i = 0; i < 4; ++i) {                             \
      unsigned short hh = (unsigned short)(__float_as_uint(WV[i]) >> 16);       \
      h0[i] = (short)hh;                                                        \
      l0[i] = (short)f2bf(WV[i] - bf2f(hh));                                    \
    }                                                                           \
    _Pragma("unroll") for (int i = 0; i < 4; ++i) {                             \
      unsigned short hh = (unsigned short)(__float_as_uint(WV[4 + i]) >> 16);   \
      h1[i] = (short)hh;                                                        \
      l1[i] = (short)f2bf(WV[4 + i] - bf2f(hh));                                \
    }                                                                           \
    *(bf4v*)(Wh[PB] + nn * 44 + kgrp * 8)     = h0;                             \
    *(bf4v*)(Wh[PB] + nn * 44 + kgrp * 8 + 4) = h1;                             \
    *(bf4v*)(Wl[PB] + nn * 44 + kgrp * 8)     = l0;                             \
    *(bf4v*)(Wl[PB] + nn * 44 + kgrp * 8 + 4) = l1;                             \
  }

#define BA_MFMA(PB, AHC, ALC)                                                   \
  _Pragma("unroll") for (int j = 0; j < 4; ++j) {                               \
    const int bc = (j * 16 + (lane & 15)) * 44 + kb;                            \
    BF8U bh, bl;                                                                \
    bh.h[0] = *(const bf4v*)(Wh[PB] + bc);                                      \
    bh.h[1] = *(const bf4v*)(Wh[PB] + bc + 4);                                  \
    bl.h[0] = *(const bf4v*)(Wl[PB] + bc);                                      \
    bl.h[1] = *(const bf4v*)(Wl[PB] + bc + 4);                                  \
    acc[j] = __builtin_amdgcn_mfma_f32_16x16x32_bf16(AHC, bh.v, acc[j], 0, 0, 0); \
    acc[j] = __builtin_amdgcn_mfma_f32_16x16x32_bf16(AHC, bl.v, acc[j], 0, 0, 0); \
    acc[j] = __builtin_amdgcn_mfma_f32_16x16x32_bf16(ALC, bh.v, acc[j], 0, 0, 0); \
  }

#define BA_LOADA(AH, AL, K0)                                                    \
  AH = *(const bf8v*)(Ahi + (size_t)arow * DIN + (K0) + kb);                    \
  AL = *(const bf8v*)(Alo + (size_t)arow * DIN + (K0) + kb);

__global__ __launch_bounds__(256) void build_adj(
    const short* __restrict__ Ahi, const short* __restrict__ Alo,
    const float* __restrict__ W, const float* __restrict__ bias,
    float* __restrict__ adj) {
  __shared__ short Wh[2][64 * 44], Wl[2][64 * 44];
  const int t = threadIdx.x, wave = t >> 6, lane = t & 63;
  const int n0 = blockIdx.x * 64;
  const int nn = t & 63, kgrp = t >> 6;   // staging coords: one n, 8 k
  const int kb = (lane >> 4) * 8;
  const int arow = wave * 16 + (lane & 15);
  f32x4 acc[4] = {};
  float wva[8], wvb[8];
  bf8v ahs0, als0, ahs1, als1;
  // prologue: issue tiles 0 (set a) and 1 (set b); convert tile0 -> buf0
  BA_LOADW(wva, 0)
  BA_LOADA(ahs0, als0, 0)
  BA_LOADW(wvb, 32)
  BA_LOADA(ahs1, als1, 32)
  BA_CONV(0, wva)
  for (int it = 0; it < 124; it += 2) {
    // even body: tile it, buf 0
    __syncthreads();
    {
      const bf8v ahc = ahs0, alc = als0;
      if (it + 2 < 125) {
        const int k2 = (it + 2) * 32;
        BA_LOADW(wva, k2)
        BA_LOADA(ahs0, als0, k2)
      }
      BA_MFMA(0, ahc, alc)
      BA_CONV(1, wvb)                 // tile it+1 -> buf1 (always exists)
    }
    // odd body: tile it+1, buf 1
    __syncthreads();
    {
      const bf8v ahc = ahs1, alc = als1;
      if (it + 3 < 125) {
        const int k2 = (it + 3) * 32;
        BA_LOADW(wvb, k2)
        BA_LOADA(ahs1, als1, k2)
      }
      BA_MFMA(1, ahc, alc)
      if (it + 2 < 125) BA_CONV(0, wva)   // tile it+2 -> buf0
    }
  }
  // tail: tile 124, buf 0
  __syncthreads();
  BA_MFMA(0, ahs0, als0)
#pragma unroll
  for (int j = 0; j < 4; ++j) {
    const int col = n0 + j * 16 + (lane & 15);
    const float bb = bias[col];
#pragma unroll
    for (int vv = 0; vv < 4; ++vv) {
      const int row = wave * 16 + (lane >> 4) * 4 + vv;
      float x = acc[j][vv] + bb;
      adj[(size_t)row * ADJN + col] = 1.0f / (1.0f + __expf(-x));
    }
  }
}

// ---------------------------------------------------------------------------
// K2: adjS = 0.5*(adj + adj^T), LDS-tiled
// ---------------------------------------------------------------------------
__global__ __launch_bounds__(256) void symmetrize(const float* __restrict__ adj,
                                                  float* __restrict__ adjS) {
  __shared__ float tl[64][65];
  const int g = blockIdx.x;
  const int i0 = (blockIdx.y >> 2) * 64, j0 = (blockIdx.y & 3) * 64;
  const int tx = threadIdx.x & 63, ty = threadIdx.x >> 6;
  const float* ag = adj + (size_t)g * ADJN;
#pragma unroll
  for (int r = 0; r < 64; r += 4) {
    const int jr = j0 + ty + r;
    tl[ty + r][tx] = (jr < NN && i0 + tx < NN) ? ag[jr * NN + i0 + tx] : 0.f;
  }
  __syncthreads();
#pragma unroll
  for (int r = 0; r < 64; r += 4) {
    const int i = i0 + ty + r, j = j0 + tx;
    if (i < NN && j < NN)
      adjS[(size_t)g * ADJN + i * NN + j] = 0.5f * (ag[i * NN + j] + tl[tx][ty + r]);
  }
}

// ---------------------------------------------------------------------------
// K2b: per-row mean / std(ddof=1)
// ---------------------------------------------------------------------------
__global__ __launch_bounds__(256) void rowstats(const float* __restrict__ adjS,
                                                float* __restrict__ meanv,
                                                float* __restrict__ stdv) {
  const int row = blockIdx.x * 4 + (threadIdx.x >> 6);
  const int lane = threadIdx.x & 63;
  const float* r = adjS + (size_t)row * NN;
  float s = 0.f, q = 0.f;
#pragma unroll
  for (int k = 0; k < 4; ++k) {
    int i = k * 64 + lane;
    if (i < NN) { float v = r[i]; s += v; q += v * v; }
  }
#pragma unroll
  for (int off = 32; off > 0; off >>= 1) { s += __shfl_xor(s, off); q += __shfl_xor(q, off); }
  if (lane == 0) {
    float m = s * (1.0f / 200.0f);
    float var = (q - 200.0f * m * m) * (1.0f / 199.0f);
    var = fmaxf(var, 0.f);
    meanv[row] = m;
    stdv[row] = sqrtf(var) + 1e-6f;
  }
}

// ---------------------------------------------------------------------------
// K3: fused radix-select (4-copy hist) + per-dst neighbor lists. 64 blocks.
// ---------------------------------------------------------------------------
__global__ __launch_bounds__(1024) void radix_lists(
    const float* __restrict__ adjS,
    int* __restrict__ cnt1, int* __restrict__ cnt2,
    unsigned char* __restrict__ list1, unsigned char* __restrict__ list2) {
  __shared__ unsigned hist[4 * 2048];
  __shared__ unsigned s_pref, s_cA;
  const int g = blockIdx.x, t = threadIdx.x, lane = t & 63, wave = t >> 6;
  const float* v = adjS + (size_t)g * ADJN;
  unsigned prefix = 0, pmask = 0, cA = 0;
  const int shifts[3] = {20, 9, 0};
  const int widths[3] = {2048, 2048, 512};
  for (int pass = 0; pass < 3; ++pass) {
    const int nb = widths[pass], sh = shifts[pass];
    for (int i = t; i < 8192; i += 1024) hist[i] = 0u;
    __syncthreads();
    const int cpy = (lane & 3) * 2048;
    for (int e = t; e < ADJN; e += 1024) {
      unsigned u = __float_as_uint(v[e]);
      if ((u & pmask) == prefix) atomicAdd(&hist[cpy + ((u >> sh) & (nb - 1))], 1u);
    }
    __syncthreads();
    if (t < 64) {
      const int CH = nb >> 6;
      unsigned lsum = 0;
      for (int i = 0; i < CH; ++i) {
        const int b = t * CH + i;
        lsum += hist[b] + hist[2048 + b] + hist[4096 + b] + hist[6144 + b];
      }
      unsigned s = lsum;
#pragma unroll
      for (int off = 1; off < 64; off <<= 1) {
        unsigned o = __shfl_down(s, off);
        if (lane + off < 64) s += o;
      }
      const unsigned need = 10000u - cA;
      unsigned sn = __shfl_down(s, 1);
      const unsigned snext = (lane == 63) ? 0u : sn;
      if (s >= need && snext < need) {
        unsigned cum = snext;
        int bsel = t * CH;
        for (int i = CH - 1; i >= 0; --i) {
          const int b = t * CH + i;
          unsigned hb = hist[b] + hist[2048 + b] + hist[4096 + b] + hist[6144 + b];
          if (cum + hb >= need) { bsel = b; break; }
          cum += hb;
        }
        s_pref = prefix | ((unsigned)bsel << sh);
        s_cA = cA + cum;
      }
    }
    __syncthreads();
    prefix = s_pref; cA = s_cA;
    pmask |= (unsigned)(widths[pass] - 1) << sh;
    __syncthreads();
  }
  const float tv = __uint_as_float(prefix);
  for (int j = wave; j < NN; j += 16) {
    const float* row = adjS + (size_t)g * ADJN + (size_t)j * NN;
    unsigned char* l1 = list1 + ((size_t)g * NN + j) * NN;
    unsigned char* l2 = list2 + ((size_t)g * NN + j) * NN;
    int c1 = 0, c2 = 0;
#pragma unroll
    for (int r = 0; r < 4; ++r) {
      int i = r * 64 + lane;
      bool p1 = false, p2 = false;
      if (i < NN) { float vv = row[i]; p1 = (vv >= tv); p2 = p1 && (i != j); }
      unsigned long long b1 = __ballot(p1);
      unsigned long long b2 = __ballot(p2);
      unsigned long long below = (lane == 0) ? 0ull : ((~0ull) >> (64 - lane));
      if (p1) l1[c1 + __popcll(b1 & below)] = (unsigned char)i;
      if (p2) l2[c2 + __popcll(b2 & below)] = (unsigned char)i;
      c1 += (int)__popcll(b1); c2 += (int)__popcll(b2);
    }
    if (lane == 0) {
      l2[c2] = (unsigned char)j;
      cnt1[g * NN + j] = c1;
      cnt2[g * NN + j] = c2 + 1;
    }
  }
}

// ---------------------------------------------------------------------------
// K6: fused node-MLP(2->8 gelu ->16)+LN(16) -> xl1/xr1 via MFMA (K=16 padded)
// ---------------------------------------------------------------------------
__global__ __launch_bounds__(256) void lin16_fused(
    const float* __restrict__ meanv, const float* __restrict__ stdv,
    const float* __restrict__ feW1, const float* __restrict__ feb1,
    const float* __restrict__ feW2, const float* __restrict__ feb2,
    const float* __restrict__ ln_g, const float* __restrict__ ln_b,
    const float* __restrict__ Wl, const float* __restrict__ bl,
    const float* __restrict__ Wr, const float* __restrict__ br,
    _Float16* __restrict__ outl, _Float16* __restrict__ outr) {
  __shared__ _Float16 Wt[1024 * 20];
  __shared__ float x0s[16][17];
  const int t = threadIdx.x, wave = t >> 6, lane = t & 63;
  const int mbase = blockIdx.x * 16;
  {
    const int n = t >> 4, o = t & 15;
    const float mu = meanv[mbase + n], sd = stdv[mbase + n];
    float h1[8];
#pragma unroll
    for (int k = 0; k < 8; ++k) h1[k] = gelu_f(mu * feW1[k] + sd * feW1[8 + k] + feb1[k]);
    float h2 = feb2[o];
#pragma unroll
    for (int k = 0; k < 8; ++k) h2 += h1[k] * feW2[k * 16 + o];
    float s = h2;
#pragma unroll
    for (int off = 1; off < 16; off <<= 1) s += __shfl_xor(s, off);
    s *= (1.0f / 16.0f);
    const float d = h2 - s;
    float vv = d * d;
#pragma unroll
    for (int off = 1; off < 16; off <<= 1) vv += __shfl_xor(vv, off);
    vv *= (1.0f / 16.0f);
    x0s[n][o] = d * (1.0f / sqrtf(vv + 1e-5f)) * ln_g[o] + ln_b[o];
  }
  __syncthreads();
  const int mrow = lane & 15, kg = lane >> 4;
  F16X8U af;
#pragma unroll
  for (int q = 0; q < 8; ++q) af.v[q] = (_Float16)0.f;
  if (kg < 2) {
#pragma unroll
    for (int q = 0; q < 8; ++q) af.v[q] = (_Float16)x0s[mrow][kg * 8 + q];
  }
#pragma unroll
  for (int mat = 0; mat < 2; ++mat) {
    if (mat) __syncthreads();
    const float* Wsrc = mat ? Wr : Wl;
    for (int i = t; i < 4096; i += 256) {
      const int k = i >> 8, n4 = (i & 255) * 4;
      float4 wv = *(const float4*)(Wsrc + (size_t)k * 1024 + n4);
      Wt[(n4 + 0) * 20 + k] = (_Float16)wv.x;
      Wt[(n4 + 1) * 20 + k] = (_Float16)wv.y;
      Wt[(n4 + 2) * 20 + k] = (_Float16)wv.z;
      Wt[(n4 + 3) * 20 + k] = (_Float16)wv.w;
    }
    __syncthreads();
    const float* bias = mat ? br : bl;
    _Float16* out = mat ? outr : outl;
#pragma unroll
    for (int nt = 0; nt < 16; ++nt) {
      const int n0 = wave * 256 + nt * 16;
      F16X8U bfv;
#pragma unroll
      for (int q = 0; q < 8; ++q) bfv.v[q] = (_Float16)0.f;
      if (kg < 2) bfv.v = *(const f16x8*)(Wt + (n0 + mrow) * 20 + kg * 8);
      f32x4 acc = {};
      acc = __builtin_amdgcn_mfma_f32_16x16x32_f16(af.v, bfv.v, acc, 0, 0, 0);
      const int col = n0 + mrow;
      const float bb = bias[col];
#pragma unroll
      for (int j = 0; j < 4; ++j)
        out[(size_t)(mbase + kg * 4 + j) * 1024 + col] = (_Float16)(acc[j] + bb);
    }
  }
}

// ---------------------------------------------------------------------------
// K9: NT-GEMM 128x128 tile, BK=64, dbuf LDS via global_load_lds (16B),
// pre-swizzled per-lane source + linear LDS dest + swizzled ds_read.
// Issue tile kt+1 right after barrier; 1 barrier/kt (m97 schedule).
// ---------------------------------------------------------------------------
__global__ __launch_bounds__(256, 2) void gemm_nt(
    const _Float16* __restrict__ A,
    const _Float16* __restrict__ Bt0, const _Float16* __restrict__ Bt1,
    const float* __restrict__ b0, const float* __restrict__ b1,
    _Float16* __restrict__ out0, _Float16* __restrict__ out1,
    int Nhalf, int tilesPerHalf) {
  __shared__ _Float16 As[2][128 * 64];
  __shared__ _Float16 Bs[2][128 * 64];
  const int mbase = blockIdx.y * 128;
  const int hsel = blockIdx.x / tilesPerHalf;
  const int ncol0 = (blockIdx.x % tilesPerHalf) * 128;
  const _Float16* Bt = hsel ? Bt1 : Bt0;
  const float* bias = hsel ? b1 : b0;
  _Float16* out = hsel ? out1 : out0;
  const int t = threadIdx.x, wave = t >> 6, lane = t & 63;
  const int wm = wave >> 1, wn = wave & 1;
  f32x4 acc[4][4] = {};
  // staging: chunk c' = wave*4+c covers rows c'*8..+7; lane: row srow, src granule swizzled
  const int srow = lane >> 3;                 // 0..7 within chunk
  const int sg = (lane & 7) ^ srow;           // pre-swizzled source granule (16B units)
  // prologue: issue tile 0 -> buf 0
#pragma unroll
  for (int c = 0; c < 4; ++c) {
    const int rbase = wave * 32 + c * 8;
    glds16(A + (size_t)(mbase + rbase + srow) * 1024 + sg * 8, As[0] + rbase * 64);
    glds16(Bt + (size_t)(ncol0 + rbase + srow) * 1024 + sg * 8, Bs[0] + rbase * 64);
  }
  __syncthreads();
  for (int kt = 0; kt < 16; ++kt) {
    const int p = kt & 1;
    if (kt < 15) {
      const int k0 = (kt + 1) * 64;
#pragma unroll
      for (int c = 0; c < 4; ++c) {
        const int rbase = wave * 32 + c * 8;
        glds16(A + (size_t)(mbase + rbase + srow) * 1024 + k0 + sg * 8, As[p ^ 1] + rbase * 64);
        glds16(Bt + (size_t)(ncol0 + rbase + srow) * 1024 + k0 + sg * 8, Bs[p ^ 1] + rbase * 64);
      }
    }
#pragma unroll
    for (int ks = 0; ks < 2; ++ks) {
      F16X8U af[4], bfv[4];
#pragma unroll
      for (int m = 0; m < 4; ++m) {
        const int row = wm * 64 + m * 16 + (lane & 15);
        const int kk = ks * 32 + (lane >> 4) * 8;
        af[m].v = *(const f16x8*)(As[p] + row * 64 + (kk ^ ((row & 7) << 3)));
      }
#pragma unroll
      for (int j = 0; j < 4; ++j) {
        const int row = wn * 64 + j * 16 + (lane & 15);
        const int kk = ks * 32 + (lane >> 4) * 8;
        bfv[j].v = *(const f16x8*)(Bs[p] + row * 64 + (kk ^ ((row & 7) << 3)));
      }
#pragma unroll
      for (int j = 0; j < 4; ++j)
#pragma unroll
        for (int m = 0; m < 4; ++m)
          acc[m][j] = __builtin_amdgcn_mfma_f32_16x16x32_f16(af[m].v, bfv[j].v, acc[m][j], 0, 0, 0);
    }
    __syncthreads();
  }
#pragma unroll
  for (int j = 0; j < 4; ++j) {
    const int col = ncol0 + wn * 64 + j * 16 + (lane & 15);
    const float bb = bias[col];
#pragma unroll
    for (int m = 0; m < 4; ++m) {
#pragma unroll
      for (int vv = 0; vv < 4; ++vv) {
        const int row = mbase + wm * 64 + m * 16 + (lane >> 4) * 4 + vv;
        out[(size_t)row * Nhalf + col] = (_Float16)(acc[m][j][vv] + bb);
      }
    }
  }
}

// ---------------------------------------------------------------------------
// K7: GATv2 layer; per-wave xr slot (pipelined global load), no xr staging.
// ---------------------------------------------------------------------------
template <int C, int HC, bool USE_LL>
__global__ __launch_bounds__(1024, 4) void gat_layer(
    const _Float16* __restrict__ xlb, const _Float16* __restrict__ xrb,
    const float* __restrict__ attw, const float* __restrict__ biasw,
    const int* __restrict__ cnts, const unsigned char* __restrict__ lists,
    _Float16* __restrict__ outb) {
  extern __shared__ char smem[];
  constexpr int XLB = 200 * C * 2;
  constexpr int XRW = 16 * C * 2;
  _Float16* xr_s = (_Float16*)(smem + XLB);
  _Float16* aw = (_Float16*)(smem + XLB + XRW);
  unsigned char* ll = (unsigned char*)(smem + XLB + XRW + 6400);
  unsigned* att_s = (unsigned*)(smem + XLB + XRW + 6400 + (USE_LL ? 3200 : 0));
  const int g = blockIdx.x;
  const int hd = blockIdx.y;
  const int t = threadIdx.x, wave = t >> 6, lane = t & 63;
  constexpr int GRP = (C == 128) ? 16 : 32;
  constexpr int NG = 64 / GRP;
  const int grp = lane / GRP, li = lane % GRP;

  for (int ch = t; ch < 200 * (C / 8); ch += 1024) {
    const int node = ch / (C / 8), cc = (ch % (C / 8)) * 8;
    f16x8 v = *(const f16x8*)(xlb + (size_t)(g * 200 + node) * HC + hd * C + cc);
    *(f16x8*)(smem + (((node * C + cc) * 2) ^ ((node & 15) << 4))) = v;
  }
  for (int i = t; i < C / 2; i += 1024) {
    f16x2 a;
    a[0] = (_Float16)attw[hd * C + 2 * i];
    a[1] = (_Float16)attw[hd * C + 2 * i + 1];
    att_s[i] = __builtin_bit_cast(unsigned, a);
  }
  __syncthreads();

  _Float16* xr_w = xr_s + wave * C;
  f16x8 xrreg;
  if (lane < C / 8)
    xrreg = *(const f16x8*)(xrb + (size_t)(g * 200 + wave) * HC + hd * C + lane * 8);

  for (int jj = wave; jj < 200; jj += 16) {
    const int gn = g * 200 + jj;
    const int cnt = cnts[gn];
    const unsigned char* lst = lists + (size_t)gn * NN;
    if (lane < C / 8) {
      *(f16x8*)(xr_w + lane * 8) = xrreg;
      if (jj + 16 < 200)
        xrreg = *(const f16x8*)(xrb + (size_t)(gn + 16) * HC + hd * C + lane * 8);
    }
    float lg[4] = {-INFINITY, -INFINITY, -INFINITY, -INFINITY};
#pragma unroll
    for (int r = 0; r < 4; ++r) {
      const int e = (r << 6) + lane;
      if (e < cnt) {
        const int s = lst[e];
        if constexpr (USE_LL) ll[wave * 200 + e] = (unsigned char)s;
        const int swz = (s & 15) << 4;
        float accv[4] = {0.f, 0.f, 0.f, 0.f};
#pragma unroll
        for (int c0 = 0; c0 < C; c0 += 16) {
          const int ai = ((c0 >> 4) & 1) * 2;
          const unsigned* ap = att_s + c0 / 2;
          F16X8U xa, xb, raa, rbb;
          xa.v = *(const f16x8*)(smem + (((s * C + c0) * 2) ^ swz));
          xb.v = *(const f16x8*)(smem + (((s * C + c0 + 8) * 2) ^ swz));
          raa.v = *(const f16x8*)(xr_w + c0);
          rbb.v = *(const f16x8*)(xr_w + c0 + 8);
#pragma unroll
          for (int pq = 0; pq < 4; ++pq) {
            f16x2 z = xa.p[pq] + raa.p[pq];
            f16x2 zs = z * (_Float16)0.2f;
            f16x2 m = __builtin_elementwise_max(z, zs);
            accv[ai] = FDOT2(__builtin_bit_cast(f16x2, ap[pq]), m, accv[ai]);
            f16x2 z2 = xb.p[pq] + rbb.p[pq];
            f16x2 zs2 = z2 * (_Float16)0.2f;
            f16x2 m2 = __builtin_elementwise_max(z2, zs2);
            accv[ai + 1] = FDOT2(__builtin_bit_cast(f16x2, ap[4 + pq]), m2, accv[ai + 1]);
          }
        }
        lg[r] = (accv[0] + accv[1]) + (accv[2] + accv[3]);
      }
    }
    float mloc = fmaxf(fmaxf(lg[0], lg[1]), fmaxf(lg[2], lg[3]));
#pragma unroll
    for (int off = 32; off > 0; off >>= 1) mloc = fmaxf(mloc, __shfl_xor(mloc, off));
    float ex[4]; float ps = 0.f;
#pragma unroll
    for (int r = 0; r < 4; ++r) { ex[r] = __expf(lg[r] - mloc); ps += ex[r]; }
#pragma unroll
    for (int off = 32; off > 0; off >>= 1) ps += __shfl_xor(ps, off);
    const float denom = ps + 1e-16f;
#pragma unroll
    for (int r = 0; r < 4; ++r) {
      const int e = (r << 6) + lane;
      if (e < cnt) aw[wave * 200 + e] = (_Float16)(ex[r] / denom);
    }
    float o[8] = {};
    for (int e0 = 0; e0 < cnt; e0 += NG) {
      const int e = e0 + grp;
      if (e < cnt) {
        const float a = (float)aw[wave * 200 + e];
        int s;
        if constexpr (USE_LL) s = ll[wave * 200 + e]; else s = lst[e];
        const int swz = (s & 15) << 4;
        f16x8 xv = *(const f16x8*)(smem + (((s * C + li * 8) * 2) ^ swz));
#pragma unroll
        for (int q = 0; q < 8; ++q) o[q] += a * (float)xv[q];
      }
    }
#pragma unroll
    for (int q = 0; q < 8; ++q) {
      if constexpr (GRP == 16) o[q] += __shfl_xor(o[q], 16);
      o[q] += __shfl_xor(o[q], 32);
    }
    if (grp == 0) {
      const int colb = hd * C + li * 8;
      f16x8 ov;
#pragma unroll
      for (int q = 0; q < 8; ++q) ov[q] = (_Float16)gelu_f(o[q] + biasw[colb + q]);
      *(f16x8*)(outb + (size_t)gn * HC + colb) = ov;
    }
  }
}

// ---------------------------------------------------------------------------
// K7-L3: GATv2 (H=1,C=512) chunked; group-parallel agg; fused pool
// ---------------------------------------------------------------------------
__global__ __launch_bounds__(1024, 4) void gat_l3(
    const _Float16* __restrict__ xlb, const _Float16* __restrict__ xrb,
    const float* __restrict__ attw, const float* __restrict__ biasw,
    const int* __restrict__ cnts, const unsigned char* __restrict__ lists,
    float* __restrict__ psum) {
  extern __shared__ char smem[];
  _Float16* xr_s = (_Float16*)(smem + 51200);
  float* plog = (float*)(smem + 64000);
  unsigned* att_s = (unsigned*)(smem + 104000);
  const int g = blockIdx.x, range = blockIdx.y, r0 = range * 50;
  const int t = threadIdx.x, wave = t >> 6, lane = t & 63;
  const int grp = lane >> 4, li = lane & 15;

  for (int chunk = 0; chunk < 4; ++chunk) {
    if (chunk) __syncthreads();
    for (int ch = t; ch < 200 * 16; ch += 1024) {
      const int node = ch >> 4, cc = (ch & 15) * 8;
      *(f16x8*)(smem + (((node * 128 + cc) * 2) ^ ((node & 15) << 4))) =
          *(const f16x8*)(xlb + (size_t)(g * 200 + node) * 512 + chunk * 128 + cc);
    }
    for (int ch = t; ch < 50 * 16; ch += 1024) {
      const int node = ch >> 4, cc = (ch & 15) * 8;
      *(f16x8*)(xr_s + node * 128 + cc) =
          *(const f16x8*)(xrb + (size_t)(g * 200 + r0 + node) * 512 + chunk * 128 + cc);
    }
    for (int i = t; i < 64; i += 1024) {
      f16x2 a;
      a[0] = (_Float16)attw[chunk * 128 + 2 * i];
      a[1] = (_Float16)attw[chunk * 128 + 2 * i + 1];
      att_s[i] = __builtin_bit_cast(unsigned, a);
    }
    __syncthreads();
    for (int jj = wave; jj < 50; jj += 16) {
      const int gn = g * 200 + r0 + jj;
      const int cnt = cnts[gn];
      const unsigned char* lst = lists + (size_t)gn * NN;
#pragma unroll
      for (int r = 0; r < 4; ++r) {
        const int e = (r << 6) + lane;
        if (e < cnt) {
          const int s = lst[e];
          const int swz = (s & 15) << 4;
          float accv[4] = {0.f, 0.f, 0.f, 0.f};
#pragma unroll
          for (int c0 = 0; c0 < 128; c0 += 16) {
            const int ai = ((c0 >> 4) & 1) * 2;
            const unsigned* ap = att_s + c0 / 2;
            F16X8U xa, xb, raa, rbb;
            xa.v = *(const f16x8*)(smem + (((s * 128 + c0) * 2) ^ swz));
            xb.v = *(const f16x8*)(smem + (((s * 128 + c0 + 8) * 2) ^ swz));
            raa.v = *(const f16x8*)(xr_s + jj * 128 + c0);
            rbb.v = *(const f16x8*)(xr_s + jj * 128 + c0 + 8);
#pragma unroll
            for (int pq = 0; pq < 4; ++pq) {
              f16x2 z = xa.p[pq] + raa.p[pq];
              f16x2 zs = z * (_Float16)0.2f;
              f16x2 m = __builtin_elementwise_max(z, zs);
              accv[ai] = FDOT2(__builtin_bit_cast(f16x2, ap[pq]), m, accv[ai]);
              f16x2 z2 = xb.p[pq] + rbb.p[pq];
              f16x2 zs2 = z2 * (_Float16)0.2f;
              f16x2 m2 = __builtin_elementwise_max(z2, zs2);
              accv[ai + 1] = FDOT2(__builtin_bit_cast(f16x2, ap[4 + pq]), m2, accv[ai + 1]);
            }
          }
          const float acc = (accv[0] + accv[1]) + (accv[2] + accv[3]);
          if (chunk == 0) plog[jj * 200 + e] = acc;
          else plog[jj * 200 + e] += acc;
        }
      }
    }
  }
  __syncthreads();
  for (int jj = wave; jj < 50; jj += 16) {
    const int gn = g * 200 + r0 + jj;
    const int cnt = cnts[gn];
    float lg[4] = {-INFINITY, -INFINITY, -INFINITY, -INFINITY};
#pragma unroll
    for (int r = 0; r < 4; ++r) {
      const int e = (r << 6) + lane;
      if (e < cnt) lg[r] = plog[jj * 200 + e];
    }
    float mloc = fmaxf(fmaxf(lg[0], lg[1]), fmaxf(lg[2], lg[3]));
#pragma unroll
    for (int off = 32; off > 0; off >>= 1) mloc = fmaxf(mloc, __shfl_xor(mloc, off));
    float ex[4]; float ps = 0.f;
#pragma unroll
    for (int r = 0; r < 4; ++r) { ex[r] = __expf(lg[r] - mloc); ps += ex[r]; }
#pragma unroll
    for (int off = 32; off > 0; off >>= 1) ps += __shfl_xor(ps, off);
    const float denom = ps + 1e-16f;
#pragma unroll
    for (int r = 0; r < 4; ++r) {
      const int e = (r << 6) + lane;
      if (e < cnt) plog[jj * 200 + e] = ex[r] / denom;
    }
  }
  for (int chunk = 0; chunk < 4; ++chunk) {
    __syncthreads();
    for (int ch = t; ch < 200 * 16; ch += 1024) {
      const int node = ch >> 4, cc = (ch & 15) * 8;
      *(f16x8*)(smem + (((node * 128 + cc) * 2) ^ ((node & 15) << 4))) =
          *(const f16x8*)(xlb + (size_t)(g * 200 + node) * 512 + chunk * 128 + cc);
    }
    __syncthreads();
    float p[8] = {};
    for (int jj = wave; jj < 50; jj += 16) {
      const int gn = g * 200 + r0 + jj;
      const int cnt = cnts[gn];
      const unsigned char* lst = lists + (size_t)gn * NN;
      float o[8] = {};
      for (int e0 = 0; e0 < cnt; e0 += 4) {
        const int e = e0 + grp;
        if (e < cnt) {
          const float a = plog[jj * 200 + e];
          const int s = lst[e];
          const int swz = (s & 15) << 4;
          f16x8 xv = *(const f16x8*)(smem + (((s * 128 + li * 8) * 2) ^ swz));
#pragma unroll
          for (int q = 0; q < 8; ++q) o[q] += a * (float)xv[q];
        }
      }
#pragma unroll
      for (int q = 0; q < 8; ++q) {
        o[q] += __shfl_xor(o[q], 16);
        o[q] += __shfl_xor(o[q], 32);
      }
      if (grp == 0) {
        const int colb = chunk * 128 + li * 8;
#pragma unroll
        for (int q = 0; q < 8; ++q) p[q] += gelu_f(o[q] + biasw[colb + q]);
      }
    }
    if (grp == 0) {
      const int slot = range * 16 + wave;
      float* pd = psum + ((size_t)slot * 64 + g) * 512 + chunk * 128 + li * 8;
      float4 a0 = {p[0], p[1], p[2], p[3]};
      float4 a1 = {p[4], p[5], p[6], p[7]};
      *(float4*)pd = a0;
      *(float4*)(pd + 4) = a1;
    }
  }
}

// ---------------------------------------------------------------------------
// K10: d_out[b][c] = (1/200) * sum over 64 partial slots
// ---------------------------------------------------------------------------
__global__ void finalize(const float* __restrict__ psum, float* __restrict__ out) {
  const int idx = blockIdx.x * 256 + threadIdx.x;  // 32768 exact
  float s = 0.f;
#pragma unroll
  for (int k = 0; k < 64; ++k) s += psum[(size_t)k * 32768 + idx];
  out[idx] = s * 0.005f;
}

// ---------------------------------------------------------------------------
extern "C" void kernel_launch(void* const* d_in, const int* in_sizes, int n_in,
                              void* d_out, int out_size, void* d_ws, size_t ws_size,
                              hipStream_t stream) {
  const float* raw_fc = (const float*)d_in[0];
  const float* gbW = (const float*)d_in[1];
  const float* gbb = (const float*)d_in[2];
  const float* feW1 = (const float*)d_in[3];
  const float* feb1 = (const float*)d_in[4];
  const float* feW2 = (const float*)d_in[5];
  const float* feb2 = (const float*)d_in[6];
  const float* ln_g = (const float*)d_in[7];
  const float* ln_b = (const float*)d_in[8];
  const float* W1l = (const float*)d_in[9];  const float* b1l = (const float*)d_in[10];
  const float* W1r = (const float*)d_in[11]; const float* b1r = (const float*)d_in[12];
  const float* att1 = (const float*)d_in[13]; const float* bias1 = (const float*)d_in[14];
  const float* W2l = (const float*)d_in[15]; const float* b2l = (const float*)d_in[16];
  const float* W2r = (const float*)d_in[17]; const float* b2r = (const float*)d_in[18];
  const float* att2 = (const float*)d_in[19]; const float* bias2 = (const float*)d_in[20];
  const float* W3l = (const float*)d_in[21]; const float* b3l = (const float*)d_in[22];
  const float* W3r = (const float*)d_in[23]; const float* b3r = (const float*)d_in[24];
  const float* att3 = (const float*)d_in[25]; const float* bias3 = (const float*)d_in[26];

  if (ws_size < 121000000) return;  // need ~115.4 MiB scratch

  char* w = (char*)d_ws;
  float* adj   = (float*)(w + 0);
  float* adjS  = (float*)(w + 10240000);
  float* meanv = (float*)(w + 20480000);
  float* stdv  = (float*)(w + 20531200);
  int* cnt1    = (int*)(w + 21401856);
  int* cnt2    = (int*)(w + 21453056);
  unsigned char* list1 = (unsigned char*)(w + 21504256);
  unsigned char* list2 = (unsigned char*)(w + 24064256);
  _Float16* bufA = (_Float16*)(w + 26624256);   // xl1 / xl2 / xl3
  _Float16* bufB = (_Float16*)(w + 52838656);   // xr1 / xr2 / xr3
  _Float16* bufC = (_Float16*)(w + 79053056);   // x2 / x3
  float* psum = (float*)(w + 105267456);        // 8,388,608 B (64 slots)
  short* Ahi  = (short*)(w + 113656064);
  short* Alo  = (short*)(w + 114168064);
  _Float16* Wt2l = (_Float16*)(w + 114680064);
  _Float16* Wt2r = (_Float16*)(w + 116777216);
  _Float16* Wt3l = (_Float16*)(w + 118874368);
  _Float16* Wt3r = (_Float16*)(w + 119922944);

  const int SMEM_L1 = 65152;    // 51200+4096+6400+3200+256
  const int SMEM_L2 = 117504;   // 102400+8192+6400+512
  const int SMEM_L3 = 104256;   // 51200+12800+40000+256
  hipFuncSetAttribute((const void*)gat_layer<128, 1024, true>,
                      hipFuncAttributeMaxDynamicSharedMemorySize, SMEM_L1);
  hipFuncSetAttribute((const void*)gat_layer<256, 1024, false>,
                      hipFuncAttributeMaxDynamicSharedMemorySize, SMEM_L2);
  hipFuncSetAttribute((const void*)gat_l3,
                      hipFuncAttributeMaxDynamicSharedMemorySize, SMEM_L3);

  prep_A<<<1000, 256, 0, stream>>>(raw_fc, Ahi, Alo);
  transp_all<<<dim3(32, 32, 4), 256, 0, stream>>>(W2l, W2r, W3l, W3r, Wt2l, Wt2r, Wt3l, Wt3r);
  build_adj<<<625, 256, 0, stream>>>(Ahi, Alo, gbW, gbb, adj);
  symmetrize<<<dim3(64, 16), 256, 0, stream>>>(adj, adjS);
  rowstats<<<3200, 256, 0, stream>>>(adjS, meanv, stdv);
  radix_lists<<<64, 1024, 0, stream>>>(adjS, cnt1, cnt2, list1, list2);
  lin16_fused<<<800, 256, 0, stream>>>(meanv, stdv, feW1, feb1, feW2, feb2, ln_g, ln_b,
                                       W1l, b1l, W1r, b1r, bufA, bufB);
  gat_layer<128, 1024, true><<<dim3(64, 8), 1024, SMEM_L1, stream>>>(
      bufA, bufB, att1, bias1, cnt1, list1, bufC);
  gemm_nt<<<dim3(16, 100), 256, 0, stream>>>(bufC, Wt2l, Wt2r, b2l, b2r, bufA, bufB, 1024, 8);
  gat_layer<256, 1024, false><<<dim3(64, 4), 1024, SMEM_L2, stream>>>(
      bufA, bufB, att2, bias2, cnt2, list2, bufC);
  gemm_nt<<<dim3(8, 100), 256, 0, stream>>>(bufC, Wt3l, Wt3r, b3l, b3r, bufA, bufB, 512, 4);
  gat_l3<<<dim3(64, 4), 1024, SMEM_L3, stream>>>(bufA, bufB, att3, bias3, cnt2, list2, psum);
  finalize<<<128, 256, 0, stream>>>(psum, (float*)d_out);
}